// Round 6
// baseline (370.628 us; speedup 1.0000x reference)
//
#include <hip/hip_runtime.h>
#include <math.h>

#define EPS 1e-5f

typedef __attribute__((ext_vector_type(8))) short bf16x8;
typedef __attribute__((ext_vector_type(4))) float f32x4;

__device__ __forceinline__ unsigned short f2bf(float f) {
    unsigned int u = __float_as_uint(f);
    u += 0x7fff + ((u >> 16) & 1);            // round-to-nearest-even
    return (unsigned short)(u >> 16);
}
__device__ __forceinline__ float bf2f(unsigned short h) {
    return __uint_as_float(((unsigned int)h) << 16);
}
__device__ __forceinline__ float lof(unsigned int u) {
    return __uint_as_float(u << 16);
}
__device__ __forceinline__ float hif(unsigned int u) {
    return __uint_as_float(u & 0xffff0000u);
}
__device__ __forceinline__ void async16(void* lds, const void* g) {
    __builtin_amdgcn_global_load_lds(
        (const __attribute__((address_space(1))) unsigned int*)g,
        (__attribute__((address_space(3))) unsigned int*)lds, 16, 0, 0);
}

// ---------------- prep: everything weight-side in ONE kernel ----------------
__global__ __launch_bounds__(256) void prep_all(
    const float* __restrict__ lnfg, const float* __restrict__ lnfb,
    const float* __restrict__ wq, const float* __restrict__ bq,
    const float* __restrict__ efpw, const float* __restrict__ efpb,
    const float* __restrict__ lngg, const float* __restrict__ lngb,
    const float* __restrict__ wk, const float* __restrict__ bk,
    const float* __restrict__ wv, const float* __restrict__ bv,
    const float* __restrict__ wo, const float* __restrict__ outcw,
    const float* __restrict__ outcb, const float* __restrict__ bng,
    const float* __restrict__ bnb, const float* __restrict__ bnm,
    const float* __restrict__ bnv, const float* __restrict__ dwk,
    unsigned short* __restrict__ Wb1t, unsigned short* __restrict__ Wb2t,
    unsigned short* __restrict__ Wot, unsigned short* __restrict__ Woc,
    float* __restrict__ dwt,
    float* __restrict__ cs1, float* __restrict__ cst1,
    float* __restrict__ cs2, float* __restrict__ cst2,
    float* __restrict__ scv, float* __restrict__ shv)
{
    int idx = blockIdx.x * 256 + threadIdx.x;
    if (idx < 262144) {                       // Wb1t [n=512][k=512]: q | efp
        int n = idx >> 9, k = idx & 511;
        float v = (n < 256) ? lnfg[k] * wq[k * 256 + n]
                            : efpw[(size_t)(n - 256) * 512 + k];
        Wb1t[idx] = f2bf(v);
    } else if (idx < 327680) {                // Wb2t [n=256][k=256]: k only
        int j = idx - 262144; int n = j >> 8, k = j & 255;
        Wb2t[j] = f2bf(lngg[k] * wk[k * 256 + n]);
    } else if (idx < 393216) {                // Wot [256][256] = wo^T
        int j = idx - 327680; int n = j >> 8, k = j & 255;
        Wot[j] = f2bf(wo[k * 256 + n]);
    } else if (idx < 458752) {                // Woc [256][256] = outc_w
        int j = idx - 393216;
        Woc[j] = f2bf(outcw[j]);
    } else if (idx < 461056) {                // dwt [tap][ch]
        int j = idx - 458752; int tap = j >> 8, ch = j & 255;
        dwt[j] = dwk[ch * 9 + tap];
    } else if (idx < 462336) {                // column constants
        int j = idx - 461056;
        if (j < 256) {
            int n = j; float cs = 0.f, ct = 0.f;
            for (int k = 0; k < 512; k++) {
                float w = wq[k * 256 + n];
                cs += lnfg[k] * w; ct += lnfb[k] * w;
            }
            cs1[n] = cs; cst1[n] = ct + bq[n];
        } else if (j < 512) {
            cs1[j] = 0.f; cst1[j] = efpb[j - 256];
        } else if (j < 768) {
            int n = j - 512; float cs = 0.f, ct = 0.f;
            for (int k = 0; k < 256; k++) {
                float w = wk[k * 256 + n];
                cs += lngg[k] * w; ct += lngb[k] * w;
            }
            cs2[n] = cs; cst2[n] = ct + bk[n];
        } else if (j < 1024) {
            int n = j - 768; float cs = 0.f, ct = 0.f;
            for (int k = 0; k < 256; k++) {
                float w = wv[k * 256 + n];
                cs += lngg[k] * w; ct += lngb[k] * w;
            }
            cs2[256 + n] = cs; cst2[256 + n] = ct + bv[n];
        } else {
            int n = j - 1024;
            float s = bng[n] * rsqrtf(bnv[n] + EPS);
            scv[n] = s;
            shv[n] = (outcb[n] - bnm[n]) * s + bnb[n];
        }
    }
}

// ------- NCHW fp32 -> [M][C] bf16 transpose, partial LN stats (no atomics) --
// 2-tile register pipeline per block: both tiles' global loads issue up-front,
// tile-2 latency hides under tile-1's LDS/store/stats phase.
__global__ __launch_bounds__(256) void transpose_fg(
    const float* __restrict__ ef, const float* __restrict__ eg,
    unsigned short* __restrict__ ef_bf, unsigned short* __restrict__ eg_bf,
    float* __restrict__ pf, float* __restrict__ pfq,
    float* __restrict__ pg, float* __restrict__ pgq)
{
    __shared__ float tile[64][65];
    __shared__ float psum[4][64], pss[4][64];
    int id = blockIdx.x;
    const float* src; unsigned short* dst; float* ps; float* pq;
    int C, cblk, b, p0;
    if (id < 2048) {                          // e_f: 8b x 8cblk x 32ptile
        src = ef; dst = ef_bf; ps = pf; pq = pfq; C = 512;
        b = id >> 8; cblk = (id >> 5) & 7; p0 = (id & 31) * 128;
    } else {                                  // e_g: 8b x 4cblk x 32ptile
        id -= 2048;
        src = eg; dst = eg_bf; ps = pg; pq = pgq; C = 256;
        b = id >> 7; cblk = (id >> 5) & 3; p0 = (id & 31) * 128;
    }
    int c0 = cblk * 64;
    const float* s = src + ((size_t)b * C + c0) * 4096 + p0;
    int t = threadIdx.x;
    int cr = t >> 4, p4 = (t & 15) * 4;
    int lane = t & 63, grp = t >> 6;
    int pr = t >> 3, c8 = (t & 7) * 8;

    // issue ALL global loads for both 64-pos tiles up-front
    float4 r1[4], r2[4];
#pragma unroll
    for (int i = 0; i < 4; i++)
        r1[i] = *(const float4*)(s + (size_t)(i * 16 + cr) * 4096 + p4);
#pragma unroll
    for (int i = 0; i < 4; i++)
        r2[i] = *(const float4*)(s + (size_t)(i * 16 + cr) * 4096 + 64 + p4);

#pragma unroll
    for (int half = 0; half < 2; half++) {
#pragma unroll
        for (int i = 0; i < 4; i++) {
            float4 v = half ? r2[i] : r1[i];
            int c = i * 16 + cr;
            tile[c][p4 + 0] = v.x; tile[c][p4 + 1] = v.y;
            tile[c][p4 + 2] = v.z; tile[c][p4 + 3] = v.w;
        }
        __syncthreads();

        int pbase = p0 + half * 64;
        unsigned short* d = dst + ((size_t)(b * 4096 + pbase)) * C + c0;
#pragma unroll
        for (int i = 0; i < 2; i++) {
            int p = i * 32 + pr;
            uint4 pk;
            pk.x = (unsigned)f2bf(tile[c8 + 0][p]) | ((unsigned)f2bf(tile[c8 + 1][p]) << 16);
            pk.y = (unsigned)f2bf(tile[c8 + 2][p]) | ((unsigned)f2bf(tile[c8 + 3][p]) << 16);
            pk.z = (unsigned)f2bf(tile[c8 + 4][p]) | ((unsigned)f2bf(tile[c8 + 5][p]) << 16);
            pk.w = (unsigned)f2bf(tile[c8 + 6][p]) | ((unsigned)f2bf(tile[c8 + 7][p]) << 16);
            *(uint4*)(d + (size_t)p * C + c8) = pk;
        }

        // partial LN stats (sum over this block's 64 channels per position)
        float sm = 0.f, sq = 0.f;
#pragma unroll
        for (int j = 0; j < 16; j++) {
            float v = tile[grp * 16 + j][lane];
            sm += v; sq += v * v;
        }
        psum[grp][lane] = sm; pss[grp][lane] = sq;
        __syncthreads();
        if (t < 64) {
            float fs = psum[0][t] + psum[1][t] + psum[2][t] + psum[3][t];
            float fq = pss[0][t] + pss[1][t] + pss[2][t] + pss[3][t];
            ps[cblk * 32768 + b * 4096 + pbase + t] = fs;
            pq[cblk * 32768 + b * 4096 + pbase + t] = fq;
        }
        if (half == 0) __syncthreads();       // tile reuse fence
    }
}

// ------- GEMM1: ef_bf x Wb1t, 128m x 256n tile: q (y=0) | efp (y=1) ---------
// LN stats folded in: 128-thread prologue reduces pf/pfq partials.
__global__ __launch_bounds__(256, 2) void gemm1_mfma(
    const unsigned short* __restrict__ ef_bf, const unsigned short* __restrict__ Wb1t,
    const float* __restrict__ cs1, const float* __restrict__ cst1,
    const float* __restrict__ pf, const float* __restrict__ pfq,
    unsigned short* __restrict__ qbuf, unsigned short* __restrict__ efpbuf)
{
    __shared__ unsigned short As[128 * 64];   // 16 KB
    __shared__ unsigned short Bs[256 * 64];   // 32 KB
    __shared__ float smf[128], srf[128];
    f32x4 acc[4][8];
    const int tid = threadIdx.x;
    const int wave = tid >> 6, lane = tid & 63;
    const int wm = (wave & 1) * 64, wn = (wave >> 1) * 128;
    const int m0 = blockIdx.x * 128, n0 = blockIdx.y * 256;

    if (tid < 128) {                          // LN finalize for this block's rows
        int gm = m0 + tid;
        float s = 0.f, q = 0.f;
#pragma unroll
        for (int i = 0; i < 8; i++) { s += pf[i * 32768 + gm]; q += pfq[i * 32768 + gm]; }
        float m = s * (1.f / 512.f);
        smf[tid] = m;
        srf[tid] = rsqrtf(q * (1.f / 512.f) - m * m + EPS);
    }

#pragma unroll
    for (int i = 0; i < 4; i++)
#pragma unroll
        for (int j = 0; j < 8; j++) acc[i][j] = (f32x4){0.f, 0.f, 0.f, 0.f};

    const int srow = lane >> 3;
    const int sg = (lane & 7) ^ (srow & 7);
    const unsigned short* ga = ef_bf + (size_t)(m0 + wave * 32 + srow) * 512 + sg * 8;
    const unsigned short* gb = Wb1t + (size_t)(n0 + wave * 64 + srow) * 512 + sg * 8;

    for (int k0 = 0; k0 < 512; k0 += 64) {
#pragma unroll
        for (int t = 0; t < 4; t++)
            async16(As + (wave * 32 + t * 8) * 64, ga + (size_t)t * 8 * 512 + k0);
#pragma unroll
        for (int t = 0; t < 8; t++)
            async16(Bs + (wave * 64 + t * 8) * 64, gb + (size_t)t * 8 * 512 + k0);
        __syncthreads();
#pragma unroll
        for (int ks = 0; ks < 2; ks++) {
            bf16x8 af[4], bfr[8];
            int kb = ks * 4 + (lane >> 4);
            int slot = (kb ^ (lane & 7)) * 8;
#pragma unroll
            for (int i = 0; i < 4; i++)
                af[i] = *(const bf16x8*)&As[(wm + i * 16 + (lane & 15)) * 64 + slot];
#pragma unroll
            for (int j = 0; j < 8; j++)
                bfr[j] = *(const bf16x8*)&Bs[(wn + j * 16 + (lane & 15)) * 64 + slot];
#pragma unroll
            for (int i = 0; i < 4; i++)
#pragma unroll
                for (int j = 0; j < 8; j++)
                    acc[i][j] = __builtin_amdgcn_mfma_f32_16x16x32_bf16(
                        af[i], bfr[j], acc[i][j], 0, 0, 0);
        }
        __syncthreads();
    }

    bool isq = (n0 == 0);
#pragma unroll
    for (int i = 0; i < 4; i++) {
#pragma unroll
        for (int r = 0; r < 4; r++) {
            int lm = wm + i * 16 + ((lane >> 4) * 4) + r;
            int gm = m0 + lm;
            float mean = smf[lm], rs = srf[lm];
#pragma unroll
            for (int j = 0; j < 8; j++) {
                int nn = wn + j * 16 + (lane & 15);   // 0..255 within half
                float v = acc[i][j][r];
                if (isq) {
                    int n = nn;
                    float o = rs * (v - mean * cs1[n]) + cst1[n];
                    qbuf[(size_t)gm * 256 + nn] = f2bf(o);
                } else {
                    int n = nn + 256;
                    efpbuf[(size_t)gm * 256 + nn] = f2bf(v + cst1[n]);
                }
            }
        }
    }
}

// ---------------- MFMA GEMM core (m97-style, 128x128) -----------------------
template<int K>
__device__ __forceinline__ void mfma_core(
    const unsigned short* __restrict__ A, const unsigned short* __restrict__ Bt,
    int m0, int n0, unsigned short* As, unsigned short* Bs, f32x4 acc[4][4])
{
    const int tid = threadIdx.x;
    const int wave = tid >> 6, lane = tid & 63;
    const int wm = (wave & 1) * 64, wn = (wave >> 1) * 64;
#pragma unroll
    for (int i = 0; i < 4; i++)
#pragma unroll
        for (int j = 0; j < 4; j++) acc[i][j] = (f32x4){0.f, 0.f, 0.f, 0.f};

    const int srow = wave * 32 + (lane >> 3);
    const int sg = (lane & 7) ^ ((lane >> 3) & 7);
    const unsigned short* ga = A + (size_t)(m0 + srow) * K + sg * 8;
    const unsigned short* gb = Bt + (size_t)(n0 + srow) * K + sg * 8;

    for (int k0 = 0; k0 < K; k0 += 64) {
#pragma unroll
        for (int t = 0; t < 4; t++) {
            async16(As + (wave * 32 + t * 8) * 64, ga + (size_t)t * 8 * K + k0);
            async16(Bs + (wave * 32 + t * 8) * 64, gb + (size_t)t * 8 * K + k0);
        }
        __syncthreads();
#pragma unroll
        for (int ks = 0; ks < 2; ks++) {
            bf16x8 af[4], bfr[4];
            int kb = ks * 4 + (lane >> 4);
            int slot = (kb ^ (lane & 7)) * 8;
#pragma unroll
            for (int i = 0; i < 4; i++) {
                int m = wm + i * 16 + (lane & 15);
                af[i] = *(const bf16x8*)&As[m * 64 + slot];
                int n = wn + i * 16 + (lane & 15);
                bfr[i] = *(const bf16x8*)&Bs[n * 64 + slot];
            }
#pragma unroll
            for (int i = 0; i < 4; i++)
#pragma unroll
                for (int j = 0; j < 4; j++)
                    acc[i][j] = __builtin_amdgcn_mfma_f32_16x16x32_bf16(
                        af[i], bfr[j], acc[i][j], 0, 0, 0);
        }
        __syncthreads();
    }
}

// ---------------- GEMM2k: eg_bf x Wb2t -> kfull (LN stats folded in) --------
__global__ __launch_bounds__(256) void gemm2k_mfma(
    const unsigned short* __restrict__ eg_bf, const unsigned short* __restrict__ Wb2t,
    const float* __restrict__ cs2, const float* __restrict__ cst2,
    const float* __restrict__ pg, const float* __restrict__ pgq,
    float* __restrict__ mg, float* __restrict__ rg,
    unsigned short* __restrict__ kfull)
{
    __shared__ unsigned short As[8192], Bs[8192];
    __shared__ float smg[128], srg[128];
    f32x4 acc[4][4];
    int m0 = blockIdx.x * 128, n0 = blockIdx.y * 128;
    int tid = threadIdx.x;

    if (tid < 128) {
        int gm = m0 + tid;
        float s = 0.f, q = 0.f;
#pragma unroll
        for (int i = 0; i < 4; i++) { s += pg[i * 32768 + gm]; q += pgq[i * 32768 + gm]; }
        float m = s * (1.f / 256.f);
        float r = rsqrtf(q * (1.f / 256.f) - m * m + EPS);
        smg[tid] = m; srg[tid] = r;
        if (n0 == 0) { mg[gm] = m; rg[gm] = r; }   // for pool_phase
    }

    mfma_core<256>(eg_bf, Wb2t, m0, n0, As, Bs, acc);
    int lane = tid & 63, wave = tid >> 6;
    int wm = (wave & 1) * 64, wn = (wave >> 1) * 64;
#pragma unroll
    for (int i = 0; i < 4; i++) {
#pragma unroll
        for (int r = 0; r < 4; r++) {
            int lm = wm + i * 16 + ((lane >> 4) * 4) + r;
            int gm = m0 + lm;
            float mean = smg[lm], rs = srg[lm];
#pragma unroll
            for (int j = 0; j < 4; j++) {
                int n = n0 + wn + j * 16 + (lane & 15);
                float o = rs * (acc[i][j][r] - mean * cs2[n]) + cst2[n];
                kfull[(size_t)gm * 256 + n] = f2bf(o);
            }
        }
    }
}

// ------ pool phase: blocks 0..127 k-maxpool; 128..639 weighted v-pool -------
__global__ __launch_bounds__(256) void pool_phase(
    const unsigned short* __restrict__ kfull, const float* __restrict__ eg,
    const float* __restrict__ rg, const float* __restrict__ mg,
    unsigned short* __restrict__ kpb, float* __restrict__ s1,
    float* __restrict__ s0)
{
    __shared__ float smem[4352];
    int id = blockIdx.x;
    int t = threadIdx.x;
    if (id < 128) {
        // ---- k max pool: (b, cell) ----
        int b = id >> 4, cell = id & 15;
        int hp = cell >> 2, wp = cell & 3;
        int g8 = t & 31, rr = t >> 5;
        float kmx[8];
#pragma unroll
        for (int j = 0; j < 8; j++) kmx[j] = -3.402823466e38f;
#pragma unroll
        for (int rsub = 0; rsub < 2; rsub++) {
            int r = rr * 2 + rsub;
            int prow = (hp * 16 + r) * 64 + wp * 16;
            for (int cl = 0; cl < 16; cl++) {
                size_t basei = ((size_t)(b * 4096 + prow + cl)) * 256 + g8 * 8;
                uint4 kv = *(const uint4*)(kfull + basei);
                kmx[0] = fmaxf(kmx[0], lof(kv.x)); kmx[1] = fmaxf(kmx[1], hif(kv.x));
                kmx[2] = fmaxf(kmx[2], lof(kv.y)); kmx[3] = fmaxf(kmx[3], hif(kv.y));
                kmx[4] = fmaxf(kmx[4], lof(kv.z)); kmx[5] = fmaxf(kmx[5], hif(kv.z));
                kmx[6] = fmaxf(kmx[6], lof(kv.w)); kmx[7] = fmaxf(kmx[7], hif(kv.w));
            }
        }
#pragma unroll
        for (int j = 0; j < 8; j++) smem[rr * 256 + g8 * 8 + j] = kmx[j];
        __syncthreads();
        float m = smem[t];
#pragma unroll
        for (int r2 = 1; r2 < 8; r2++) m = fmaxf(m, smem[r2 * 256 + t]);
        kpb[(size_t)(b * 16 + cell) * 256 + t] = f2bf(m);   // lossless
    } else {
        // ---- weighted v-pool partials: (b, hp, cgrp) ----
        int id2 = id - 128;
        int b = id2 >> 6, hp = (id2 >> 4) & 3, cgrp = id2 & 15;
        int rr = t >> 4, cq = t & 15, cx = cq >> 2;
        int p = (hp * 16 + rr) * 64 + cq * 4;
        float4 w4 = *(const float4*)&rg[b * 4096 + p];
        float part[16];
        const float* egb = eg + ((size_t)b * 256 + cgrp * 16) * 4096 + p;
#pragma unroll
        for (int cc = 0; cc < 16; cc++) {
            float4 v4 = *(const float4*)(egb + (size_t)cc * 4096);
            part[cc] = w4.x * v4.x + w4.y * v4.y + w4.z * v4.z + w4.w * v4.w;
        }
#pragma unroll
        for (int cc = 0; cc < 16; cc++) smem[t * 16 + cc] = part[cc];
        if (cgrp == 0) {
            float4 m4 = *(const float4*)&mg[b * 4096 + p];
            smem[4096 + t] = w4.x * m4.x + w4.y * m4.y + w4.z * m4.z + w4.w * m4.w;
        }
        __syncthreads();
        if (t < 64) {
            int cx2 = t >> 4, cc = t & 15;
            float sacc = 0.f;
#pragma unroll
            for (int rr2 = 0; rr2 < 16; rr2++)
#pragma unroll
                for (int dq = 0; dq < 4; dq++)
                    sacc += smem[(rr2 * 16 + cx2 * 4 + dq) * 16 + cc];
            s1[((size_t)(b * 16 + hp * 4 + cx2)) * 256 + cgrp * 16 + cc] = sacc;
        }
        if (cgrp == 0 && t < 4) {
            float sacc = 0.f;
#pragma unroll
            for (int rr2 = 0; rr2 < 16; rr2++)
#pragma unroll
                for (int dq = 0; dq < 4; dq++)
                    sacc += smem[4096 + rr2 * 16 + t * 4 + dq];
            s0[b * 16 + hp * 4 + t] = sacc;
        }
    }
}

// ------- v-pool mini-GEMM: vp[cell][n] from s1/s0 (fp32, exact path) --------
__global__ __launch_bounds__(256) void vpool_gemm(
    const float* __restrict__ s1, const float* __restrict__ s0,
    const float* __restrict__ lngg, const float* __restrict__ wv,
    const float* __restrict__ cs2, const float* __restrict__ cst2,
    float* __restrict__ vp)
{
    int cell = blockIdx.x;        // 0..127 = b*16+cell
    int n = threadIdx.x;
    const float* s1r = s1 + (size_t)cell * 256;
    float acc = 0.f;
    for (int c = 0; c < 256; c++)
        acc = fmaf(lngg[c] * s1r[c], wv[c * 256 + n], acc);
    vp[(size_t)cell * 256 + n] = acc * (1.f / 256.f)
        - (s0[cell] * (1.f / 256.f)) * cs2[256 + n] + cst2[256 + n];
}

// ---- fused: combined (attn@vp + dw3x3(q)) -> GEMM3 (+gate) -> GEMM4 -> out.
// Block = one image row (64 pos). Wave w: scores+softmax for its 16-pos
// segment -> PV + depthwise conv -> pack combined bf16 DIRECTLY into LDS in
// the xor-swizzled A-layout phase-1 MFMA reads. No global `combined` buffer.
// eat aliases comb after phase-1 is fully consumed (barrier-protected).
__global__ __launch_bounds__(256) void fused_cdw34(
    const unsigned short* __restrict__ qbuf, const unsigned short* __restrict__ kpb,
    const float* __restrict__ vp, const float* __restrict__ dwt,
    const unsigned short* __restrict__ Wot, const float* __restrict__ bo,
    const unsigned short* __restrict__ efp, const unsigned short* __restrict__ Woc,
    const float* __restrict__ scv, const float* __restrict__ shv,
    float* __restrict__ outp)
{
    __shared__ unsigned short comb[64 * 256]; // 32 KB (later reused as eat)
    __shared__ unsigned short Bs[256 * 64];   // 32 KB: Wot then Woc
    __shared__ float attns[1024];             // 4 KB: [seg4][pos16][cell16]
    const int tid = threadIdx.x;
    const int wave = tid >> 6, lane = tid & 63;
    const int m0 = blockIdx.x * 64;
    const int b = m0 >> 12;
    const int prow0 = m0 & 4095;              // h*64
    const int h = prow0 >> 6;

    // ---- scores + softmax for segment `wave` (16 positions) ----
    {
        int fr = lane & 15, quad = lane >> 4;
        const unsigned short* qrow =
            qbuf + (size_t)(b * 4096 + prow0 + wave * 16 + fr) * 256 + quad * 8;
        const unsigned short* krow = kpb + (size_t)(b * 16 + fr) * 256 + quad * 8;
        f32x4 sacc = {0.f, 0.f, 0.f, 0.f};
#pragma unroll
        for (int ks = 0; ks < 8; ks++) {
            bf16x8 af = *(const bf16x8*)(qrow + ks * 32);
            bf16x8 bf_ = *(const bf16x8*)(krow + ks * 32);
            sacc = __builtin_amdgcn_mfma_f32_16x16x32_bf16(af, bf_, sacc, 0, 0, 0);
        }
#pragma unroll
        for (int r = 0; r < 4; r++) {
            float s = sacc[r] * 0.0625f;  // HID^-0.5
            float mx = s;
#pragma unroll
            for (int off = 8; off >= 1; off >>= 1) mx = fmaxf(mx, __shfl_xor(mx, off));
            float e = __expf(s - mx);
            float sum = e;
#pragma unroll
            for (int off = 8; off >= 1; off >>= 1) sum += __shfl_xor(sum, off);
            attns[wave * 256 + (quad * 4 + r) * 16 + fr] = e / sum;
        }
    }
    // (each wave reads only its own attns segment; within-wave LDS ordering ok)

    // ---- PV + dw for this wave's 16 positions -> comb (swizzled bf16) ----
    {
        int o4 = lane * 4;
        float4 kreg[9];
#pragma unroll
        for (int tap = 0; tap < 9; tap++)
            kreg[tap] = *(const float4*)&dwt[tap * 256 + o4];
        const float* arow_base = attns + wave * 256;
        const int kcq = lane >> 4;            // k>>6 of this lane's 4 channels
        const int kbq = (lane >> 1) & 7;      // k-octet
        const int koff = (lane & 1) * 4;      // offset within octet

#pragma unroll
        for (int sub = 0; sub < 4; sub++) {
            int p0w = wave * 16 + sub * 4;    // within-row pos of group of 4
            float4 acc[4];
#pragma unroll
            for (int i = 0; i < 4; i++) acc[i] = (float4){0.f, 0.f, 0.f, 0.f};
#pragma unroll
            for (int c = 0; c < 16; c++) {
                float4 v = *(const float4*)&vp[(size_t)(b * 16 + c) * 256 + o4];
#pragma unroll
                for (int i = 0; i < 4; i++) {
                    float a = arow_base[(sub * 4 + i) * 16 + c];
                    acc[i].x = fmaf(a, v.x, acc[i].x); acc[i].y = fmaf(a, v.y, acc[i].y);
                    acc[i].z = fmaf(a, v.z, acc[i].z); acc[i].w = fmaf(a, v.w, acc[i].w);
                }
            }
#pragma unroll
            for (int dy = 0; dy < 3; dy++) {
                int hh = h + dy - 1;
                if (hh < 0 || hh > 63) continue;
                const unsigned short* qr = qbuf + ((size_t)(b * 4096 + hh * 64)) * 256;
                float4 ft[6];
#pragma unroll
                for (int c = 0; c < 6; c++) {
                    int xx = p0w - 1 + c;
                    if (xx < 0 || xx > 63) {
                        ft[c] = (float4){0.f, 0.f, 0.f, 0.f};
                    } else {
                        uint2 qa = *(const uint2*)(qr + (size_t)xx * 256 + o4);
                        ft[c] = (float4){lof(qa.x), hif(qa.x), lof(qa.y), hif(qa.y)};
                    }
                }
#pragma unroll
                for (int dx = 0; dx < 3; dx++) {
                    float4 kk = kreg[dy * 3 + dx];
#pragma unroll
                    for (int i = 0; i < 4; i++) {
                        float4 qv = ft[i + dx];
                        acc[i].x = fmaf(qv.x, kk.x, acc[i].x);
                        acc[i].y = fmaf(qv.y, kk.y, acc[i].y);
                        acc[i].z = fmaf(qv.z, kk.z, acc[i].z);
                        acc[i].w = fmaf(qv.w, kk.w, acc[i].w);
                    }
                }
            }
            // write 4 pos x 4 ch (uint2 = 4 bf16) into swizzled comb layout
#pragma unroll
            for (int i = 0; i < 4; i++) {
                int p = p0w + i;
                uint2 pk;
                pk.x = (unsigned)f2bf(acc[i].x) | ((unsigned)f2bf(acc[i].y) << 16);
                pk.y = (unsigned)f2bf(acc[i].z) | ((unsigned)f2bf(acc[i].w) << 16);
                *(uint2*)&comb[p * 256 + kcq * 64 + (kbq ^ (p & 7)) * 8 + koff] = pk;
            }
        }
    }
    __syncthreads();

    const int srow = lane >> 3;
    const int sg = (lane & 7) ^ (srow & 7);

    // ---- phase 1 (GEMM3): comb x Wot -> acc (wave n-split wn = wave*64) ----
    f32x4 acc[4][4];
#pragma unroll
    for (int i = 0; i < 4; i++)
#pragma unroll
        for (int j = 0; j < 4; j++) acc[i][j] = (f32x4){0.f, 0.f, 0.f, 0.f};

    const unsigned short* gb = Wot + (size_t)(wave * 64 + srow) * 256 + sg * 8;
    for (int k0 = 0; k0 < 256; k0 += 64) {
#pragma unroll
        for (int t = 0; t < 8; t++)
            async16(Bs + (wave * 64 + t * 8) * 64, gb + (size_t)t * 8 * 256 + k0);
        __syncthreads();
        int kc = k0 >> 6;
#pragma unroll
        for (int ks = 0; ks < 2; ks++) {
            bf16x8 af[4], bfr[4];
            int kb = ks * 4 + (lane >> 4);
            int slot = (kb ^ (lane & 7)) * 8;
#pragma unroll
            for (int i = 0; i < 4; i++) {
                af[i]  = *(const bf16x8*)&comb[(i * 16 + (lane & 15)) * 256 + kc * 64 + slot];
                bfr[i] = *(const bf16x8*)&Bs[(wave * 64 + i * 16 + (lane & 15)) * 64 + slot];
            }
#pragma unroll
            for (int i = 0; i < 4; i++)
#pragma unroll
                for (int j = 0; j < 4; j++)
                    acc[i][j] = __builtin_amdgcn_mfma_f32_16x16x32_bf16(
                        af[i], bfr[j], acc[i][j], 0, 0, 0);
        }
        __syncthreads();
    }
    // after the last barrier above, all waves are done READING comb -> reuse it
    unsigned short* eat = comb;

    // ---- epilogue: +bo, gate by efp, bf16 -> eat (chunk-slot swizzled) ------
    float bo4[4];
#pragma unroll
    for (int j = 0; j < 4; j++) bo4[j] = bo[wave * 64 + j * 16 + (lane & 15)];
#pragma unroll
    for (int i = 0; i < 4; i++) {
#pragma unroll
        for (int r = 0; r < 4; r++) {
            int pos = i * 16 + ((lane >> 4) * 4) + r;
#pragma unroll
            for (int j = 0; j < 4; j++) {
                int n = wave * 64 + j * 16 + (lane & 15);
                float o = (acc[i][j][r] + bo4[j])
                          * bf2f(efp[(size_t)(m0 + pos) * 256 + n]);
                int o8 = j * 2 + ((lane >> 3) & 1);       // k-octet in chunk
                int slot = o8 ^ (pos & 7);
                eat[pos * 256 + wave * 64 + slot * 8 + (lane & 7)] = f2bf(o);
            }
        }
    }

    // ---- phase 2 (GEMM4): Woc x eat^T -> out (wave co-split) ----------------
    f32x4 acc2[4][4];
#pragma unroll
    for (int i = 0; i < 4; i++)
#pragma unroll
        for (int j = 0; j < 4; j++) acc2[i][j] = (f32x4){0.f, 0.f, 0.f, 0.f};

    const unsigned short* gw = Woc + (size_t)(wave * 64 + srow) * 256 + sg * 8;
    for (int k0 = 0; k0 < 256; k0 += 64) {
#pragma unroll
        for (int t = 0; t < 8; t++)
            async16(Bs + (wave * 64 + t * 8) * 64, gw + (size_t)t * 8 * 256 + k0);
        __syncthreads();
        int kc = k0 >> 6;
#pragma unroll
        for (int ks = 0; ks < 2; ks++) {
            bf16x8 af2[4], bf2_[4];
            int kb = ks * 4 + (lane >> 4);
            int slot = (kb ^ (lane & 7)) * 8;
#pragma unroll
            for (int i = 0; i < 4; i++) {
                af2[i]  = *(const bf16x8*)&Bs[(wave * 64 + i * 16 + (lane & 15)) * 64 + slot];
                bf2_[i] = *(const bf16x8*)&eat[(i * 16 + (lane & 15)) * 256 + kc * 64 + slot];
            }
#pragma unroll
            for (int i = 0; i < 4; i++)
#pragma unroll
                for (int j = 0; j < 4; j++)
                    acc2[i][j] = __builtin_amdgcn_mfma_f32_16x16x32_bf16(
                        af2[i], bf2_[j], acc2[i][j], 0, 0, 0);
        }
        __syncthreads();
    }

    // ---- BN + ReLU, store NCHW ----------------------------------------------
#pragma unroll
    for (int i = 0; i < 4; i++) {
#pragma unroll
        for (int r = 0; r < 4; r++) {
            int co = wave * 64 + i * 16 + ((lane >> 4) * 4) + r;
            float s = scv[co], hh2 = shv[co];
#pragma unroll
            for (int j = 0; j < 4; j++) {
                int p = m0 + j * 16 + (lane & 15);
                float o = fmaxf(fmaf(acc2[i][j][r], s, hh2), 0.f);
                outp[((size_t)(p >> 12)) * 1048576 + (size_t)co * 4096 + (p & 4095)] = o;
            }
        }
    }
}

// ---------------------------------------------------------------------------
extern "C" void kernel_launch(void* const* d_in, const int* in_sizes, int n_in,
                              void* d_out, int out_size, void* d_ws, size_t ws_size,
                              hipStream_t stream)
{
    const float* e_f   = (const float*)d_in[0];
    const float* e_g   = (const float*)d_in[1];
    const float* lnfg  = (const float*)d_in[4];
    const float* lnfb  = (const float*)d_in[5];
    const float* lngg  = (const float*)d_in[6];
    const float* lngb  = (const float*)d_in[7];
    const float* wq    = (const float*)d_in[8];
    const float* bq    = (const float*)d_in[9];
    const float* wk    = (const float*)d_in[10];
    const float* bk    = (const float*)d_in[11];
    const float* wv    = (const float*)d_in[12];
    const float* bv    = (const float*)d_in[13];
    const float* wo    = (const float*)d_in[14];
    const float* bo    = (const float*)d_in[15];
    const float* dwk   = (const float*)d_in[16];
    const float* efpw  = (const float*)d_in[17];
    const float* efpb  = (const float*)d_in[18];
    const float* outcw = (const float*)d_in[19];
    const float* outcb = (const float*)d_in[20];
    const float* bng   = (const float*)d_in[21];
    const float* bnb   = (const float*)d_in[22];
    const float* bnm   = (const float*)d_in[23];
    const float* bnv   = (const float*)d_in[24];
    float* outp = (float*)d_out;

    char* base = (char*)d_ws;
    auto alloc = [&](size_t bytes) -> char* {
        char* r = base; base += (bytes + 255) & ~(size_t)255; return r;
    };
    float* pf    = (float*)alloc(8 * 32768 * 4);
    float* pfq   = (float*)alloc(8 * 32768 * 4);
    float* pg    = (float*)alloc(4 * 32768 * 4);
    float* pgq   = (float*)alloc(4 * 32768 * 4);
    float* mg    = (float*)alloc(32768 * 4);
    float* rg    = (float*)alloc(32768 * 4);
    float* cs1   = (float*)alloc(512 * 4);
    float* cst1  = (float*)alloc(512 * 4);
    float* cs2   = (float*)alloc(512 * 4);
    float* cst2  = (float*)alloc(512 * 4);
    float* scv   = (float*)alloc(256 * 4);
    float* shv   = (float*)alloc(256 * 4);
    float* dwt   = (float*)alloc(9 * 256 * 4);
    unsigned short* Wb1t = (unsigned short*)alloc(262144 * 2);
    unsigned short* Wb2t = (unsigned short*)alloc(65536 * 2);
    unsigned short* Wot  = (unsigned short*)alloc(65536 * 2);
    unsigned short* Woc  = (unsigned short*)alloc(65536 * 2);
    unsigned short* ef_bf = (unsigned short*)alloc((size_t)32768 * 512 * 2);
    unsigned short* eg_bf = (unsigned short*)alloc((size_t)32768 * 256 * 2);
    unsigned short* qbuf  = (unsigned short*)alloc((size_t)32768 * 256 * 2);
    unsigned short* efpbuf = (unsigned short*)alloc((size_t)32768 * 256 * 2);
    unsigned short* kfull = (unsigned short*)alloc((size_t)32768 * 256 * 2);
    unsigned short* kpb  = (unsigned short*)alloc(128 * 256 * 2);
    float* vp    = (float*)alloc(128 * 256 * 4);
    float* s1    = (float*)alloc(128 * 256 * 4);
    float* s0    = (float*)alloc(128 * 4);

    prep_all<<<1806, 256, 0, stream>>>(
        lnfg, lnfb, wq, bq, efpw, efpb, lngg, lngb, wk, bk, wv, bv, wo,
        outcw, outcb, bng, bnb, bnm, bnv, dwk,
        Wb1t, Wb2t, Wot, Woc, dwt, cs1, cst1, cs2, cst2, scv, shv);
    transpose_fg<<<3072, 256, 0, stream>>>(e_f, e_g, ef_bf, eg_bf,
                                           pf, pfq, pg, pgq);
    gemm1_mfma<<<dim3(256, 2), 256, 0, stream>>>(ef_bf, Wb1t, cs1, cst1, pf, pfq,
                                                 qbuf, efpbuf);
    gemm2k_mfma<<<dim3(256, 2), 256, 0, stream>>>(eg_bf, Wb2t, cs2, cst2, pg, pgq,
                                                  mg, rg, kfull);
    pool_phase<<<640, 256, 0, stream>>>(kfull, e_g, rg, mg, kpb, s1, s0);
    vpool_gemm<<<128, 256, 0, stream>>>(s1, s0, lngg, wv, cs2, cst2, vp);
    fused_cdw34<<<512, 256, 0, stream>>>(qbuf, kpb, vp, dwt, Wot, bo, efpbuf,
                                         Woc, scv, shv, outp);
}

// Round 7
// 311.485 us; speedup vs baseline: 1.1899x; 1.1899x over previous
//
#include <hip/hip_runtime.h>
#include <math.h>

#define EPS 1e-5f

typedef __attribute__((ext_vector_type(8))) short bf16x8;
typedef __attribute__((ext_vector_type(4))) float f32x4;

__device__ __forceinline__ unsigned short f2bf(float f) {
    unsigned int u = __float_as_uint(f);
    u += 0x7fff + ((u >> 16) & 1);            // round-to-nearest-even
    return (unsigned short)(u >> 16);
}
__device__ __forceinline__ float bf2f(unsigned short h) {
    return __uint_as_float(((unsigned int)h) << 16);
}
__device__ __forceinline__ float lof(unsigned int u) {
    return __uint_as_float(u << 16);
}
__device__ __forceinline__ float hif(unsigned int u) {
    return __uint_as_float(u & 0xffff0000u);
}
__device__ __forceinline__ void async16(void* lds, const void* g) {
    __builtin_amdgcn_global_load_lds(
        (const __attribute__((address_space(1))) unsigned int*)g,
        (__attribute__((address_space(3))) unsigned int*)lds, 16, 0, 0);
}

// ---- merged: NCHW->bf16 transpose + LN partials (blocks 0..3071)
//      and weight-prep (blocks 3072..4877). Bodies verbatim from r3. --------
__global__ __launch_bounds__(256) void trans_prep(
    const float* __restrict__ ef, const float* __restrict__ eg,
    unsigned short* __restrict__ ef_bf, unsigned short* __restrict__ eg_bf,
    float* __restrict__ pf, float* __restrict__ pfq,
    float* __restrict__ pg, float* __restrict__ pgq,
    const float* __restrict__ lnfg, const float* __restrict__ lnfb,
    const float* __restrict__ wq, const float* __restrict__ bq,
    const float* __restrict__ efpw, const float* __restrict__ efpb,
    const float* __restrict__ lngg, const float* __restrict__ lngb,
    const float* __restrict__ wk, const float* __restrict__ bk,
    const float* __restrict__ wv, const float* __restrict__ bv,
    const float* __restrict__ wo, const float* __restrict__ outcw,
    const float* __restrict__ outcb, const float* __restrict__ bng,
    const float* __restrict__ bnb, const float* __restrict__ bnm,
    const float* __restrict__ bnv, const float* __restrict__ dwk,
    unsigned short* __restrict__ Wb1t, unsigned short* __restrict__ Wb2t,
    unsigned short* __restrict__ Wot, unsigned short* __restrict__ Woc,
    float* __restrict__ dwt,
    float* __restrict__ cs1, float* __restrict__ cst1,
    float* __restrict__ cs2, float* __restrict__ cst2,
    float* __restrict__ scv, float* __restrict__ shv)
{
    __shared__ float tile[64][65];
    __shared__ float psum[4][64], pss[4][64];
    int id = blockIdx.x;
    if (id < 3072) {
        // ---------------- transpose path (r3 verbatim) ----------------
        const float* src; unsigned short* dst; float* ps; float* pq;
        int C, cblk, b, p0;
        if (id < 2048) {                          // e_f: 8b x 8cblk x 32ptile
            src = ef; dst = ef_bf; ps = pf; pq = pfq; C = 512;
            b = id >> 8; cblk = (id >> 5) & 7; p0 = (id & 31) * 128;
        } else {                                  // e_g: 8b x 4cblk x 32ptile
            id -= 2048;
            src = eg; dst = eg_bf; ps = pg; pq = pgq; C = 256;
            b = id >> 7; cblk = (id >> 5) & 3; p0 = (id & 31) * 128;
        }
        int c0 = cblk * 64;
        const float* s = src + ((size_t)b * C + c0) * 4096 + p0;
        int t = threadIdx.x;
        int cr = t >> 4, p4 = (t & 15) * 4;
        int lane = t & 63, grp = t >> 6;
        int pr = t >> 3, c8 = (t & 7) * 8;

        float4 r1[4], r2[4];
#pragma unroll
        for (int i = 0; i < 4; i++)
            r1[i] = *(const float4*)(s + (size_t)(i * 16 + cr) * 4096 + p4);
#pragma unroll
        for (int i = 0; i < 4; i++)
            r2[i] = *(const float4*)(s + (size_t)(i * 16 + cr) * 4096 + 64 + p4);

#pragma unroll
        for (int half = 0; half < 2; half++) {
#pragma unroll
            for (int i = 0; i < 4; i++) {
                float4 v = half ? r2[i] : r1[i];
                int c = i * 16 + cr;
                tile[c][p4 + 0] = v.x; tile[c][p4 + 1] = v.y;
                tile[c][p4 + 2] = v.z; tile[c][p4 + 3] = v.w;
            }
            __syncthreads();

            int pbase = p0 + half * 64;
            unsigned short* d = dst + ((size_t)(b * 4096 + pbase)) * C + c0;
#pragma unroll
            for (int i = 0; i < 2; i++) {
                int p = i * 32 + pr;
                uint4 pk;
                pk.x = (unsigned)f2bf(tile[c8 + 0][p]) | ((unsigned)f2bf(tile[c8 + 1][p]) << 16);
                pk.y = (unsigned)f2bf(tile[c8 + 2][p]) | ((unsigned)f2bf(tile[c8 + 3][p]) << 16);
                pk.z = (unsigned)f2bf(tile[c8 + 4][p]) | ((unsigned)f2bf(tile[c8 + 5][p]) << 16);
                pk.w = (unsigned)f2bf(tile[c8 + 6][p]) | ((unsigned)f2bf(tile[c8 + 7][p]) << 16);
                *(uint4*)(d + (size_t)p * C + c8) = pk;
            }

            float sm = 0.f, sq = 0.f;
#pragma unroll
            for (int j = 0; j < 16; j++) {
                float v = tile[grp * 16 + j][lane];
                sm += v; sq += v * v;
            }
            psum[grp][lane] = sm; pss[grp][lane] = sq;
            __syncthreads();
            if (t < 64) {
                float fs = psum[0][t] + psum[1][t] + psum[2][t] + psum[3][t];
                float fq = pss[0][t] + pss[1][t] + pss[2][t] + pss[3][t];
                ps[cblk * 32768 + b * 4096 + pbase + t] = fs;
                pq[cblk * 32768 + b * 4096 + pbase + t] = fq;
            }
            if (half == 0) __syncthreads();       // tile reuse fence
        }
    } else {
        // ---------------- prep path (r3 prep_all verbatim) ----------------
        int idx = (id - 3072) * 256 + threadIdx.x;
        if (idx < 262144) {                       // Wb1t [n=512][k=512]: q | efp
            int n = idx >> 9, k = idx & 511;
            float v = (n < 256) ? lnfg[k] * wq[k * 256 + n]
                                : efpw[(size_t)(n - 256) * 512 + k];
            Wb1t[idx] = f2bf(v);
        } else if (idx < 327680) {                // Wb2t [n=256][k=256]: k only
            int j = idx - 262144; int n = j >> 8, k = j & 255;
            Wb2t[j] = f2bf(lngg[k] * wk[k * 256 + n]);
        } else if (idx < 393216) {                // Wot [256][256] = wo^T
            int j = idx - 327680; int n = j >> 8, k = j & 255;
            Wot[j] = f2bf(wo[k * 256 + n]);
        } else if (idx < 458752) {                // Woc [256][256] = outc_w
            int j = idx - 393216;
            Woc[j] = f2bf(outcw[j]);
        } else if (idx < 461056) {                // dwt [tap][ch]
            int j = idx - 458752; int tap = j >> 8, ch = j & 255;
            dwt[j] = dwk[ch * 9 + tap];
        } else if (idx < 462336) {                // column constants
            int j = idx - 461056;
            if (j < 256) {
                int n = j; float cs = 0.f, ct = 0.f;
                for (int k = 0; k < 512; k++) {
                    float w = wq[k * 256 + n];
                    cs += lnfg[k] * w; ct += lnfb[k] * w;
                }
                cs1[n] = cs; cst1[n] = ct + bq[n];
            } else if (j < 512) {
                cs1[j] = 0.f; cst1[j] = efpb[j - 256];
            } else if (j < 768) {
                int n = j - 512; float cs = 0.f, ct = 0.f;
                for (int k = 0; k < 256; k++) {
                    float w = wk[k * 256 + n];
                    cs += lngg[k] * w; ct += lngb[k] * w;
                }
                cs2[n] = cs; cst2[n] = ct + bk[n];
            } else if (j < 1024) {
                int n = j - 768; float cs = 0.f, ct = 0.f;
                for (int k = 0; k < 256; k++) {
                    float w = wv[k * 256 + n];
                    cs += lngg[k] * w; ct += lngb[k] * w;
                }
                cs2[256 + n] = cs; cst2[256 + n] = ct + bv[n];
            } else {
                int n = j - 1024;
                float s = bng[n] * rsqrtf(bnv[n] + EPS);
                scv[n] = s;
                shv[n] = (outcb[n] - bnm[n]) * s + bnb[n];
            }
        }
    }
}

// ---------------- MFMA GEMM core (m97-style, 128x128) -----------------------
template<int K>
__device__ __forceinline__ void mfma_core(
    const unsigned short* __restrict__ A, const unsigned short* __restrict__ Bt,
    int m0, int n0, unsigned short* As, unsigned short* Bs, f32x4 acc[4][4])
{
    const int tid = threadIdx.x;
    const int wave = tid >> 6, lane = tid & 63;
    const int wm = (wave & 1) * 64, wn = (wave >> 1) * 64;
#pragma unroll
    for (int i = 0; i < 4; i++)
#pragma unroll
        for (int j = 0; j < 4; j++) acc[i][j] = (f32x4){0.f, 0.f, 0.f, 0.f};

    const int srow = wave * 32 + (lane >> 3);
    const int sg = (lane & 7) ^ ((lane >> 3) & 7);
    const unsigned short* ga = A + (size_t)(m0 + srow) * K + sg * 8;
    const unsigned short* gb = Bt + (size_t)(n0 + srow) * K + sg * 8;

    for (int k0 = 0; k0 < K; k0 += 64) {
#pragma unroll
        for (int t = 0; t < 4; t++) {
            async16(As + (wave * 32 + t * 8) * 64, ga + (size_t)t * 8 * K + k0);
            async16(Bs + (wave * 32 + t * 8) * 64, gb + (size_t)t * 8 * K + k0);
        }
        __syncthreads();
#pragma unroll
        for (int ks = 0; ks < 2; ks++) {
            bf16x8 af[4], bfr[4];
            int kb = ks * 4 + (lane >> 4);
            int slot = (kb ^ (lane & 7)) * 8;
#pragma unroll
            for (int i = 0; i < 4; i++) {
                int m = wm + i * 16 + (lane & 15);
                af[i] = *(const bf16x8*)&As[m * 64 + slot];
                int n = wn + i * 16 + (lane & 15);
                bfr[i] = *(const bf16x8*)&Bs[n * 64 + slot];
            }
#pragma unroll
            for (int i = 0; i < 4; i++)
#pragma unroll
                for (int j = 0; j < 4; j++)
                    acc[i][j] = __builtin_amdgcn_mfma_f32_16x16x32_bf16(
                        af[i], bfr[j], acc[i][j], 0, 0, 0);
        }
        __syncthreads();
    }
}

// ---- merged projection GEMMs: blocks 0..511 = gemm1 (ef_bf x Wb1t ->
//      q|efp, 128m x 256n, LN prologue); blocks 512..1023 = gemm2k
//      (eg_bf x Wb2t -> kfull, 128m x 128n, LN prologue). Bodies r3-verbatim.
__global__ __launch_bounds__(256, 2) void gemm_proj(
    const unsigned short* __restrict__ ef_bf, const unsigned short* __restrict__ Wb1t,
    const float* __restrict__ cs1, const float* __restrict__ cst1,
    const float* __restrict__ pf, const float* __restrict__ pfq,
    unsigned short* __restrict__ qbuf, unsigned short* __restrict__ efpbuf,
    const unsigned short* __restrict__ eg_bf, const unsigned short* __restrict__ Wb2t,
    const float* __restrict__ cs2, const float* __restrict__ cst2,
    const float* __restrict__ pg, const float* __restrict__ pgq,
    float* __restrict__ mg, float* __restrict__ rg,
    unsigned short* __restrict__ kfull)
{
    __shared__ unsigned short As[128 * 64];   // 16 KB
    __shared__ unsigned short Bs[256 * 64];   // 32 KB (gemm2k uses first half)
    __shared__ float sstat[256];              // mean[128] | rstd[128]
    const int tid = threadIdx.x;
    const int wave = tid >> 6, lane = tid & 63;
    const int bid = blockIdx.x;

    if (bid < 512) {
        // ------------------------- gemm1 path -------------------------
        const int m0 = (bid >> 1) * 128, n0 = (bid & 1) * 256;
        const int wm = (wave & 1) * 64, wn = (wave >> 1) * 128;
        f32x4 acc[4][8];

        if (tid < 128) {                      // LN finalize for this block's rows
            int gm = m0 + tid;
            float s = 0.f, q = 0.f;
#pragma unroll
            for (int i = 0; i < 8; i++) { s += pf[i * 32768 + gm]; q += pfq[i * 32768 + gm]; }
            float m = s * (1.f / 512.f);
            sstat[tid] = m;
            sstat[128 + tid] = rsqrtf(q * (1.f / 512.f) - m * m + EPS);
        }

#pragma unroll
        for (int i = 0; i < 4; i++)
#pragma unroll
            for (int j = 0; j < 8; j++) acc[i][j] = (f32x4){0.f, 0.f, 0.f, 0.f};

        const int srow = lane >> 3;
        const int sg = (lane & 7) ^ (srow & 7);
        const unsigned short* ga = ef_bf + (size_t)(m0 + wave * 32 + srow) * 512 + sg * 8;
        const unsigned short* gb = Wb1t + (size_t)(n0 + wave * 64 + srow) * 512 + sg * 8;

        for (int k0 = 0; k0 < 512; k0 += 64) {
#pragma unroll
            for (int t = 0; t < 4; t++)
                async16(As + (wave * 32 + t * 8) * 64, ga + (size_t)t * 8 * 512 + k0);
#pragma unroll
            for (int t = 0; t < 8; t++)
                async16(Bs + (wave * 64 + t * 8) * 64, gb + (size_t)t * 8 * 512 + k0);
            __syncthreads();
#pragma unroll
            for (int ks = 0; ks < 2; ks++) {
                bf16x8 af[4], bfr[8];
                int kb = ks * 4 + (lane >> 4);
                int slot = (kb ^ (lane & 7)) * 8;
#pragma unroll
                for (int i = 0; i < 4; i++)
                    af[i] = *(const bf16x8*)&As[(wm + i * 16 + (lane & 15)) * 64 + slot];
#pragma unroll
                for (int j = 0; j < 8; j++)
                    bfr[j] = *(const bf16x8*)&Bs[(wn + j * 16 + (lane & 15)) * 64 + slot];
#pragma unroll
                for (int i = 0; i < 4; i++)
#pragma unroll
                    for (int j = 0; j < 8; j++)
                        acc[i][j] = __builtin_amdgcn_mfma_f32_16x16x32_bf16(
                            af[i], bfr[j], acc[i][j], 0, 0, 0);
            }
            __syncthreads();
        }

        bool isq = (n0 == 0);
#pragma unroll
        for (int i = 0; i < 4; i++) {
#pragma unroll
            for (int r = 0; r < 4; r++) {
                int lm = wm + i * 16 + ((lane >> 4) * 4) + r;
                int gm = m0 + lm;
                float mean = sstat[lm], rs = sstat[128 + lm];
#pragma unroll
                for (int j = 0; j < 8; j++) {
                    int nn = wn + j * 16 + (lane & 15);   // 0..255 within half
                    float v = acc[i][j][r];
                    if (isq) {
                        int n = nn;
                        float o = rs * (v - mean * cs1[n]) + cst1[n];
                        qbuf[(size_t)gm * 256 + nn] = f2bf(o);
                    } else {
                        int n = nn + 256;
                        efpbuf[(size_t)gm * 256 + nn] = f2bf(v + cst1[n]);
                    }
                }
            }
        }
    } else {
        // ------------------------- gemm2k path ------------------------
        const int j2 = bid - 512;
        const int m0 = (j2 >> 1) * 128, n0 = (j2 & 1) * 128;
        f32x4 acc[4][4];

        if (tid < 128) {
            int gm = m0 + tid;
            float s = 0.f, q = 0.f;
#pragma unroll
            for (int i = 0; i < 4; i++) { s += pg[i * 32768 + gm]; q += pgq[i * 32768 + gm]; }
            float m = s * (1.f / 256.f);
            float r = rsqrtf(q * (1.f / 256.f) - m * m + EPS);
            sstat[tid] = m; sstat[128 + tid] = r;
            if (n0 == 0) { mg[gm] = m; rg[gm] = r; }   // for pool_phase
        }

        mfma_core<256>(eg_bf, Wb2t, m0, n0, As, Bs, acc);
        int wm = (wave & 1) * 64, wn = (wave >> 1) * 64;
#pragma unroll
        for (int i = 0; i < 4; i++) {
#pragma unroll
            for (int r = 0; r < 4; r++) {
                int lm = wm + i * 16 + ((lane >> 4) * 4) + r;
                int gm = m0 + lm;
                float mean = sstat[lm], rs = sstat[128 + lm];
#pragma unroll
                for (int j = 0; j < 4; j++) {
                    int n = n0 + wn + j * 16 + (lane & 15);
                    float o = rs * (acc[i][j][r] - mean * cs2[n]) + cst2[n];
                    kfull[(size_t)gm * 256 + n] = f2bf(o);
                }
            }
        }
    }
}

// ------ pool phase: blocks 0..127 k-maxpool; 128..639 weighted v-pool -------
__global__ __launch_bounds__(256) void pool_phase(
    const unsigned short* __restrict__ kfull, const float* __restrict__ eg,
    const float* __restrict__ rg, const float* __restrict__ mg,
    unsigned short* __restrict__ kpb, float* __restrict__ s1,
    float* __restrict__ s0)
{
    __shared__ float smem[4352];
    int id = blockIdx.x;
    int t = threadIdx.x;
    if (id < 128) {
        // ---- k max pool: (b, cell) ----
        int b = id >> 4, cell = id & 15;
        int hp = cell >> 2, wp = cell & 3;
        int g8 = t & 31, rr = t >> 5;
        float kmx[8];
#pragma unroll
        for (int j = 0; j < 8; j++) kmx[j] = -3.402823466e38f;
#pragma unroll
        for (int rsub = 0; rsub < 2; rsub++) {
            int r = rr * 2 + rsub;
            int prow = (hp * 16 + r) * 64 + wp * 16;
            for (int cl = 0; cl < 16; cl++) {
                size_t basei = ((size_t)(b * 4096 + prow + cl)) * 256 + g8 * 8;
                uint4 kv = *(const uint4*)(kfull + basei);
                kmx[0] = fmaxf(kmx[0], lof(kv.x)); kmx[1] = fmaxf(kmx[1], hif(kv.x));
                kmx[2] = fmaxf(kmx[2], lof(kv.y)); kmx[3] = fmaxf(kmx[3], hif(kv.y));
                kmx[4] = fmaxf(kmx[4], lof(kv.z)); kmx[5] = fmaxf(kmx[5], hif(kv.z));
                kmx[6] = fmaxf(kmx[6], lof(kv.w)); kmx[7] = fmaxf(kmx[7], hif(kv.w));
            }
        }
#pragma unroll
        for (int j = 0; j < 8; j++) smem[rr * 256 + g8 * 8 + j] = kmx[j];
        __syncthreads();
        float m = smem[t];
#pragma unroll
        for (int r2 = 1; r2 < 8; r2++) m = fmaxf(m, smem[r2 * 256 + t]);
        kpb[(size_t)(b * 16 + cell) * 256 + t] = f2bf(m);   // lossless
    } else {
        // ---- weighted v-pool partials: (b, hp, cgrp) ----
        int id2 = id - 128;
        int b = id2 >> 6, hp = (id2 >> 4) & 3, cgrp = id2 & 15;
        int rr = t >> 4, cq = t & 15, cx = cq >> 2;
        int p = (hp * 16 + rr) * 64 + cq * 4;
        float4 w4 = *(const float4*)&rg[b * 4096 + p];
        float part[16];
        const float* egb = eg + ((size_t)b * 256 + cgrp * 16) * 4096 + p;
#pragma unroll
        for (int cc = 0; cc < 16; cc++) {
            float4 v4 = *(const float4*)(egb + (size_t)cc * 4096);
            part[cc] = w4.x * v4.x + w4.y * v4.y + w4.z * v4.z + w4.w * v4.w;
        }
#pragma unroll
        for (int cc = 0; cc < 16; cc++) smem[t * 16 + cc] = part[cc];
        if (cgrp == 0) {
            float4 m4 = *(const float4*)&mg[b * 4096 + p];
            smem[4096 + t] = w4.x * m4.x + w4.y * m4.y + w4.z * m4.z + w4.w * m4.w;
        }
        __syncthreads();
        if (t < 64) {
            int cx2 = t >> 4, cc = t & 15;
            float sacc = 0.f;
#pragma unroll
            for (int rr2 = 0; rr2 < 16; rr2++)
#pragma unroll
                for (int dq = 0; dq < 4; dq++)
                    sacc += smem[(rr2 * 16 + cx2 * 4 + dq) * 16 + cc];
            s1[((size_t)(b * 16 + hp * 4 + cx2)) * 256 + cgrp * 16 + cc] = sacc;
        }
        if (cgrp == 0 && t < 4) {
            float sacc = 0.f;
#pragma unroll
            for (int rr2 = 0; rr2 < 16; rr2++)
#pragma unroll
                for (int dq = 0; dq < 4; dq++)
                    sacc += smem[4096 + rr2 * 16 + t * 4 + dq];
            s0[b * 16 + hp * 4 + t] = sacc;
        }
    }
}

// ------- v-pool mini-GEMM: vp[cell][n] from s1/s0 (fp32, exact path) --------
__global__ __launch_bounds__(256) void vpool_gemm(
    const float* __restrict__ s1, const float* __restrict__ s0,
    const float* __restrict__ lngg, const float* __restrict__ wv,
    const float* __restrict__ cs2, const float* __restrict__ cst2,
    float* __restrict__ vp)
{
    int cell = blockIdx.x;        // 0..127 = b*16+cell
    int n = threadIdx.x;
    const float* s1r = s1 + (size_t)cell * 256;
    float acc = 0.f;
    for (int c = 0; c < 256; c++)
        acc = fmaf(lngg[c] * s1r[c], wv[c * 256 + n], acc);
    vp[(size_t)cell * 256 + n] = acc * (1.f / 256.f)
        - (s0[cell] * (1.f / 256.f)) * cs2[256 + n] + cst2[256 + n];
}

// ---- combined = attn@vp + dw3x3(q): scores fused, no global attns ----------
// Block: 16 consecutive positions (same image row). Wave 0: MFMA scores ->
// softmax -> LDS. Then all 4 waves x 4 positions: a_i + depthwise conv.
__global__ __launch_bounds__(256) void combined_dw(
    const unsigned short* __restrict__ qbuf, const unsigned short* __restrict__ kpb,
    const float* __restrict__ vp, const float* __restrict__ dwt,
    unsigned short* __restrict__ combined)
{
    __shared__ float attns[256];          // 16 pos x 16 cells
    int wave = threadIdx.x >> 6, lane = threadIdx.x & 63;
    int id = blockIdx.x;                  // 2048
    int b = id & 7, seg = id >> 3;        // batch pinned per XCD
    int pidx0 = seg * 16;

    if (wave == 0) {
        int fr = lane & 15, quad = lane >> 4;
        const unsigned short* qrow = qbuf + (size_t)(b * 4096 + pidx0 + fr) * 256 + quad * 8;
        const unsigned short* krow = kpb + (size_t)(b * 16 + fr) * 256 + quad * 8;
        f32x4 sacc = {0.f, 0.f, 0.f, 0.f};
#pragma unroll
        for (int ks = 0; ks < 8; ks++) {
            bf16x8 af = *(const bf16x8*)(qrow + ks * 32);
            bf16x8 bf_ = *(const bf16x8*)(krow + ks * 32);
            sacc = __builtin_amdgcn_mfma_f32_16x16x32_bf16(af, bf_, sacc, 0, 0, 0);
        }
#pragma unroll
        for (int r = 0; r < 4; r++) {
            float s = sacc[r] * 0.0625f;  // HID^-0.5
            float mx = s;
#pragma unroll
            for (int off = 8; off >= 1; off >>= 1) mx = fmaxf(mx, __shfl_xor(mx, off));
            float e = __expf(s - mx);
            float sum = e;
#pragma unroll
            for (int off = 8; off >= 1; off >>= 1) sum += __shfl_xor(sum, off);
            attns[(quad * 4 + r) * 16 + fr] = e / sum;
        }
    }
    __syncthreads();

    int pidx = pidx0 + wave * 4;
    int h = pidx >> 6, w0 = pidx & 63;
    int o4 = lane * 4;

    float4 kreg[9];
#pragma unroll
    for (int tap = 0; tap < 9; tap++)
        kreg[tap] = *(const float4*)&dwt[tap * 256 + o4];

    float4 acc[4];
#pragma unroll
    for (int i = 0; i < 4; i++) acc[i] = (float4){0.f, 0.f, 0.f, 0.f};

    const float* arow = attns + (wave * 4) * 16;
#pragma unroll
    for (int c = 0; c < 16; c++) {
        float4 v = *(const float4*)&vp[(size_t)(b * 16 + c) * 256 + o4];
#pragma unroll
        for (int i = 0; i < 4; i++) {
            float a = arow[i * 16 + c];
            acc[i].x = fmaf(a, v.x, acc[i].x); acc[i].y = fmaf(a, v.y, acc[i].y);
            acc[i].z = fmaf(a, v.z, acc[i].z); acc[i].w = fmaf(a, v.w, acc[i].w);
        }
    }
#pragma unroll
    for (int dy = 0; dy < 3; dy++) {
        int hh = h + dy - 1;
        if (hh < 0 || hh > 63) continue;
        const unsigned short* qr = qbuf + ((size_t)(b * 4096 + hh * 64)) * 256;
        float4 ft[6];
#pragma unroll
        for (int c = 0; c < 6; c++) {
            int xx = w0 - 1 + c;
            if (xx < 0 || xx > 63) {
                ft[c] = (float4){0.f, 0.f, 0.f, 0.f};
            } else {
                uint2 qa = *(const uint2*)(qr + (size_t)xx * 256 + o4);
                ft[c] = (float4){lof(qa.x), hif(qa.x), lof(qa.y), hif(qa.y)};
            }
        }
#pragma unroll
        for (int dx = 0; dx < 3; dx++) {
            float4 kk = kreg[dy * 3 + dx];
#pragma unroll
            for (int i = 0; i < 4; i++) {
                float4 qv = ft[i + dx];
                acc[i].x = fmaf(qv.x, kk.x, acc[i].x);
                acc[i].y = fmaf(qv.y, kk.y, acc[i].y);
                acc[i].z = fmaf(qv.z, kk.z, acc[i].z);
                acc[i].w = fmaf(qv.w, kk.w, acc[i].w);
            }
        }
    }
#pragma unroll
    for (int i = 0; i < 4; i++) {
        uint2 pk;
        pk.x = (unsigned)f2bf(acc[i].x) | ((unsigned)f2bf(acc[i].y) << 16);
        pk.y = (unsigned)f2bf(acc[i].z) | ((unsigned)f2bf(acc[i].w) << 16);
        *(uint2*)(combined + ((size_t)(b * 4096 + pidx + i)) * 256 + o4) = pk;
    }
}

// ------ GEMM3+4 fused: comb x Wot -> +bo, gate(efp) -> ea in LDS;
//        then Woc x ea^T -> out NCHW with BN+ReLU. 64 pos x 256 per block. ---
__global__ __launch_bounds__(256) void gemm34_mfma(
    const unsigned short* __restrict__ comb, const unsigned short* __restrict__ Wot,
    const float* __restrict__ bo, const unsigned short* __restrict__ efp,
    const unsigned short* __restrict__ Woc,
    const float* __restrict__ scv, const float* __restrict__ shv,
    float* __restrict__ outp)
{
    __shared__ unsigned short As[64 * 64];    // 8 KB  : phase1 A (64 pos x 64 k)
    __shared__ unsigned short Bs[256 * 64];   // 32 KB : phase1 Wot / phase2 Woc
    __shared__ unsigned short eat[64 * 256];  // 32 KB : gated ea tile (swizzled)
    const int tid = threadIdx.x;
    const int wave = tid >> 6, lane = tid & 63;
    const int m0 = blockIdx.x * 64;

    const int srow = lane >> 3;               // 0..7
    const int sg = (lane & 7) ^ (srow & 7);   // pre-swizzled k-chunk (m173)

    // ---- phase 1: comb[m0..m0+63][:] x Wot -> acc (wave n-split wn=wave*64) -
    f32x4 acc[4][4];
#pragma unroll
    for (int i = 0; i < 4; i++)
#pragma unroll
        for (int j = 0; j < 4; j++) acc[i][j] = (f32x4){0.f, 0.f, 0.f, 0.f};

    const unsigned short* ga = comb + (size_t)(m0 + wave * 16 + srow) * 256 + sg * 8;
    const unsigned short* gb = Wot + (size_t)(wave * 64 + srow) * 256 + sg * 8;

    for (int k0 = 0; k0 < 256; k0 += 64) {
#pragma unroll
        for (int t = 0; t < 2; t++)
            async16(As + (wave * 16 + t * 8) * 64, ga + (size_t)t * 8 * 256 + k0);
#pragma unroll
        for (int t = 0; t < 8; t++)
            async16(Bs + (wave * 64 + t * 8) * 64, gb + (size_t)t * 8 * 256 + k0);
        __syncthreads();
#pragma unroll
        for (int ks = 0; ks < 2; ks++) {
            bf16x8 af[4], bfr[4];
            int kb = ks * 4 + (lane >> 4);
            int slot = (kb ^ (lane & 7)) * 8;
#pragma unroll
            for (int i = 0; i < 4; i++) {
                af[i]  = *(const bf16x8*)&As[(i * 16 + (lane & 15)) * 64 + slot];
                bfr[i] = *(const bf16x8*)&Bs[(wave * 64 + i * 16 + (lane & 15)) * 64 + slot];
            }
#pragma unroll
            for (int i = 0; i < 4; i++)
#pragma unroll
                for (int j = 0; j < 4; j++)
                    acc[i][j] = __builtin_amdgcn_mfma_f32_16x16x32_bf16(
                        af[i], bfr[j], acc[i][j], 0, 0, 0);
        }
        __syncthreads();
    }

    // ---- epilogue: +bo, gate by efp, bf16 -> eat (chunk-slot swizzled) ------
    float bo4[4];
#pragma unroll
    for (int j = 0; j < 4; j++) bo4[j] = bo[wave * 64 + j * 16 + (lane & 15)];
#pragma unroll
    for (int i = 0; i < 4; i++) {
#pragma unroll
        for (int r = 0; r < 4; r++) {
            int pos = i * 16 + ((lane >> 4) * 4) + r;
#pragma unroll
            for (int j = 0; j < 4; j++) {
                int n = wave * 64 + j * 16 + (lane & 15);
                float o = (acc[i][j][r] + bo4[j])
                          * bf2f(efp[(size_t)(m0 + pos) * 256 + n]);
                int o8 = j * 2 + ((lane >> 3) & 1);       // k-octet in chunk
                int slot = o8 ^ (pos & 7);
                eat[pos * 256 + wave * 64 + slot * 8 + (lane & 7)] = f2bf(o);
            }
        }
    }

    // ---- phase 2: Woc x eat^T -> out (wave co-split, co = wave*64 + ...) ----
    f32x4 acc2[4][4];
#pragma unroll
    for (int i = 0; i < 4; i++)
#pragma unroll
        for (int j = 0; j < 4; j++) acc2[i][j] = (f32x4){0.f, 0.f, 0.f, 0.f};

    const unsigned short* gw = Woc + (size_t)(wave * 64 + srow) * 256 + sg * 8;
    for (int k0 = 0; k0 < 256; k0 += 64) {
#pragma unroll
        for (int t = 0; t < 8; t++)
            async16(Bs + (wave * 64 + t * 8) * 64, gw + (size_t)t * 8 * 256 + k0);
        __syncthreads();
        int kc = k0 >> 6;
#pragma unroll
        for (int ks = 0; ks < 2; ks++) {
            bf16x8 af2[4], bf2_[4];
            int kb = ks * 4 + (lane >> 4);
            int slot = (kb ^ (lane & 7)) * 8;
#pragma unroll
            for (int i = 0; i < 4; i++) {
                af2[i]  = *(const bf16x8*)&Bs[(wave * 64 + i * 16 + (lane & 15)) * 64 + slot];
                bf2_[i] = *(const bf16x8*)&eat[(i * 16 + (lane & 15)) * 256 + kc * 64 + slot];
            }
#pragma unroll
            for (int i = 0; i < 4; i++)
#pragma unroll
                for (int j = 0; j < 4; j++)
                    acc2[i][j] = __builtin_amdgcn_mfma_f32_16x16x32_bf16(
                        af2[i], bf2_[j], acc2[i][j], 0, 0, 0);
        }
        __syncthreads();
    }

    // ---- BN + ReLU, store NCHW -----------------------------------------------
#pragma unroll
    for (int i = 0; i < 4; i++) {
#pragma unroll
        for (int r = 0; r < 4; r++) {
            int co = wave * 64 + i * 16 + ((lane >> 4) * 4) + r;
            float s = scv[co], hh = shv[co];
#pragma unroll
            for (int j = 0; j < 4; j++) {
                int p = m0 + j * 16 + (lane & 15);
                float o = fmaxf(fmaf(acc2[i][j][r], s, hh), 0.f);
                outp[((size_t)(p >> 12)) * 1048576 + (size_t)co * 4096 + (p & 4095)] = o;
            }
        }
    }
}

// ---------------------------------------------------------------------------
extern "C" void kernel_launch(void* const* d_in, const int* in_sizes, int n_in,
                              void* d_out, int out_size, void* d_ws, size_t ws_size,
                              hipStream_t stream)
{
    const float* e_f   = (const float*)d_in[0];
    const float* e_g   = (const float*)d_in[1];
    const float* lnfg  = (const float*)d_in[4];
    const float* lnfb  = (const float*)d_in[5];
    const float* lngg  = (const float*)d_in[6];
    const float* lngb  = (const float*)d_in[7];
    const float* wq    = (const float*)d_in[8];
    const float* bq    = (const float*)d_in[9];
    const float* wk    = (const float*)d_in[10];
    const float* bk    = (const float*)d_in[11];
    const float* wv    = (const float*)d_in[12];
    const float* bv    = (const float*)d_in[13];
    const float* wo    = (const float*)d_in[14];
    const float* bo    = (const float*)d_in[15];
    const float* dwk   = (const float*)d_in[16];
    const float* efpw  = (const float*)d_in[17];
    const float* efpb  = (const float*)d_in[18];
    const float* outcw = (const float*)d_in[19];
    const float* outcb = (const float*)d_in[20];
    const float* bng   = (const float*)d_in[21];
    const float* bnb   = (const float*)d_in[22];
    const float* bnm   = (const float*)d_in[23];
    const float* bnv   = (const float*)d_in[24];
    float* outp = (float*)d_out;

    char* base = (char*)d_ws;
    auto alloc = [&](size_t bytes) -> char* {
        char* r = base; base += (bytes + 255) & ~(size_t)255; return r;
    };
    float* pf    = (float*)alloc(8 * 32768 * 4);
    float* pfq   = (float*)alloc(8 * 32768 * 4);
    float* pg    = (float*)alloc(4 * 32768 * 4);
    float* pgq   = (float*)alloc(4 * 32768 * 4);
    float* mg    = (float*)alloc(32768 * 4);
    float* rg    = (float*)alloc(32768 * 4);
    float* cs1   = (float*)alloc(512 * 4);
    float* cst1  = (float*)alloc(512 * 4);
    float* cs2   = (float*)alloc(512 * 4);
    float* cst2  = (float*)alloc(512 * 4);
    float* scv   = (float*)alloc(256 * 4);
    float* shv   = (float*)alloc(256 * 4);
    float* dwt   = (float*)alloc(9 * 256 * 4);
    unsigned short* Wb1t = (unsigned short*)alloc(262144 * 2);
    unsigned short* Wb2t = (unsigned short*)alloc(65536 * 2);
    unsigned short* Wot  = (unsigned short*)alloc(65536 * 2);
    unsigned short* Woc  = (unsigned short*)alloc(65536 * 2);
    unsigned short* ef_bf = (unsigned short*)alloc((size_t)32768 * 512 * 2);
    unsigned short* eg_bf = (unsigned short*)alloc((size_t)32768 * 256 * 2);
    unsigned short* qbuf  = (unsigned short*)alloc((size_t)32768 * 256 * 2);
    unsigned short* efpbuf = (unsigned short*)alloc((size_t)32768 * 256 * 2);
    unsigned short* kfull = (unsigned short*)alloc((size_t)32768 * 256 * 2); // -> combined
    unsigned short* kpb  = (unsigned short*)alloc(128 * 256 * 2);
    float* vp    = (float*)alloc(128 * 256 * 4);
    float* s1    = (float*)alloc(128 * 256 * 4);
    float* s0    = (float*)alloc(128 * 4);

    trans_prep<<<4878, 256, 0, stream>>>(
        e_f, e_g, ef_bf, eg_bf, pf, pfq, pg, pgq,
        lnfg, lnfb, wq, bq, efpw, efpb, lngg, lngb, wk, bk, wv, bv, wo,
        outcw, outcb, bng, bnb, bnm, bnv, dwk,
        Wb1t, Wb2t, Wot, Woc, dwt, cs1, cst1, cs2, cst2, scv, shv);
    gemm_proj<<<1024, 256, 0, stream>>>(
        ef_bf, Wb1t, cs1, cst1, pf, pfq, qbuf, efpbuf,
        eg_bf, Wb2t, cs2, cst2, pg, pgq, mg, rg, kfull);
    pool_phase<<<640, 256, 0, stream>>>(kfull, e_g, rg, mg, kpb, s1, s0);
    vpool_gemm<<<128, 256, 0, stream>>>(s1, s0, lngg, wv, cs2, cst2, vp);
    combined_dw<<<2048, 256, 0, stream>>>(qbuf, kpb, vp, dwt, /*combined=*/kfull);
    gemm34_mfma<<<512, 256, 0, stream>>>(/*combined=*/kfull, Wot, bo, efpbuf,
                                         Woc, scv, shv, outp);
}

// Round 8
// 303.751 us; speedup vs baseline: 1.2202x; 1.0255x over previous
//
#include <hip/hip_runtime.h>
#include <math.h>

#define EPS 1e-5f

typedef __attribute__((ext_vector_type(8))) short bf16x8;
typedef __attribute__((ext_vector_type(4))) float f32x4;

__device__ __forceinline__ unsigned short f2bf(float f) {
    unsigned int u = __float_as_uint(f);
    u += 0x7fff + ((u >> 16) & 1);            // round-to-nearest-even
    return (unsigned short)(u >> 16);
}
__device__ __forceinline__ float bf2f(unsigned short h) {
    return __uint_as_float(((unsigned int)h) << 16);
}
__device__ __forceinline__ float lof(unsigned int u) {
    return __uint_as_float(u << 16);
}
__device__ __forceinline__ float hif(unsigned int u) {
    return __uint_as_float(u & 0xffff0000u);
}
__device__ __forceinline__ void async16(void* lds, const void* g) {
    __builtin_amdgcn_global_load_lds(
        (const __attribute__((address_space(1))) unsigned int*)g,
        (__attribute__((address_space(3))) unsigned int*)lds, 16, 0, 0);
}

// ---- merged: NCHW->bf16 transpose + LN partials (blocks 0..3071)
//      and weight-prep (blocks 3072..3332, coalesced LDS-tiled). -------------
__global__ __launch_bounds__(256) void trans_prep(
    const float* __restrict__ ef, const float* __restrict__ eg,
    unsigned short* __restrict__ ef_bf, unsigned short* __restrict__ eg_bf,
    float* __restrict__ pf, float* __restrict__ pfq,
    float* __restrict__ pg, float* __restrict__ pgq,
    const float* __restrict__ lnfg, const float* __restrict__ lnfb,
    const float* __restrict__ wq, const float* __restrict__ bq,
    const float* __restrict__ efpw, const float* __restrict__ efpb,
    const float* __restrict__ lngg, const float* __restrict__ lngb,
    const float* __restrict__ wk, const float* __restrict__ bk,
    const float* __restrict__ wv, const float* __restrict__ bv,
    const float* __restrict__ wo, const float* __restrict__ outcw,
    const float* __restrict__ outcb, const float* __restrict__ bng,
    const float* __restrict__ bnb, const float* __restrict__ bnm,
    const float* __restrict__ bnv, const float* __restrict__ dwk,
    unsigned short* __restrict__ Wb1t, unsigned short* __restrict__ Wb2t,
    unsigned short* __restrict__ Wot, unsigned short* __restrict__ Woc,
    float* __restrict__ dwt,
    float* __restrict__ cs1, float* __restrict__ cst1,
    float* __restrict__ cs2, float* __restrict__ cst2,
    float* __restrict__ scv, float* __restrict__ shv)
{
    __shared__ float tile[64][65];
    __shared__ float psum[4][64], pss[4][64];
    int id = blockIdx.x;
    int t = threadIdx.x;
    if (id < 3072) {
        // ---------------- transpose path (r3 verbatim) ----------------
        const float* src; unsigned short* dst; float* ps; float* pq;
        int C, cblk, b, p0;
        if (id < 2048) {                          // e_f: 8b x 8cblk x 32ptile
            src = ef; dst = ef_bf; ps = pf; pq = pfq; C = 512;
            b = id >> 8; cblk = (id >> 5) & 7; p0 = (id & 31) * 128;
        } else {                                  // e_g: 8b x 4cblk x 32ptile
            id -= 2048;
            src = eg; dst = eg_bf; ps = pg; pq = pgq; C = 256;
            b = id >> 7; cblk = (id >> 5) & 3; p0 = (id & 31) * 128;
        }
        int c0 = cblk * 64;
        const float* s = src + ((size_t)b * C + c0) * 4096 + p0;
        int cr = t >> 4, p4 = (t & 15) * 4;
        int lane = t & 63, grp = t >> 6;
        int pr = t >> 3, c8 = (t & 7) * 8;

        float4 r1[4], r2[4];
#pragma unroll
        for (int i = 0; i < 4; i++)
            r1[i] = *(const float4*)(s + (size_t)(i * 16 + cr) * 4096 + p4);
#pragma unroll
        for (int i = 0; i < 4; i++)
            r2[i] = *(const float4*)(s + (size_t)(i * 16 + cr) * 4096 + 64 + p4);

#pragma unroll
        for (int half = 0; half < 2; half++) {
#pragma unroll
            for (int i = 0; i < 4; i++) {
                float4 v = half ? r2[i] : r1[i];
                int c = i * 16 + cr;
                tile[c][p4 + 0] = v.x; tile[c][p4 + 1] = v.y;
                tile[c][p4 + 2] = v.z; tile[c][p4 + 3] = v.w;
            }
            __syncthreads();

            int pbase = p0 + half * 64;
            unsigned short* d = dst + ((size_t)(b * 4096 + pbase)) * C + c0;
#pragma unroll
            for (int i = 0; i < 2; i++) {
                int p = i * 32 + pr;
                uint4 pk;
                pk.x = (unsigned)f2bf(tile[c8 + 0][p]) | ((unsigned)f2bf(tile[c8 + 1][p]) << 16);
                pk.y = (unsigned)f2bf(tile[c8 + 2][p]) | ((unsigned)f2bf(tile[c8 + 3][p]) << 16);
                pk.z = (unsigned)f2bf(tile[c8 + 4][p]) | ((unsigned)f2bf(tile[c8 + 5][p]) << 16);
                pk.w = (unsigned)f2bf(tile[c8 + 6][p]) | ((unsigned)f2bf(tile[c8 + 7][p]) << 16);
                *(uint4*)(d + (size_t)p * C + c8) = pk;
            }

            float sm = 0.f, sq = 0.f;
#pragma unroll
            for (int j = 0; j < 16; j++) {
                float v = tile[grp * 16 + j][lane];
                sm += v; sq += v * v;
            }
            psum[grp][lane] = sm; pss[grp][lane] = sq;
            __syncthreads();
            if (t < 64) {
                float fs = psum[0][t] + psum[1][t] + psum[2][t] + psum[3][t];
                float fq = pss[0][t] + pss[1][t] + pss[2][t] + pss[3][t];
                ps[cblk * 32768 + b * 4096 + pbase + t] = fs;
                pq[cblk * 32768 + b * 4096 + pbase + t] = fq;
            }
            if (half == 0) __syncthreads();       // tile reuse fence
        }
    } else {
        int id2 = id - 3072;
        if (id2 < 64) {
            // -- LDS-tiled 64x64 weight transpose (coalesced both sides) --
            const float* src; unsigned short* dst; const float* scale;
            int K, k0, n0;
            if (id2 < 32) {            // Wb1t-q: wq[512][256] -> [n<256][512]
                src = wq; dst = Wb1t; scale = lnfg; K = 512;
                k0 = (id2 >> 2) * 64; n0 = (id2 & 3) * 64;
            } else if (id2 < 48) {     // Wb2t: wk[256][256] -> [n][256]
                int j = id2 - 32;
                src = wk; dst = Wb2t; scale = lngg; K = 256;
                k0 = (j >> 2) * 64; n0 = (j & 3) * 64;
            } else {                   // Wot: wo[256][256] -> [n][256]
                int j = id2 - 48;
                src = wo; dst = Wot; scale = nullptr; K = 256;
                k0 = (j >> 2) * 64; n0 = (j & 3) * 64;
            }
            int rr = t >> 6, cc = t & 63;
#pragma unroll
            for (int i = 0; i < 16; i++) {
                int r = i * 4 + rr;
                tile[r][cc] = src[(size_t)(k0 + r) * 256 + n0 + cc];
            }
            __syncthreads();
            int nn = t >> 3, k8 = (t & 7) * 8;
#pragma unroll
            for (int i = 0; i < 2; i++) {
                int n = i * 32 + nn;
                float v[8];
#pragma unroll
                for (int j = 0; j < 8; j++) {
                    float s = scale ? scale[k0 + k8 + j] : 1.f;
                    v[j] = s * tile[k8 + j][n];
                }
                uint4 pk;
                pk.x = (unsigned)f2bf(v[0]) | ((unsigned)f2bf(v[1]) << 16);
                pk.y = (unsigned)f2bf(v[2]) | ((unsigned)f2bf(v[3]) << 16);
                pk.z = (unsigned)f2bf(v[4]) | ((unsigned)f2bf(v[5]) << 16);
                pk.w = (unsigned)f2bf(v[6]) | ((unsigned)f2bf(v[7]) << 16);
                *(uint4*)(dst + (size_t)(n0 + n) * K + k0 + k8) = pk;
            }
        } else if (id2 < 192) {        // Wb1t-efp half: row-major copy-convert
            int j = (id2 - 64) * 1024 + t * 4;
            float4 v = *(const float4*)(efpw + j);
            uint2 pk;
            pk.x = (unsigned)f2bf(v.x) | ((unsigned)f2bf(v.y) << 16);
            pk.y = (unsigned)f2bf(v.z) | ((unsigned)f2bf(v.w) << 16);
            *(uint2*)(Wb1t + 131072 + j) = pk;
        } else if (id2 < 256) {        // Woc copy-convert
            int j = (id2 - 192) * 1024 + t * 4;
            float4 v = *(const float4*)(outcw + j);
            uint2 pk;
            pk.x = (unsigned)f2bf(v.x) | ((unsigned)f2bf(v.y) << 16);
            pk.y = (unsigned)f2bf(v.z) | ((unsigned)f2bf(v.w) << 16);
            *(uint2*)(Woc + j) = pk;
        } else if (id2 == 256) {       // dwt [tap][ch]
#pragma unroll
            for (int tap = 0; tap < 9; tap++)
                dwt[tap * 256 + t] = dwk[t * 9 + tap];
        } else if (id2 == 257) {       // cs1/cst1 (+efp constants)
            int n = t; float cs = 0.f, ct = 0.f;
            for (int k = 0; k < 512; k++) {
                float w = wq[k * 256 + n];
                cs += lnfg[k] * w; ct += lnfb[k] * w;
            }
            cs1[n] = cs; cst1[n] = ct + bq[n];
            cs1[256 + n] = 0.f; cst1[256 + n] = efpb[n];
        } else if (id2 == 258) {       // cs2-k
            int n = t; float cs = 0.f, ct = 0.f;
            for (int k = 0; k < 256; k++) {
                float w = wk[k * 256 + n];
                cs += lngg[k] * w; ct += lngb[k] * w;
            }
            cs2[n] = cs; cst2[n] = ct + bk[n];
        } else if (id2 == 259) {       // cs2-v
            int n = t; float cs = 0.f, ct = 0.f;
            for (int k = 0; k < 256; k++) {
                float w = wv[k * 256 + n];
                cs += lngg[k] * w; ct += lngb[k] * w;
            }
            cs2[256 + n] = cs; cst2[256 + n] = ct + bv[n];
        } else {                       // id2 == 260: BN constants
            int n = t;
            float s = bng[n] * rsqrtf(bnv[n] + EPS);
            scv[n] = s;
            shv[n] = (outcb[n] - bnm[n]) * s + bnb[n];
        }
    }
}

// ---------------- MFMA GEMM core (m97-style, 128x128) -----------------------
template<int K>
__device__ __forceinline__ void mfma_core(
    const unsigned short* __restrict__ A, const unsigned short* __restrict__ Bt,
    int m0, int n0, unsigned short* As, unsigned short* Bs, f32x4 acc[4][4])
{
    const int tid = threadIdx.x;
    const int wave = tid >> 6, lane = tid & 63;
    const int wm = (wave & 1) * 64, wn = (wave >> 1) * 64;
#pragma unroll
    for (int i = 0; i < 4; i++)
#pragma unroll
        for (int j = 0; j < 4; j++) acc[i][j] = (f32x4){0.f, 0.f, 0.f, 0.f};

    const int srow = wave * 32 + (lane >> 3);
    const int sg = (lane & 7) ^ ((lane >> 3) & 7);
    const unsigned short* ga = A + (size_t)(m0 + srow) * K + sg * 8;
    const unsigned short* gb = Bt + (size_t)(n0 + srow) * K + sg * 8;

    for (int k0 = 0; k0 < K; k0 += 64) {
#pragma unroll
        for (int t = 0; t < 4; t++) {
            async16(As + (wave * 32 + t * 8) * 64, ga + (size_t)t * 8 * K + k0);
            async16(Bs + (wave * 32 + t * 8) * 64, gb + (size_t)t * 8 * K + k0);
        }
        __syncthreads();
#pragma unroll
        for (int ks = 0; ks < 2; ks++) {
            bf16x8 af[4], bfr[4];
            int kb = ks * 4 + (lane >> 4);
            int slot = (kb ^ (lane & 7)) * 8;
#pragma unroll
            for (int i = 0; i < 4; i++) {
                int m = wm + i * 16 + (lane & 15);
                af[i] = *(const bf16x8*)&As[m * 64 + slot];
                int n = wn + i * 16 + (lane & 15);
                bfr[i] = *(const bf16x8*)&Bs[n * 64 + slot];
            }
#pragma unroll
            for (int i = 0; i < 4; i++)
#pragma unroll
                for (int j = 0; j < 4; j++)
                    acc[i][j] = __builtin_amdgcn_mfma_f32_16x16x32_bf16(
                        af[i], bfr[j], acc[i][j], 0, 0, 0);
        }
        __syncthreads();
    }
}

// ---- merged projection GEMMs: blocks 0..511 = gemm1 (ef_bf x Wb1t ->
//      q|efp, 128m x 256n, LN prologue); blocks 512..1023 = gemm2k
//      (eg_bf x Wb2t -> kfull, 128m x 128n, LN prologue). Bodies r3-verbatim.
__global__ __launch_bounds__(256, 2) void gemm_proj(
    const unsigned short* __restrict__ ef_bf, const unsigned short* __restrict__ Wb1t,
    const float* __restrict__ cs1, const float* __restrict__ cst1,
    const float* __restrict__ pf, const float* __restrict__ pfq,
    unsigned short* __restrict__ qbuf, unsigned short* __restrict__ efpbuf,
    const unsigned short* __restrict__ eg_bf, const unsigned short* __restrict__ Wb2t,
    const float* __restrict__ cs2, const float* __restrict__ cst2,
    const float* __restrict__ pg, const float* __restrict__ pgq,
    float* __restrict__ mg, float* __restrict__ rg,
    unsigned short* __restrict__ kfull)
{
    __shared__ unsigned short As[128 * 64];   // 16 KB
    __shared__ unsigned short Bs[256 * 64];   // 32 KB (gemm2k uses first half)
    __shared__ float sstat[256];              // mean[128] | rstd[128]
    const int tid = threadIdx.x;
    const int wave = tid >> 6, lane = tid & 63;
    const int bid = blockIdx.x;

    if (bid < 512) {
        // ------------------------- gemm1 path -------------------------
        const int m0 = (bid >> 1) * 128, n0 = (bid & 1) * 256;
        const int wm = (wave & 1) * 64, wn = (wave >> 1) * 128;
        f32x4 acc[4][8];

        if (tid < 128) {                      // LN finalize for this block's rows
            int gm = m0 + tid;
            float s = 0.f, q = 0.f;
#pragma unroll
            for (int i = 0; i < 8; i++) { s += pf[i * 32768 + gm]; q += pfq[i * 32768 + gm]; }
            float m = s * (1.f / 512.f);
            sstat[tid] = m;
            sstat[128 + tid] = rsqrtf(q * (1.f / 512.f) - m * m + EPS);
        }

#pragma unroll
        for (int i = 0; i < 4; i++)
#pragma unroll
            for (int j = 0; j < 8; j++) acc[i][j] = (f32x4){0.f, 0.f, 0.f, 0.f};

        const int srow = lane >> 3;
        const int sg = (lane & 7) ^ (srow & 7);
        const unsigned short* ga = ef_bf + (size_t)(m0 + wave * 32 + srow) * 512 + sg * 8;
        const unsigned short* gb = Wb1t + (size_t)(n0 + wave * 64 + srow) * 512 + sg * 8;

        for (int k0 = 0; k0 < 512; k0 += 64) {
#pragma unroll
            for (int t = 0; t < 4; t++)
                async16(As + (wave * 32 + t * 8) * 64, ga + (size_t)t * 8 * 512 + k0);
#pragma unroll
            for (int t = 0; t < 8; t++)
                async16(Bs + (wave * 64 + t * 8) * 64, gb + (size_t)t * 8 * 512 + k0);
            __syncthreads();
#pragma unroll
            for (int ks = 0; ks < 2; ks++) {
                bf16x8 af[4], bfr[8];
                int kb = ks * 4 + (lane >> 4);
                int slot = (kb ^ (lane & 7)) * 8;
#pragma unroll
                for (int i = 0; i < 4; i++)
                    af[i] = *(const bf16x8*)&As[(wm + i * 16 + (lane & 15)) * 64 + slot];
#pragma unroll
                for (int j = 0; j < 8; j++)
                    bfr[j] = *(const bf16x8*)&Bs[(wn + j * 16 + (lane & 15)) * 64 + slot];
#pragma unroll
                for (int i = 0; i < 4; i++)
#pragma unroll
                    for (int j = 0; j < 8; j++)
                        acc[i][j] = __builtin_amdgcn_mfma_f32_16x16x32_bf16(
                            af[i], bfr[j], acc[i][j], 0, 0, 0);
            }
            __syncthreads();
        }

        bool isq = (n0 == 0);
#pragma unroll
        for (int i = 0; i < 4; i++) {
#pragma unroll
            for (int r = 0; r < 4; r++) {
                int lm = wm + i * 16 + ((lane >> 4) * 4) + r;
                int gm = m0 + lm;
                float mean = sstat[lm], rs = sstat[128 + lm];
#pragma unroll
                for (int j = 0; j < 8; j++) {
                    int nn = wn + j * 16 + (lane & 15);   // 0..255 within half
                    float v = acc[i][j][r];
                    if (isq) {
                        int n = nn;
                        float o = rs * (v - mean * cs1[n]) + cst1[n];
                        qbuf[(size_t)gm * 256 + nn] = f2bf(o);
                    } else {
                        int n = nn + 256;
                        efpbuf[(size_t)gm * 256 + nn] = f2bf(v + cst1[n]);
                    }
                }
            }
        }
    } else {
        // ------------------------- gemm2k path ------------------------
        const int j2 = bid - 512;
        const int m0 = (j2 >> 1) * 128, n0 = (j2 & 1) * 128;
        f32x4 acc[4][4];

        if (tid < 128) {
            int gm = m0 + tid;
            float s = 0.f, q = 0.f;
#pragma unroll
            for (int i = 0; i < 4; i++) { s += pg[i * 32768 + gm]; q += pgq[i * 32768 + gm]; }
            float m = s * (1.f / 256.f);
            float r = rsqrtf(q * (1.f / 256.f) - m * m + EPS);
            sstat[tid] = m; sstat[128 + tid] = r;
            if (n0 == 0) { mg[gm] = m; rg[gm] = r; }   // for pool_phase
        }

        mfma_core<256>(eg_bf, Wb2t, m0, n0, As, Bs, acc);
        int wm = (wave & 1) * 64, wn = (wave >> 1) * 64;
#pragma unroll
        for (int i = 0; i < 4; i++) {
#pragma unroll
            for (int r = 0; r < 4; r++) {
                int lm = wm + i * 16 + ((lane >> 4) * 4) + r;
                int gm = m0 + lm;
                float mean = sstat[lm], rs = sstat[128 + lm];
#pragma unroll
                for (int j = 0; j < 4; j++) {
                    int n = n0 + wn + j * 16 + (lane & 15);
                    float o = rs * (acc[i][j][r] - mean * cs2[n]) + cst2[n];
                    kfull[(size_t)gm * 256 + n] = f2bf(o);
                }
            }
        }
    }
}

// ------ pool phase: blocks 0..127 k-maxpool; 128..639 weighted v-pool -------
__global__ __launch_bounds__(256) void pool_phase(
    const unsigned short* __restrict__ kfull, const float* __restrict__ eg,
    const float* __restrict__ rg, const float* __restrict__ mg,
    unsigned short* __restrict__ kpb, float* __restrict__ s1,
    float* __restrict__ s0)
{
    __shared__ float smem[4352];
    int id = blockIdx.x;
    int t = threadIdx.x;
    if (id < 128) {
        // ---- k max pool: (b, cell) ----
        int b = id >> 4, cell = id & 15;
        int hp = cell >> 2, wp = cell & 3;
        int g8 = t & 31, rr = t >> 5;
        float kmx[8];
#pragma unroll
        for (int j = 0; j < 8; j++) kmx[j] = -3.402823466e38f;
#pragma unroll
        for (int rsub = 0; rsub < 2; rsub++) {
            int r = rr * 2 + rsub;
            int prow = (hp * 16 + r) * 64 + wp * 16;
            for (int cl = 0; cl < 16; cl++) {
                size_t basei = ((size_t)(b * 4096 + prow + cl)) * 256 + g8 * 8;
                uint4 kv = *(const uint4*)(kfull + basei);
                kmx[0] = fmaxf(kmx[0], lof(kv.x)); kmx[1] = fmaxf(kmx[1], hif(kv.x));
                kmx[2] = fmaxf(kmx[2], lof(kv.y)); kmx[3] = fmaxf(kmx[3], hif(kv.y));
                kmx[4] = fmaxf(kmx[4], lof(kv.z)); kmx[5] = fmaxf(kmx[5], hif(kv.z));
                kmx[6] = fmaxf(kmx[6], lof(kv.w)); kmx[7] = fmaxf(kmx[7], hif(kv.w));
            }
        }
#pragma unroll
        for (int j = 0; j < 8; j++) smem[rr * 256 + g8 * 8 + j] = kmx[j];
        __syncthreads();
        float m = smem[t];
#pragma unroll
        for (int r2 = 1; r2 < 8; r2++) m = fmaxf(m, smem[r2 * 256 + t]);
        kpb[(size_t)(b * 16 + cell) * 256 + t] = f2bf(m);   // lossless
    } else {
        // ---- weighted v-pool partials: (b, hp, cgrp) ----
        int id2 = id - 128;
        int b = id2 >> 6, hp = (id2 >> 4) & 3, cgrp = id2 & 15;
        int rr = t >> 4, cq = t & 15, cx = cq >> 2;
        int p = (hp * 16 + rr) * 64 + cq * 4;
        float4 w4 = *(const float4*)&rg[b * 4096 + p];
        float part[16];
        const float* egb = eg + ((size_t)b * 256 + cgrp * 16) * 4096 + p;
#pragma unroll
        for (int cc = 0; cc < 16; cc++) {
            float4 v4 = *(const float4*)(egb + (size_t)cc * 4096);
            part[cc] = w4.x * v4.x + w4.y * v4.y + w4.z * v4.z + w4.w * v4.w;
        }
#pragma unroll
        for (int cc = 0; cc < 16; cc++) smem[t * 16 + cc] = part[cc];
        if (cgrp == 0) {
            float4 m4 = *(const float4*)&mg[b * 4096 + p];
            smem[4096 + t] = w4.x * m4.x + w4.y * m4.y + w4.z * m4.z + w4.w * m4.w;
        }
        __syncthreads();
        if (t < 64) {
            int cx2 = t >> 4, cc = t & 15;
            float sacc = 0.f;
#pragma unroll
            for (int rr2 = 0; rr2 < 16; rr2++)
#pragma unroll
                for (int dq = 0; dq < 4; dq++)
                    sacc += smem[(rr2 * 16 + cx2 * 4 + dq) * 16 + cc];
            s1[((size_t)(b * 16 + hp * 4 + cx2)) * 256 + cgrp * 16 + cc] = sacc;
        }
        if (cgrp == 0 && t < 4) {
            float sacc = 0.f;
#pragma unroll
            for (int rr2 = 0; rr2 < 16; rr2++)
#pragma unroll
                for (int dq = 0; dq < 4; dq++)
                    sacc += smem[4096 + rr2 * 16 + t * 4 + dq];
            s0[b * 16 + hp * 4 + t] = sacc;
        }
    }
}

// ------- v-pool mini-GEMM: vp[cell][n] from s1/s0 (fp32, exact path) --------
__global__ __launch_bounds__(256) void vpool_gemm(
    const float* __restrict__ s1, const float* __restrict__ s0,
    const float* __restrict__ lngg, const float* __restrict__ wv,
    const float* __restrict__ cs2, const float* __restrict__ cst2,
    float* __restrict__ vp)
{
    int cell = blockIdx.x;        // 0..127 = b*16+cell
    int n = threadIdx.x;
    const float* s1r = s1 + (size_t)cell * 256;
    float acc = 0.f;
    for (int c = 0; c < 256; c++)
        acc = fmaf(lngg[c] * s1r[c], wv[c * 256 + n], acc);
    vp[(size_t)cell * 256 + n] = acc * (1.f / 256.f)
        - (s0[cell] * (1.f / 256.f)) * cs2[256 + n] + cst2[256 + n];
}

// ---- combined = attn@vp + dw3x3(q): scores fused, no global attns ----------
// Block: 16 consecutive positions (same image row). Wave 0: MFMA scores ->
// softmax -> LDS. Then all 4 waves x 4 positions: a_i + depthwise conv.
__global__ __launch_bounds__(256) void combined_dw(
    const unsigned short* __restrict__ qbuf, const unsigned short* __restrict__ kpb,
    const float* __restrict__ vp, const float* __restrict__ dwt,
    unsigned short* __restrict__ combined)
{
    __shared__ float attns[256];          // 16 pos x 16 cells
    int wave = threadIdx.x >> 6, lane = threadIdx.x & 63;
    int id = blockIdx.x;                  // 2048
    int b = id & 7, seg = id >> 3;        // batch pinned per XCD
    int pidx0 = seg * 16;

    if (wave == 0) {
        int fr = lane & 15, quad = lane >> 4;
        const unsigned short* qrow = qbuf + (size_t)(b * 4096 + pidx0 + fr) * 256 + quad * 8;
        const unsigned short* krow = kpb + (size_t)(b * 16 + fr) * 256 + quad * 8;
        f32x4 sacc = {0.f, 0.f, 0.f, 0.f};
#pragma unroll
        for (int ks = 0; ks < 8; ks++) {
            bf16x8 af = *(const bf16x8*)(qrow + ks * 32);
            bf16x8 bf_ = *(const bf16x8*)(krow + ks * 32);
            sacc = __builtin_amdgcn_mfma_f32_16x16x32_bf16(af, bf_, sacc, 0, 0, 0);
        }
#pragma unroll
        for (int r = 0; r < 4; r++) {
            float s = sacc[r] * 0.0625f;  // HID^-0.5
            float mx = s;
#pragma unroll
            for (int off = 8; off >= 1; off >>= 1) mx = fmaxf(mx, __shfl_xor(mx, off));
            float e = __expf(s - mx);
            float sum = e;
#pragma unroll
            for (int off = 8; off >= 1; off >>= 1) sum += __shfl_xor(sum, off);
            attns[(quad * 4 + r) * 16 + fr] = e / sum;
        }
    }
    __syncthreads();

    int pidx = pidx0 + wave * 4;
    int h = pidx >> 6, w0 = pidx & 63;
    int o4 = lane * 4;

    float4 kreg[9];
#pragma unroll
    for (int tap = 0; tap < 9; tap++)
        kreg[tap] = *(const float4*)&dwt[tap * 256 + o4];

    float4 acc[4];
#pragma unroll
    for (int i = 0; i < 4; i++) acc[i] = (float4){0.f, 0.f, 0.f, 0.f};

    const float* arow = attns + (wave * 4) * 16;
#pragma unroll
    for (int c = 0; c < 16; c++) {
        float4 v = *(const float4*)&vp[(size_t)(b * 16 + c) * 256 + o4];
#pragma unroll
        for (int i = 0; i < 4; i++) {
            float a = arow[i * 16 + c];
            acc[i].x = fmaf(a, v.x, acc[i].x); acc[i].y = fmaf(a, v.y, acc[i].y);
            acc[i].z = fmaf(a, v.z, acc[i].z); acc[i].w = fmaf(a, v.w, acc[i].w);
        }
    }
#pragma unroll
    for (int dy = 0; dy < 3; dy++) {
        int hh = h + dy - 1;
        if (hh < 0 || hh > 63) continue;
        const unsigned short* qr = qbuf + ((size_t)(b * 4096 + hh * 64)) * 256;
        float4 ft[6];
#pragma unroll
        for (int c = 0; c < 6; c++) {
            int xx = w0 - 1 + c;
            if (xx < 0 || xx > 63) {
                ft[c] = (float4){0.f, 0.f, 0.f, 0.f};
            } else {
                uint2 qa = *(const uint2*)(qr + (size_t)xx * 256 + o4);
                ft[c] = (float4){lof(qa.x), hif(qa.x), lof(qa.y), hif(qa.y)};
            }
        }
#pragma unroll
        for (int dx = 0; dx < 3; dx++) {
            float4 kk = kreg[dy * 3 + dx];
#pragma unroll
            for (int i = 0; i < 4; i++) {
                float4 qv = ft[i + dx];
                acc[i].x = fmaf(qv.x, kk.x, acc[i].x);
                acc[i].y = fmaf(qv.y, kk.y, acc[i].y);
                acc[i].z = fmaf(qv.z, kk.z, acc[i].z);
                acc[i].w = fmaf(qv.w, kk.w, acc[i].w);
            }
        }
    }
#pragma unroll
    for (int i = 0; i < 4; i++) {
        uint2 pk;
        pk.x = (unsigned)f2bf(acc[i].x) | ((unsigned)f2bf(acc[i].y) << 16);
        pk.y = (unsigned)f2bf(acc[i].z) | ((unsigned)f2bf(acc[i].w) << 16);
        *(uint2*)(combined + ((size_t)(b * 4096 + pidx + i)) * 256 + o4) = pk;
    }
}

// ------ GEMM3+4 fused: comb x Wot -> +bo, gate(efp) -> ea in LDS;
//        then Woc x ea^T -> out NCHW with BN+ReLU. 64 pos x 256 per block. ---
__global__ __launch_bounds__(256) void gemm34_mfma(
    const unsigned short* __restrict__ comb, const unsigned short* __restrict__ Wot,
    const float* __restrict__ bo, const unsigned short* __restrict__ efp,
    const unsigned short* __restrict__ Woc,
    const float* __restrict__ scv, const float* __restrict__ shv,
    float* __restrict__ outp)
{
    __shared__ unsigned short As[64 * 64];    // 8 KB  : phase1 A (64 pos x 64 k)
    __shared__ unsigned short Bs[256 * 64];   // 32 KB : phase1 Wot / phase2 Woc
    __shared__ unsigned short eat[64 * 256];  // 32 KB : gated ea tile (swizzled)
    const int tid = threadIdx.x;
    const int wave = tid >> 6, lane = tid & 63;
    const int m0 = blockIdx.x * 64;

    const int srow = lane >> 3;               // 0..7
    const int sg = (lane & 7) ^ (srow & 7);   // pre-swizzled k-chunk (m173)

    // ---- phase 1: comb[m0..m0+63][:] x Wot -> acc (wave n-split wn=wave*64) -
    f32x4 acc[4][4];
#pragma unroll
    for (int i = 0; i < 4; i++)
#pragma unroll
        for (int j = 0; j < 4; j++) acc[i][j] = (f32x4){0.f, 0.f, 0.f, 0.f};

    const unsigned short* ga = comb + (size_t)(m0 + wave * 16 + srow) * 256 + sg * 8;
    const unsigned short* gb = Wot + (size_t)(wave * 64 + srow) * 256 + sg * 8;

    for (int k0 = 0; k0 < 256; k0 += 64) {
#pragma unroll
        for (int t = 0; t < 2; t++)
            async16(As + (wave * 16 + t * 8) * 64, ga + (size_t)t * 8 * 256 + k0);
#pragma unroll
        for (int t = 0; t < 8; t++)
            async16(Bs + (wave * 64 + t * 8) * 64, gb + (size_t)t * 8 * 256 + k0);
        __syncthreads();
#pragma unroll
        for (int ks = 0; ks < 2; ks++) {
            bf16x8 af[4], bfr[4];
            int kb = ks * 4 + (lane >> 4);
            int slot = (kb ^ (lane & 7)) * 8;
#pragma unroll
            for (int i = 0; i < 4; i++) {
                af[i]  = *(const bf16x8*)&As[(i * 16 + (lane & 15)) * 64 + slot];
                bfr[i] = *(const bf16x8*)&Bs[(wave * 64 + i * 16 + (lane & 15)) * 64 + slot];
            }
#pragma unroll
            for (int i = 0; i < 4; i++)
#pragma unroll
                for (int j = 0; j < 4; j++)
                    acc[i][j] = __builtin_amdgcn_mfma_f32_16x16x32_bf16(
                        af[i], bfr[j], acc[i][j], 0, 0, 0);
        }
        __syncthreads();
    }

    // ---- epilogue: +bo, gate by efp, bf16 -> eat (chunk-slot swizzled) ------
    float bo4[4];
#pragma unroll
    for (int j = 0; j < 4; j++) bo4[j] = bo[wave * 64 + j * 16 + (lane & 15)];
#pragma unroll
    for (int i = 0; i < 4; i++) {
#pragma unroll
        for (int r = 0; r < 4; r++) {
            int pos = i * 16 + ((lane >> 4) * 4) + r;
#pragma unroll
            for (int j = 0; j < 4; j++) {
                int n = wave * 64 + j * 16 + (lane & 15);
                float o = (acc[i][j][r] + bo4[j])
                          * bf2f(efp[(size_t)(m0 + pos) * 256 + n]);
                int o8 = j * 2 + ((lane >> 3) & 1);       // k-octet in chunk
                int slot = o8 ^ (pos & 7);
                eat[pos * 256 + wave * 64 + slot * 8 + (lane & 7)] = f2bf(o);
            }
        }
    }

    // ---- phase 2: Woc x eat^T -> out (wave co-split, co = wave*64 + ...) ----
    f32x4 acc2[4][4];
#pragma unroll
    for (int i = 0; i < 4; i++)
#pragma unroll
        for (int j = 0; j < 4; j++) acc2[i][j] = (f32x4){0.f, 0.f, 0.f, 0.f};

    const unsigned short* gw = Woc + (size_t)(wave * 64 + srow) * 256 + sg * 8;
    for (int k0 = 0; k0 < 256; k0 += 64) {
#pragma unroll
        for (int t = 0; t < 8; t++)
            async16(Bs + (wave * 64 + t * 8) * 64, gw + (size_t)t * 8 * 256 + k0);
        __syncthreads();
        int kc = k0 >> 6;
#pragma unroll
        for (int ks = 0; ks < 2; ks++) {
            bf16x8 af2[4], bf2_[4];
            int kb = ks * 4 + (lane >> 4);
            int slot = (kb ^ (lane & 7)) * 8;
#pragma unroll
            for (int i = 0; i < 4; i++) {
                af2[i]  = *(const bf16x8*)&Bs[(wave * 64 + i * 16 + (lane & 15)) * 64 + slot];
                bf2_[i] = *(const bf16x8*)&eat[(i * 16 + (lane & 15)) * 256 + kc * 64 + slot];
            }
#pragma unroll
            for (int i = 0; i < 4; i++)
#pragma unroll
                for (int j = 0; j < 4; j++)
                    acc2[i][j] = __builtin_amdgcn_mfma_f32_16x16x32_bf16(
                        af2[i], bf2_[j], acc2[i][j], 0, 0, 0);
        }
        __syncthreads();
    }

    // ---- BN + ReLU, store NCHW -----------------------------------------------
#pragma unroll
    for (int i = 0; i < 4; i++) {
#pragma unroll
        for (int r = 0; r < 4; r++) {
            int co = wave * 64 + i * 16 + ((lane >> 4) * 4) + r;
            float s = scv[co], hh = shv[co];
#pragma unroll
            for (int j = 0; j < 4; j++) {
                int p = m0 + j * 16 + (lane & 15);
                float o = fmaxf(fmaf(acc2[i][j][r], s, hh), 0.f);
                outp[((size_t)(p >> 12)) * 1048576 + (size_t)co * 4096 + (p & 4095)] = o;
            }
        }
    }
}

// ---------------------------------------------------------------------------
extern "C" void kernel_launch(void* const* d_in, const int* in_sizes, int n_in,
                              void* d_out, int out_size, void* d_ws, size_t ws_size,
                              hipStream_t stream)
{
    const float* e_f   = (const float*)d_in[0];
    const float* e_g   = (const float*)d_in[1];
    const float* lnfg  = (const float*)d_in[4];
    const float* lnfb  = (const float*)d_in[5];
    const float* lngg  = (const float*)d_in[6];
    const float* lngb  = (const float*)d_in[7];
    const float* wq    = (const float*)d_in[8];
    const float* bq    = (const float*)d_in[9];
    const float* wk    = (const float*)d_in[10];
    const float* bk    = (const float*)d_in[11];
    const float* wv    = (const float*)d_in[12];
    const float* bv    = (const float*)d_in[13];
    const float* wo    = (const float*)d_in[14];
    const float* bo    = (const float*)d_in[15];
    const float* dwk   = (const float*)d_in[16];
    const float* efpw  = (const float*)d_in[17];
    const float* efpb  = (const float*)d_in[18];
    const float* outcw = (const float*)d_in[19];
    const float* outcb = (const float*)d_in[20];
    const float* bng   = (const float*)d_in[21];
    const float* bnb   = (const float*)d_in[22];
    const float* bnm   = (const float*)d_in[23];
    const float* bnv   = (const float*)d_in[24];
    float* outp = (float*)d_out;

    char* base = (char*)d_ws;
    auto alloc = [&](size_t bytes) -> char* {
        char* r = base; base += (bytes + 255) & ~(size_t)255; return r;
    };
    float* pf    = (float*)alloc(8 * 32768 * 4);
    float* pfq   = (float*)alloc(8 * 32768 * 4);
    float* pg    = (float*)alloc(4 * 32768 * 4);
    float* pgq   = (float*)alloc(4 * 32768 * 4);
    float* mg    = (float*)alloc(32768 * 4);
    float* rg    = (float*)alloc(32768 * 4);
    float* cs1   = (float*)alloc(512 * 4);
    float* cst1  = (float*)alloc(512 * 4);
    float* cs2   = (float*)alloc(512 * 4);
    float* cst2  = (float*)alloc(512 * 4);
    float* scv   = (float*)alloc(256 * 4);
    float* shv   = (float*)alloc(256 * 4);
    float* dwt   = (float*)alloc(9 * 256 * 4);
    unsigned short* Wb1t = (unsigned short*)alloc(262144 * 2);
    unsigned short* Wb2t = (unsigned short*)alloc(65536 * 2);
    unsigned short* Wot  = (unsigned short*)alloc(65536 * 2);
    unsigned short* Woc  = (unsigned short*)alloc(65536 * 2);
    unsigned short* ef_bf = (unsigned short*)alloc((size_t)32768 * 512 * 2);
    unsigned short* eg_bf = (unsigned short*)alloc((size_t)32768 * 256 * 2);
    unsigned short* qbuf  = (unsigned short*)alloc((size_t)32768 * 256 * 2);
    unsigned short* efpbuf = (unsigned short*)alloc((size_t)32768 * 256 * 2);
    unsigned short* kfull = (unsigned short*)alloc((size_t)32768 * 256 * 2); // -> combined
    unsigned short* kpb  = (unsigned short*)alloc(128 * 256 * 2);
    float* vp    = (float*)alloc(128 * 256 * 4);
    float* s1    = (float*)alloc(128 * 256 * 4);
    float* s0    = (float*)alloc(128 * 4);

    trans_prep<<<3333, 256, 0, stream>>>(
        e_f, e_g, ef_bf, eg_bf, pf, pfq, pg, pgq,
        lnfg, lnfb, wq, bq, efpw, efpb, lngg, lngb, wk, bk, wv, bv, wo,
        outcw, outcb, bng, bnb, bnm, bnv, dwk,
        Wb1t, Wb2t, Wot, Woc, dwt, cs1, cst1, cs2, cst2, scv, shv);
    gemm_proj<<<1024, 256, 0, stream>>>(
        ef_bf, Wb1t, cs1, cst1, pf, pfq, qbuf, efpbuf,
        eg_bf, Wb2t, cs2, cst2, pg, pgq, mg, rg, kfull);
    pool_phase<<<640, 256, 0, stream>>>(kfull, e_g, rg, mg, kpb, s1, s0);
    vpool_gemm<<<128, 256, 0, stream>>>(s1, s0, lngg, wv, cs2, cst2, vp);
    combined_dw<<<2048, 256, 0, stream>>>(qbuf, kpb, vp, dwt, /*combined=*/kfull);
    gemm34_mfma<<<512, 256, 0, stream>>>(/*combined=*/kfull, Wot, bo, efpbuf,
                                         Woc, scv, shv, outp);
}

// Round 9
// 288.967 us; speedup vs baseline: 1.2826x; 1.0512x over previous
//
#include <hip/hip_runtime.h>
#include <math.h>

#define EPS 1e-5f

typedef __attribute__((ext_vector_type(8))) short bf16x8;
typedef __attribute__((ext_vector_type(4))) float f32x4;

__device__ __forceinline__ unsigned short f2bf(float f) {
    unsigned int u = __float_as_uint(f);
    u += 0x7fff + ((u >> 16) & 1);            // round-to-nearest-even
    return (unsigned short)(u >> 16);
}
__device__ __forceinline__ float bf2f(unsigned short h) {
    return __uint_as_float(((unsigned int)h) << 16);
}
__device__ __forceinline__ float lof(unsigned int u) {
    return __uint_as_float(u << 16);
}
__device__ __forceinline__ float hif(unsigned int u) {
    return __uint_as_float(u & 0xffff0000u);
}
__device__ __forceinline__ void async16(void* lds, const void* g) {
    __builtin_amdgcn_global_load_lds(
        (const __attribute__((address_space(1))) unsigned int*)g,
        (__attribute__((address_space(3))) unsigned int*)lds, 16, 0, 0);
}

// ---- merged: NCHW->bf16 transpose + LN partials (blocks 0..3071)
//      and weight-prep (blocks 3072..; constants k-parallelized, no straggler)
__global__ __launch_bounds__(256) void trans_prep(
    const float* __restrict__ ef, const float* __restrict__ eg,
    unsigned short* __restrict__ ef_bf, unsigned short* __restrict__ eg_bf,
    float* __restrict__ pf, float* __restrict__ pfq,
    float* __restrict__ pg, float* __restrict__ pgq,
    const float* __restrict__ lnfg, const float* __restrict__ lnfb,
    const float* __restrict__ wq, const float* __restrict__ bq,
    const float* __restrict__ efpw, const float* __restrict__ efpb,
    const float* __restrict__ lngg, const float* __restrict__ lngb,
    const float* __restrict__ wk, const float* __restrict__ bk,
    const float* __restrict__ wv, const float* __restrict__ bv,
    const float* __restrict__ wo, const float* __restrict__ outcw,
    const float* __restrict__ outcb, const float* __restrict__ bng,
    const float* __restrict__ bnb, const float* __restrict__ bnm,
    const float* __restrict__ bnv, const float* __restrict__ dwk,
    unsigned short* __restrict__ Wb1t, unsigned short* __restrict__ Wb2t,
    unsigned short* __restrict__ Wot, unsigned short* __restrict__ Woc,
    float* __restrict__ dwt,
    float* __restrict__ cs1, float* __restrict__ cst1,
    float* __restrict__ cs2, float* __restrict__ cst2,
    float* __restrict__ scv, float* __restrict__ shv)
{
    __shared__ float tile[64][65];
    __shared__ float psum[4][64], pss[4][64];
    int id = blockIdx.x;
    int t = threadIdx.x;
    if (id < 3072) {
        // ---------------- transpose path (r3 verbatim) ----------------
        const float* src; unsigned short* dst; float* ps; float* pq;
        int C, cblk, b, p0;
        if (id < 2048) {                          // e_f: 8b x 8cblk x 32ptile
            src = ef; dst = ef_bf; ps = pf; pq = pfq; C = 512;
            b = id >> 8; cblk = (id >> 5) & 7; p0 = (id & 31) * 128;
        } else {                                  // e_g: 8b x 4cblk x 32ptile
            id -= 2048;
            src = eg; dst = eg_bf; ps = pg; pq = pgq; C = 256;
            b = id >> 7; cblk = (id >> 5) & 3; p0 = (id & 31) * 128;
        }
        int c0 = cblk * 64;
        const float* s = src + ((size_t)b * C + c0) * 4096 + p0;
        int cr = t >> 4, p4 = (t & 15) * 4;
        int lane = t & 63, grp = t >> 6;
        int pr = t >> 3, c8 = (t & 7) * 8;

        float4 r1[4], r2[4];
#pragma unroll
        for (int i = 0; i < 4; i++)
            r1[i] = *(const float4*)(s + (size_t)(i * 16 + cr) * 4096 + p4);
#pragma unroll
        for (int i = 0; i < 4; i++)
            r2[i] = *(const float4*)(s + (size_t)(i * 16 + cr) * 4096 + 64 + p4);

#pragma unroll
        for (int half = 0; half < 2; half++) {
#pragma unroll
            for (int i = 0; i < 4; i++) {
                float4 v = half ? r2[i] : r1[i];
                int c = i * 16 + cr;
                tile[c][p4 + 0] = v.x; tile[c][p4 + 1] = v.y;
                tile[c][p4 + 2] = v.z; tile[c][p4 + 3] = v.w;
            }
            __syncthreads();

            int pbase = p0 + half * 64;
            unsigned short* d = dst + ((size_t)(b * 4096 + pbase)) * C + c0;
#pragma unroll
            for (int i = 0; i < 2; i++) {
                int p = i * 32 + pr;
                uint4 pk;
                pk.x = (unsigned)f2bf(tile[c8 + 0][p]) | ((unsigned)f2bf(tile[c8 + 1][p]) << 16);
                pk.y = (unsigned)f2bf(tile[c8 + 2][p]) | ((unsigned)f2bf(tile[c8 + 3][p]) << 16);
                pk.z = (unsigned)f2bf(tile[c8 + 4][p]) | ((unsigned)f2bf(tile[c8 + 5][p]) << 16);
                pk.w = (unsigned)f2bf(tile[c8 + 6][p]) | ((unsigned)f2bf(tile[c8 + 7][p]) << 16);
                *(uint4*)(d + (size_t)p * C + c8) = pk;
            }

            float sm = 0.f, sq = 0.f;
#pragma unroll
            for (int j = 0; j < 16; j++) {
                float v = tile[grp * 16 + j][lane];
                sm += v; sq += v * v;
            }
            psum[grp][lane] = sm; pss[grp][lane] = sq;
            __syncthreads();
            if (t < 64) {
                float fs = psum[0][t] + psum[1][t] + psum[2][t] + psum[3][t];
                float fq = pss[0][t] + pss[1][t] + pss[2][t] + pss[3][t];
                ps[cblk * 32768 + b * 4096 + pbase + t] = fs;
                pq[cblk * 32768 + b * 4096 + pbase + t] = fq;
            }
            if (half == 0) __syncthreads();       // tile reuse fence
        }
    } else {
        int id2 = id - 3072;
        float* red1 = (float*)psum;               // 256-float scratch
        float* red2 = (float*)pss;
        if (id2 < 64) {
            // -- LDS-tiled 64x64 weight transpose (coalesced both sides) --
            const float* src; unsigned short* dst; const float* scale;
            int K, k0, n0;
            if (id2 < 32) {            // Wb1t-q: wq[512][256] -> [n<256][512]
                src = wq; dst = Wb1t; scale = lnfg; K = 512;
                k0 = (id2 >> 2) * 64; n0 = (id2 & 3) * 64;
            } else if (id2 < 48) {     // Wb2t: wk[256][256] -> [n][256]
                int j = id2 - 32;
                src = wk; dst = Wb2t; scale = lngg; K = 256;
                k0 = (j >> 2) * 64; n0 = (j & 3) * 64;
            } else {                   // Wot: wo[256][256] -> [n][256]
                int j = id2 - 48;
                src = wo; dst = Wot; scale = nullptr; K = 256;
                k0 = (j >> 2) * 64; n0 = (j & 3) * 64;
            }
            int rr = t >> 6, cc = t & 63;
#pragma unroll
            for (int i = 0; i < 16; i++) {
                int r = i * 4 + rr;
                tile[r][cc] = src[(size_t)(k0 + r) * 256 + n0 + cc];
            }
            __syncthreads();
            int nn = t >> 3, k8 = (t & 7) * 8;
#pragma unroll
            for (int i = 0; i < 2; i++) {
                int n = i * 32 + nn;
                float v[8];
#pragma unroll
                for (int j = 0; j < 8; j++) {
                    float s = scale ? scale[k0 + k8 + j] : 1.f;
                    v[j] = s * tile[k8 + j][n];
                }
                uint4 pk;
                pk.x = (unsigned)f2bf(v[0]) | ((unsigned)f2bf(v[1]) << 16);
                pk.y = (unsigned)f2bf(v[2]) | ((unsigned)f2bf(v[3]) << 16);
                pk.z = (unsigned)f2bf(v[4]) | ((unsigned)f2bf(v[5]) << 16);
                pk.w = (unsigned)f2bf(v[6]) | ((unsigned)f2bf(v[7]) << 16);
                *(uint4*)(dst + (size_t)(n0 + n) * K + k0 + k8) = pk;
            }
        } else if (id2 < 192) {        // Wb1t-efp half: row-major copy-convert
            int j = (id2 - 64) * 1024 + t * 4;
            float4 v = *(const float4*)(efpw + j);
            uint2 pk;
            pk.x = (unsigned)f2bf(v.x) | ((unsigned)f2bf(v.y) << 16);
            pk.y = (unsigned)f2bf(v.z) | ((unsigned)f2bf(v.w) << 16);
            *(uint2*)(Wb1t + 131072 + j) = pk;
        } else if (id2 < 256) {        // Woc copy-convert
            int j = (id2 - 192) * 1024 + t * 4;
            float4 v = *(const float4*)(outcw + j);
            uint2 pk;
            pk.x = (unsigned)f2bf(v.x) | ((unsigned)f2bf(v.y) << 16);
            pk.y = (unsigned)f2bf(v.z) | ((unsigned)f2bf(v.w) << 16);
            *(uint2*)(Woc + j) = pk;
        } else if (id2 == 256) {       // dwt [tap][ch]
#pragma unroll
            for (int tap = 0; tap < 9; tap++)
                dwt[tap * 256 + t] = dwk[t * 9 + tap];
        } else if (id2 < 265) {        // cs1/cst1: 8 blocks x 32 n, k-parallel
            int n0 = (id2 - 257) * 32;
            int nl = t & 31, kq = t >> 5;         // 8 k-groups of 64
            float cs = 0.f, ct = 0.f;
#pragma unroll 4
            for (int kk = 0; kk < 64; kk++) {
                int k = kq * 64 + kk;
                float w = wq[k * 256 + n0 + nl];
                cs += lnfg[k] * w; ct += lnfb[k] * w;
            }
            red1[kq * 32 + nl] = cs; red2[kq * 32 + nl] = ct;
            __syncthreads();
            if (t < 32) {
                float s = 0.f, c2 = 0.f;
#pragma unroll
                for (int q = 0; q < 8; q++) { s += red1[q * 32 + t]; c2 += red2[q * 32 + t]; }
                int n = n0 + t;
                cs1[n] = s; cst1[n] = c2 + bq[n];
                cs1[256 + n] = 0.f; cst1[256 + n] = efpb[n];
            }
        } else if (id2 < 273) {        // cs2-k: 8 blocks x 32 n, k-parallel
            int n0 = (id2 - 265) * 32;
            int nl = t & 31, kq = t >> 5;         // 8 k-groups of 32
            float cs = 0.f, ct = 0.f;
#pragma unroll 4
            for (int kk = 0; kk < 32; kk++) {
                int k = kq * 32 + kk;
                float w = wk[k * 256 + n0 + nl];
                cs += lngg[k] * w; ct += lngb[k] * w;
            }
            red1[kq * 32 + nl] = cs; red2[kq * 32 + nl] = ct;
            __syncthreads();
            if (t < 32) {
                float s = 0.f, c2 = 0.f;
#pragma unroll
                for (int q = 0; q < 8; q++) { s += red1[q * 32 + t]; c2 += red2[q * 32 + t]; }
                int n = n0 + t;
                cs2[n] = s; cst2[n] = c2 + bk[n];
            }
        } else if (id2 < 281) {        // cs2-v: 8 blocks x 32 n, k-parallel
            int n0 = (id2 - 273) * 32;
            int nl = t & 31, kq = t >> 5;
            float cs = 0.f, ct = 0.f;
#pragma unroll 4
            for (int kk = 0; kk < 32; kk++) {
                int k = kq * 32 + kk;
                float w = wv[k * 256 + n0 + nl];
                cs += lngg[k] * w; ct += lngb[k] * w;
            }
            red1[kq * 32 + nl] = cs; red2[kq * 32 + nl] = ct;
            __syncthreads();
            if (t < 32) {
                float s = 0.f, c2 = 0.f;
#pragma unroll
                for (int q = 0; q < 8; q++) { s += red1[q * 32 + t]; c2 += red2[q * 32 + t]; }
                int n = n0 + t;
                cs2[256 + n] = s; cst2[256 + n] = c2 + bv[n];
            }
        } else {                       // id2 == 281: BN constants
            int n = t;
            float s = bng[n] * rsqrtf(bnv[n] + EPS);
            scv[n] = s;
            shv[n] = (outcb[n] - bnm[n]) * s + bnb[n];
        }
    }
}

// ---------------- MFMA GEMM core (m97-style, 128x128) -----------------------
template<int K>
__device__ __forceinline__ void mfma_core(
    const unsigned short* __restrict__ A, const unsigned short* __restrict__ Bt,
    int m0, int n0, unsigned short* As, unsigned short* Bs, f32x4 acc[4][4])
{
    const int tid = threadIdx.x;
    const int wave = tid >> 6, lane = tid & 63;
    const int wm = (wave & 1) * 64, wn = (wave >> 1) * 64;
#pragma unroll
    for (int i = 0; i < 4; i++)
#pragma unroll
        for (int j = 0; j < 4; j++) acc[i][j] = (f32x4){0.f, 0.f, 0.f, 0.f};

    const int srow = wave * 32 + (lane >> 3);
    const int sg = (lane & 7) ^ ((lane >> 3) & 7);
    const unsigned short* ga = A + (size_t)(m0 + srow) * K + sg * 8;
    const unsigned short* gb = Bt + (size_t)(n0 + srow) * K + sg * 8;

    for (int k0 = 0; k0 < K; k0 += 64) {
#pragma unroll
        for (int t = 0; t < 4; t++) {
            async16(As + (wave * 32 + t * 8) * 64, ga + (size_t)t * 8 * K + k0);
            async16(Bs + (wave * 32 + t * 8) * 64, gb + (size_t)t * 8 * K + k0);
        }
        __syncthreads();
#pragma unroll
        for (int ks = 0; ks < 2; ks++) {
            bf16x8 af[4], bfr[4];
            int kb = ks * 4 + (lane >> 4);
            int slot = (kb ^ (lane & 7)) * 8;
#pragma unroll
            for (int i = 0; i < 4; i++) {
                int m = wm + i * 16 + (lane & 15);
                af[i] = *(const bf16x8*)&As[m * 64 + slot];
                int n = wn + i * 16 + (lane & 15);
                bfr[i] = *(const bf16x8*)&Bs[n * 64 + slot];
            }
#pragma unroll
            for (int i = 0; i < 4; i++)
#pragma unroll
                for (int j = 0; j < 4; j++)
                    acc[i][j] = __builtin_amdgcn_mfma_f32_16x16x32_bf16(
                        af[i], bfr[j], acc[i][j], 0, 0, 0);
        }
        __syncthreads();
    }
}

// ---- merged projection GEMMs: blocks 0..511 = gemm1 (ef_bf x Wb1t ->
//      q|efp, 128m x 256n, LN prologue); blocks 512..1023 = gemm2k
//      (eg_bf x Wb2t -> kfull, 128m x 128n, LN prologue). Bodies r3-verbatim.
__global__ __launch_bounds__(256, 2) void gemm_proj(
    const unsigned short* __restrict__ ef_bf, const unsigned short* __restrict__ Wb1t,
    const float* __restrict__ cs1, const float* __restrict__ cst1,
    const float* __restrict__ pf, const float* __restrict__ pfq,
    unsigned short* __restrict__ qbuf, unsigned short* __restrict__ efpbuf,
    const unsigned short* __restrict__ eg_bf, const unsigned short* __restrict__ Wb2t,
    const float* __restrict__ cs2, const float* __restrict__ cst2,
    const float* __restrict__ pg, const float* __restrict__ pgq,
    float* __restrict__ mg, float* __restrict__ rg,
    unsigned short* __restrict__ kfull)
{
    __shared__ unsigned short As[128 * 64];   // 16 KB
    __shared__ unsigned short Bs[256 * 64];   // 32 KB (gemm2k uses first half)
    __shared__ float sstat[256];              // mean[128] | rstd[128]
    const int tid = threadIdx.x;
    const int wave = tid >> 6, lane = tid & 63;
    const int bid = blockIdx.x;

    if (bid < 512) {
        // ------------------------- gemm1 path -------------------------
        const int m0 = (bid >> 1) * 128, n0 = (bid & 1) * 256;
        const int wm = (wave & 1) * 64, wn = (wave >> 1) * 128;
        f32x4 acc[4][8];

        if (tid < 128) {                      // LN finalize for this block's rows
            int gm = m0 + tid;
            float s = 0.f, q = 0.f;
#pragma unroll
            for (int i = 0; i < 8; i++) { s += pf[i * 32768 + gm]; q += pfq[i * 32768 + gm]; }
            float m = s * (1.f / 512.f);
            sstat[tid] = m;
            sstat[128 + tid] = rsqrtf(q * (1.f / 512.f) - m * m + EPS);
        }

#pragma unroll
        for (int i = 0; i < 4; i++)
#pragma unroll
            for (int j = 0; j < 8; j++) acc[i][j] = (f32x4){0.f, 0.f, 0.f, 0.f};

        const int srow = lane >> 3;
        const int sg = (lane & 7) ^ (srow & 7);
        const unsigned short* ga = ef_bf + (size_t)(m0 + wave * 32 + srow) * 512 + sg * 8;
        const unsigned short* gb = Wb1t + (size_t)(n0 + wave * 64 + srow) * 512 + sg * 8;

        for (int k0 = 0; k0 < 512; k0 += 64) {
#pragma unroll
            for (int t = 0; t < 4; t++)
                async16(As + (wave * 32 + t * 8) * 64, ga + (size_t)t * 8 * 512 + k0);
#pragma unroll
            for (int t = 0; t < 8; t++)
                async16(Bs + (wave * 64 + t * 8) * 64, gb + (size_t)t * 8 * 512 + k0);
            __syncthreads();
#pragma unroll
            for (int ks = 0; ks < 2; ks++) {
                bf16x8 af[4], bfr[8];
                int kb = ks * 4 + (lane >> 4);
                int slot = (kb ^ (lane & 7)) * 8;
#pragma unroll
                for (int i = 0; i < 4; i++)
                    af[i] = *(const bf16x8*)&As[(wm + i * 16 + (lane & 15)) * 64 + slot];
#pragma unroll
                for (int j = 0; j < 8; j++)
                    bfr[j] = *(const bf16x8*)&Bs[(wn + j * 16 + (lane & 15)) * 64 + slot];
#pragma unroll
                for (int i = 0; i < 4; i++)
#pragma unroll
                    for (int j = 0; j < 8; j++)
                        acc[i][j] = __builtin_amdgcn_mfma_f32_16x16x32_bf16(
                            af[i], bfr[j], acc[i][j], 0, 0, 0);
            }
            __syncthreads();
        }

        bool isq = (n0 == 0);
#pragma unroll
        for (int i = 0; i < 4; i++) {
#pragma unroll
            for (int r = 0; r < 4; r++) {
                int lm = wm + i * 16 + ((lane >> 4) * 4) + r;
                int gm = m0 + lm;
                float mean = sstat[lm], rs = sstat[128 + lm];
#pragma unroll
                for (int j = 0; j < 8; j++) {
                    int nn = wn + j * 16 + (lane & 15);   // 0..255 within half
                    float v = acc[i][j][r];
                    if (isq) {
                        int n = nn;
                        float o = rs * (v - mean * cs1[n]) + cst1[n];
                        qbuf[(size_t)gm * 256 + nn] = f2bf(o);
                    } else {
                        int n = nn + 256;
                        efpbuf[(size_t)gm * 256 + nn] = f2bf(v + cst1[n]);
                    }
                }
            }
        }
    } else {
        // ------------------------- gemm2k path ------------------------
        const int j2 = bid - 512;
        const int m0 = (j2 >> 1) * 128, n0 = (j2 & 1) * 128;
        f32x4 acc[4][4];

        if (tid < 128) {
            int gm = m0 + tid;
            float s = 0.f, q = 0.f;
#pragma unroll
            for (int i = 0; i < 4; i++) { s += pg[i * 32768 + gm]; q += pgq[i * 32768 + gm]; }
            float m = s * (1.f / 256.f);
            float r = rsqrtf(q * (1.f / 256.f) - m * m + EPS);
            sstat[tid] = m; sstat[128 + tid] = r;
            if (n0 == 0) { mg[gm] = m; rg[gm] = r; }   // for pool_phase
        }

        mfma_core<256>(eg_bf, Wb2t, m0, n0, As, Bs, acc);
        int wm = (wave & 1) * 64, wn = (wave >> 1) * 64;
#pragma unroll
        for (int i = 0; i < 4; i++) {
#pragma unroll
            for (int r = 0; r < 4; r++) {
                int lm = wm + i * 16 + ((lane >> 4) * 4) + r;
                int gm = m0 + lm;
                float mean = sstat[lm], rs = sstat[128 + lm];
#pragma unroll
                for (int j = 0; j < 4; j++) {
                    int n = n0 + wn + j * 16 + (lane & 15);
                    float o = rs * (acc[i][j][r] - mean * cs2[n]) + cst2[n];
                    kfull[(size_t)gm * 256 + n] = f2bf(o);
                }
            }
        }
    }
}

// ------ pool phase: blocks 0..127 k-maxpool; 128..639 weighted v-pool -------
__global__ __launch_bounds__(256) void pool_phase(
    const unsigned short* __restrict__ kfull, const float* __restrict__ eg,
    const float* __restrict__ rg, const float* __restrict__ mg,
    unsigned short* __restrict__ kpb, float* __restrict__ s1,
    float* __restrict__ s0)
{
    __shared__ float smem[4352];
    int id = blockIdx.x;
    int t = threadIdx.x;
    if (id < 128) {
        // ---- k max pool: (b, cell) ----
        int b = id >> 4, cell = id & 15;
        int hp = cell >> 2, wp = cell & 3;
        int g8 = t & 31, rr = t >> 5;
        float kmx[8];
#pragma unroll
        for (int j = 0; j < 8; j++) kmx[j] = -3.402823466e38f;
#pragma unroll
        for (int rsub = 0; rsub < 2; rsub++) {
            int r = rr * 2 + rsub;
            int prow = (hp * 16 + r) * 64 + wp * 16;
            for (int cl = 0; cl < 16; cl++) {
                size_t basei = ((size_t)(b * 4096 + prow + cl)) * 256 + g8 * 8;
                uint4 kv = *(const uint4*)(kfull + basei);
                kmx[0] = fmaxf(kmx[0], lof(kv.x)); kmx[1] = fmaxf(kmx[1], hif(kv.x));
                kmx[2] = fmaxf(kmx[2], lof(kv.y)); kmx[3] = fmaxf(kmx[3], hif(kv.y));
                kmx[4] = fmaxf(kmx[4], lof(kv.z)); kmx[5] = fmaxf(kmx[5], hif(kv.z));
                kmx[6] = fmaxf(kmx[6], lof(kv.w)); kmx[7] = fmaxf(kmx[7], hif(kv.w));
            }
        }
#pragma unroll
        for (int j = 0; j < 8; j++) smem[rr * 256 + g8 * 8 + j] = kmx[j];
        __syncthreads();
        float m = smem[t];
#pragma unroll
        for (int r2 = 1; r2 < 8; r2++) m = fmaxf(m, smem[r2 * 256 + t]);
        kpb[(size_t)(b * 16 + cell) * 256 + t] = f2bf(m);   // lossless
    } else {
        // ---- weighted v-pool partials: (b, hp, cgrp) ----
        int id2 = id - 128;
        int b = id2 >> 6, hp = (id2 >> 4) & 3, cgrp = id2 & 15;
        int rr = t >> 4, cq = t & 15, cx = cq >> 2;
        int p = (hp * 16 + rr) * 64 + cq * 4;
        float4 w4 = *(const float4*)&rg[b * 4096 + p];
        float part[16];
        const float* egb = eg + ((size_t)b * 256 + cgrp * 16) * 4096 + p;
#pragma unroll
        for (int cc = 0; cc < 16; cc++) {
            float4 v4 = *(const float4*)(egb + (size_t)cc * 4096);
            part[cc] = w4.x * v4.x + w4.y * v4.y + w4.z * v4.z + w4.w * v4.w;
        }
#pragma unroll
        for (int cc = 0; cc < 16; cc++) smem[t * 16 + cc] = part[cc];
        if (cgrp == 0) {
            float4 m4 = *(const float4*)&mg[b * 4096 + p];
            smem[4096 + t] = w4.x * m4.x + w4.y * m4.y + w4.z * m4.z + w4.w * m4.w;
        }
        __syncthreads();
        if (t < 64) {
            int cx2 = t >> 4, cc = t & 15;
            float sacc = 0.f;
#pragma unroll
            for (int rr2 = 0; rr2 < 16; rr2++)
#pragma unroll
                for (int dq = 0; dq < 4; dq++)
                    sacc += smem[(rr2 * 16 + cx2 * 4 + dq) * 16 + cc];
            s1[((size_t)(b * 16 + hp * 4 + cx2)) * 256 + cgrp * 16 + cc] = sacc;
        }
        if (cgrp == 0 && t < 4) {
            float sacc = 0.f;
#pragma unroll
            for (int rr2 = 0; rr2 < 16; rr2++)
#pragma unroll
                for (int dq = 0; dq < 4; dq++)
                    sacc += smem[4096 + rr2 * 16 + t * 4 + dq];
            s0[b * 16 + hp * 4 + t] = sacc;
        }
    }
}

// ------- v-pool mini-GEMM: vp[cell][n] from s1/s0 (fp32, exact path) --------
__global__ __launch_bounds__(256) void vpool_gemm(
    const float* __restrict__ s1, const float* __restrict__ s0,
    const float* __restrict__ lngg, const float* __restrict__ wv,
    const float* __restrict__ cs2, const float* __restrict__ cst2,
    float* __restrict__ vp)
{
    int cell = blockIdx.x;        // 0..127 = b*16+cell
    int n = threadIdx.x;
    const float* s1r = s1 + (size_t)cell * 256;
    float acc = 0.f;
    for (int c = 0; c < 256; c++)
        acc = fmaf(lngg[c] * s1r[c], wv[c * 256 + n], acc);
    vp[(size_t)cell * 256 + n] = acc * (1.f / 256.f)
        - (s0[cell] * (1.f / 256.f)) * cs2[256 + n] + cst2[256 + n];
}

// ---- combined = attn@vp + dw3x3(q): scores fused, no global attns ----------
// Block: 16 consecutive positions (same image row). Wave 0: MFMA scores ->
// softmax -> LDS. Then all 4 waves x 4 positions: a_i + depthwise conv.
__global__ __launch_bounds__(256) void combined_dw(
    const unsigned short* __restrict__ qbuf, const unsigned short* __restrict__ kpb,
    const float* __restrict__ vp, const float* __restrict__ dwt,
    unsigned short* __restrict__ combined)
{
    __shared__ float attns[256];          // 16 pos x 16 cells
    int wave = threadIdx.x >> 6, lane = threadIdx.x & 63;
    int id = blockIdx.x;                  // 2048
    int b = id & 7, seg = id >> 3;        // batch pinned per XCD
    int pidx0 = seg * 16;

    if (wave == 0) {
        int fr = lane & 15, quad = lane >> 4;
        const unsigned short* qrow = qbuf + (size_t)(b * 4096 + pidx0 + fr) * 256 + quad * 8;
        const unsigned short* krow = kpb + (size_t)(b * 16 + fr) * 256 + quad * 8;
        f32x4 sacc = {0.f, 0.f, 0.f, 0.f};
#pragma unroll
        for (int ks = 0; ks < 8; ks++) {
            bf16x8 af = *(const bf16x8*)(qrow + ks * 32);
            bf16x8 bf_ = *(const bf16x8*)(krow + ks * 32);
            sacc = __builtin_amdgcn_mfma_f32_16x16x32_bf16(af, bf_, sacc, 0, 0, 0);
        }
#pragma unroll
        for (int r = 0; r < 4; r++) {
            float s = sacc[r] * 0.0625f;  // HID^-0.5
            float mx = s;
#pragma unroll
            for (int off = 8; off >= 1; off >>= 1) mx = fmaxf(mx, __shfl_xor(mx, off));
            float e = __expf(s - mx);
            float sum = e;
#pragma unroll
            for (int off = 8; off >= 1; off >>= 1) sum += __shfl_xor(sum, off);
            attns[(quad * 4 + r) * 16 + fr] = e / sum;
        }
    }
    __syncthreads();

    int pidx = pidx0 + wave * 4;
    int h = pidx >> 6, w0 = pidx & 63;
    int o4 = lane * 4;

    float4 kreg[9];
#pragma unroll
    for (int tap = 0; tap < 9; tap++)
        kreg[tap] = *(const float4*)&dwt[tap * 256 + o4];

    float4 acc[4];
#pragma unroll
    for (int i = 0; i < 4; i++) acc[i] = (float4){0.f, 0.f, 0.f, 0.f};

    const float* arow = attns + (wave * 4) * 16;
#pragma unroll
    for (int c = 0; c < 16; c++) {
        float4 v = *(const float4*)&vp[(size_t)(b * 16 + c) * 256 + o4];
#pragma unroll
        for (int i = 0; i < 4; i++) {
            float a = arow[i * 16 + c];
            acc[i].x = fmaf(a, v.x, acc[i].x); acc[i].y = fmaf(a, v.y, acc[i].y);
            acc[i].z = fmaf(a, v.z, acc[i].z); acc[i].w = fmaf(a, v.w, acc[i].w);
        }
    }
#pragma unroll
    for (int dy = 0; dy < 3; dy++) {
        int hh = h + dy - 1;
        if (hh < 0 || hh > 63) continue;
        const unsigned short* qr = qbuf + ((size_t)(b * 4096 + hh * 64)) * 256;
        float4 ft[6];
#pragma unroll
        for (int c = 0; c < 6; c++) {
            int xx = w0 - 1 + c;
            if (xx < 0 || xx > 63) {
                ft[c] = (float4){0.f, 0.f, 0.f, 0.f};
            } else {
                uint2 qa = *(const uint2*)(qr + (size_t)xx * 256 + o4);
                ft[c] = (float4){lof(qa.x), hif(qa.x), lof(qa.y), hif(qa.y)};
            }
        }
#pragma unroll
        for (int dx = 0; dx < 3; dx++) {
            float4 kk = kreg[dy * 3 + dx];
#pragma unroll
            for (int i = 0; i < 4; i++) {
                float4 qv = ft[i + dx];
                acc[i].x = fmaf(qv.x, kk.x, acc[i].x);
                acc[i].y = fmaf(qv.y, kk.y, acc[i].y);
                acc[i].z = fmaf(qv.z, kk.z, acc[i].z);
                acc[i].w = fmaf(qv.w, kk.w, acc[i].w);
            }
        }
    }
#pragma unroll
    for (int i = 0; i < 4; i++) {
        uint2 pk;
        pk.x = (unsigned)f2bf(acc[i].x) | ((unsigned)f2bf(acc[i].y) << 16);
        pk.y = (unsigned)f2bf(acc[i].z) | ((unsigned)f2bf(acc[i].w) << 16);
        *(uint2*)(combined + ((size_t)(b * 4096 + pidx + i)) * 256 + o4) = pk;
    }
}

// ------ GEMM3+4 fused: comb x Wot -> +bo, gate(efp) -> ea in LDS;
//        then Woc x ea^T -> out NCHW with BN+ReLU. 64 pos x 256 per block. ---
__global__ __launch_bounds__(256) void gemm34_mfma(
    const unsigned short* __restrict__ comb, const unsigned short* __restrict__ Wot,
    const float* __restrict__ bo, const unsigned short* __restrict__ efp,
    const unsigned short* __restrict__ Woc,
    const float* __restrict__ scv, const float* __restrict__ shv,
    float* __restrict__ outp)
{
    __shared__ unsigned short As[64 * 64];    // 8 KB  : phase1 A (64 pos x 64 k)
    __shared__ unsigned short Bs[256 * 64];   // 32 KB : phase1 Wot / phase2 Woc
    __shared__ unsigned short eat[64 * 256];  // 32 KB : gated ea tile (swizzled)
    const int tid = threadIdx.x;
    const int wave = tid >> 6, lane = tid & 63;
    const int m0 = blockIdx.x * 64;

    const int srow = lane >> 3;               // 0..7
    const int sg = (lane & 7) ^ (srow & 7);   // pre-swizzled k-chunk (m173)

    // ---- phase 1: comb[m0..m0+63][:] x Wot -> acc (wave n-split wn=wave*64) -
    f32x4 acc[4][4];
#pragma unroll
    for (int i = 0; i < 4; i++)
#pragma unroll
        for (int j = 0; j < 4; j++) acc[i][j] = (f32x4){0.f, 0.f, 0.f, 0.f};

    const unsigned short* ga = comb + (size_t)(m0 + wave * 16 + srow) * 256 + sg * 8;
    const unsigned short* gb = Wot + (size_t)(wave * 64 + srow) * 256 + sg * 8;

    for (int k0 = 0; k0 < 256; k0 += 64) {
#pragma unroll
        for (int t = 0; t < 2; t++)
            async16(As + (wave * 16 + t * 8) * 64, ga + (size_t)t * 8 * 256 + k0);
#pragma unroll
        for (int t = 0; t < 8; t++)
            async16(Bs + (wave * 64 + t * 8) * 64, gb + (size_t)t * 8 * 256 + k0);
        __syncthreads();
#pragma unroll
        for (int ks = 0; ks < 2; ks++) {
            bf16x8 af[4], bfr[4];
            int kb = ks * 4 + (lane >> 4);
            int slot = (kb ^ (lane & 7)) * 8;
#pragma unroll
            for (int i = 0; i < 4; i++) {
                af[i]  = *(const bf16x8*)&As[(i * 16 + (lane & 15)) * 64 + slot];
                bfr[i] = *(const bf16x8*)&Bs[(wave * 64 + i * 16 + (lane & 15)) * 64 + slot];
            }
#pragma unroll
            for (int i = 0; i < 4; i++)
#pragma unroll
                for (int j = 0; j < 4; j++)
                    acc[i][j] = __builtin_amdgcn_mfma_f32_16x16x32_bf16(
                        af[i], bfr[j], acc[i][j], 0, 0, 0);
        }
        __syncthreads();
    }

    // ---- epilogue: +bo, gate by efp, bf16 -> eat (chunk-slot swizzled) ------
    float bo4[4];
#pragma unroll
    for (int j = 0; j < 4; j++) bo4[j] = bo[wave * 64 + j * 16 + (lane & 15)];
#pragma unroll
    for (int i = 0; i < 4; i++) {
#pragma unroll
        for (int r = 0; r < 4; r++) {
            int pos = i * 16 + ((lane >> 4) * 4) + r;
#pragma unroll
            for (int j = 0; j < 4; j++) {
                int n = wave * 64 + j * 16 + (lane & 15);
                float o = (acc[i][j][r] + bo4[j])
                          * bf2f(efp[(size_t)(m0 + pos) * 256 + n]);
                int o8 = j * 2 + ((lane >> 3) & 1);       // k-octet in chunk
                int slot = o8 ^ (pos & 7);
                eat[pos * 256 + wave * 64 + slot * 8 + (lane & 7)] = f2bf(o);
            }
        }
    }

    // ---- phase 2: Woc x eat^T -> out (wave co-split, co = wave*64 + ...) ----
    f32x4 acc2[4][4];
#pragma unroll
    for (int i = 0; i < 4; i++)
#pragma unroll
        for (int j = 0; j < 4; j++) acc2[i][j] = (f32x4){0.f, 0.f, 0.f, 0.f};

    const unsigned short* gw = Woc + (size_t)(wave * 64 + srow) * 256 + sg * 8;
    for (int k0 = 0; k0 < 256; k0 += 64) {
#pragma unroll
        for (int t = 0; t < 8; t++)
            async16(Bs + (wave * 64 + t * 8) * 64, gw + (size_t)t * 8 * 256 + k0);
        __syncthreads();
        int kc = k0 >> 6;
#pragma unroll
        for (int ks = 0; ks < 2; ks++) {
            bf16x8 af2[4], bf2_[4];
            int kb = ks * 4 + (lane >> 4);
            int slot = (kb ^ (lane & 7)) * 8;
#pragma unroll
            for (int i = 0; i < 4; i++) {
                af2[i]  = *(const bf16x8*)&Bs[(wave * 64 + i * 16 + (lane & 15)) * 64 + slot];
                bf2_[i] = *(const bf16x8*)&eat[(i * 16 + (lane & 15)) * 256 + kc * 64 + slot];
            }
#pragma unroll
            for (int i = 0; i < 4; i++)
#pragma unroll
                for (int j = 0; j < 4; j++)
                    acc2[i][j] = __builtin_amdgcn_mfma_f32_16x16x32_bf16(
                        af2[i], bf2_[j], acc2[i][j], 0, 0, 0);
        }
        __syncthreads();
    }

    // ---- BN + ReLU, store NCHW -----------------------------------------------
#pragma unroll
    for (int i = 0; i < 4; i++) {
#pragma unroll
        for (int r = 0; r < 4; r++) {
            int co = wave * 64 + i * 16 + ((lane >> 4) * 4) + r;
            float s = scv[co], hh = shv[co];
#pragma unroll
            for (int j = 0; j < 4; j++) {
                int p = m0 + j * 16 + (lane & 15);
                float o = fmaxf(fmaf(acc2[i][j][r], s, hh), 0.f);
                outp[((size_t)(p >> 12)) * 1048576 + (size_t)co * 4096 + (p & 4095)] = o;
            }
        }
    }
}

// ---------------------------------------------------------------------------
extern "C" void kernel_launch(void* const* d_in, const int* in_sizes, int n_in,
                              void* d_out, int out_size, void* d_ws, size_t ws_size,
                              hipStream_t stream)
{
    const float* e_f   = (const float*)d_in[0];
    const float* e_g   = (const float*)d_in[1];
    const float* lnfg  = (const float*)d_in[4];
    const float* lnfb  = (const float*)d_in[5];
    const float* lngg  = (const float*)d_in[6];
    const float* lngb  = (const float*)d_in[7];
    const float* wq    = (const float*)d_in[8];
    const float* bq    = (const float*)d_in[9];
    const float* wk    = (const float*)d_in[10];
    const float* bk    = (const float*)d_in[11];
    const float* wv    = (const float*)d_in[12];
    const float* bv    = (const float*)d_in[13];
    const float* wo    = (const float*)d_in[14];
    const float* bo    = (const float*)d_in[15];
    const float* dwk   = (const float*)d_in[16];
    const float* efpw  = (const float*)d_in[17];
    const float* efpb  = (const float*)d_in[18];
    const float* outcw = (const float*)d_in[19];
    const float* outcb = (const float*)d_in[20];
    const float* bng   = (const float*)d_in[21];
    const float* bnb   = (const float*)d_in[22];
    const float* bnm   = (const float*)d_in[23];
    const float* bnv   = (const float*)d_in[24];
    float* outp = (float*)d_out;

    char* base = (char*)d_ws;
    auto alloc = [&](size_t bytes) -> char* {
        char* r = base; base += (bytes + 255) & ~(size_t)255; return r;
    };
    float* pf    = (float*)alloc(8 * 32768 * 4);
    float* pfq   = (float*)alloc(8 * 32768 * 4);
    float* pg    = (float*)alloc(4 * 32768 * 4);
    float* pgq   = (float*)alloc(4 * 32768 * 4);
    float* mg    = (float*)alloc(32768 * 4);
    float* rg    = (float*)alloc(32768 * 4);
    float* cs1   = (float*)alloc(512 * 4);
    float* cst1  = (float*)alloc(512 * 4);
    float* cs2   = (float*)alloc(512 * 4);
    float* cst2  = (float*)alloc(512 * 4);
    float* scv   = (float*)alloc(256 * 4);
    float* shv   = (float*)alloc(256 * 4);
    float* dwt   = (float*)alloc(9 * 256 * 4);
    unsigned short* Wb1t = (unsigned short*)alloc(262144 * 2);
    unsigned short* Wb2t = (unsigned short*)alloc(65536 * 2);
    unsigned short* Wot  = (unsigned short*)alloc(65536 * 2);
    unsigned short* Woc  = (unsigned short*)alloc(65536 * 2);
    unsigned short* ef_bf = (unsigned short*)alloc((size_t)32768 * 512 * 2);
    unsigned short* eg_bf = (unsigned short*)alloc((size_t)32768 * 256 * 2);
    unsigned short* qbuf  = (unsigned short*)alloc((size_t)32768 * 256 * 2);
    unsigned short* efpbuf = (unsigned short*)alloc((size_t)32768 * 256 * 2);
    unsigned short* kfull = (unsigned short*)alloc((size_t)32768 * 256 * 2); // -> combined
    unsigned short* kpb  = (unsigned short*)alloc(128 * 256 * 2);
    float* vp    = (float*)alloc(128 * 256 * 4);
    float* s1    = (float*)alloc(128 * 256 * 4);
    float* s0    = (float*)alloc(128 * 4);

    trans_prep<<<3354, 256, 0, stream>>>(
        e_f, e_g, ef_bf, eg_bf, pf, pfq, pg, pgq,
        lnfg, lnfb, wq, bq, efpw, efpb, lngg, lngb, wk, bk, wv, bv, wo,
        outcw, outcb, bng, bnb, bnm, bnv, dwk,
        Wb1t, Wb2t, Wot, Woc, dwt, cs1, cst1, cs2, cst2, scv, shv);
    gemm_proj<<<1024, 256, 0, stream>>>(
        ef_bf, Wb1t, cs1, cst1, pf, pfq, qbuf, efpbuf,
        eg_bf, Wb2t, cs2, cst2, pg, pgq, mg, rg, kfull);
    pool_phase<<<640, 256, 0, stream>>>(kfull, e_g, rg, mg, kpb, s1, s0);
    vpool_gemm<<<128, 256, 0, stream>>>(s1, s0, lngg, wv, cs2, cst2, vp);
    combined_dw<<<2048, 256, 0, stream>>>(qbuf, kpb, vp, dwt, /*combined=*/kfull);
    gemm34_mfma<<<512, 256, 0, stream>>>(/*combined=*/kfull, Wot, bo, efpbuf,
                                         Woc, scv, shv, outp);
}

// Round 10
// 287.357 us; speedup vs baseline: 1.2898x; 1.0056x over previous
//
#include <hip/hip_runtime.h>
#include <math.h>

#define EPS 1e-5f

typedef __attribute__((ext_vector_type(8))) short bf16x8;
typedef __attribute__((ext_vector_type(4))) float f32x4;

__device__ __forceinline__ unsigned short f2bf(float f) {
    unsigned int u = __float_as_uint(f);
    u += 0x7fff + ((u >> 16) & 1);            // round-to-nearest-even
    return (unsigned short)(u >> 16);
}
__device__ __forceinline__ float bf2f(unsigned short h) {
    return __uint_as_float(((unsigned int)h) << 16);
}
__device__ __forceinline__ float lof(unsigned int u) {
    return __uint_as_float(u << 16);
}
__device__ __forceinline__ float hif(unsigned int u) {
    return __uint_as_float(u & 0xffff0000u);
}
__device__ __forceinline__ void async16(void* lds, const void* g) {
    __builtin_amdgcn_global_load_lds(
        (const __attribute__((address_space(1))) unsigned int*)g,
        (__attribute__((address_space(3))) unsigned int*)lds, 16, 0, 0);
}

// ---- merged: NCHW->bf16 transpose + LN partials (blocks 0..3071)
//      and weight-prep (blocks 3072..; constants k-parallelized) -------------
__global__ __launch_bounds__(256) void trans_prep(
    const float* __restrict__ ef, const float* __restrict__ eg,
    unsigned short* __restrict__ ef_bf, unsigned short* __restrict__ eg_bf,
    float* __restrict__ pf, float* __restrict__ pfq,
    float* __restrict__ pg, float* __restrict__ pgq,
    const float* __restrict__ lnfg, const float* __restrict__ lnfb,
    const float* __restrict__ wq, const float* __restrict__ bq,
    const float* __restrict__ efpw, const float* __restrict__ efpb,
    const float* __restrict__ lngg, const float* __restrict__ lngb,
    const float* __restrict__ wk, const float* __restrict__ bk,
    const float* __restrict__ wv, const float* __restrict__ bv,
    const float* __restrict__ wo, const float* __restrict__ outcw,
    const float* __restrict__ outcb, const float* __restrict__ bng,
    const float* __restrict__ bnb, const float* __restrict__ bnm,
    const float* __restrict__ bnv, const float* __restrict__ dwk,
    unsigned short* __restrict__ Wb1t, unsigned short* __restrict__ Wb2t,
    unsigned short* __restrict__ Wot, unsigned short* __restrict__ Woc,
    float* __restrict__ dwt,
    float* __restrict__ cs1, float* __restrict__ cst1,
    float* __restrict__ cs2, float* __restrict__ cst2,
    float* __restrict__ scv, float* __restrict__ shv)
{
    __shared__ float tile[64][65];
    __shared__ float psum[4][64], pss[4][64];
    int id = blockIdx.x;
    int t = threadIdx.x;
    if (id < 3072) {
        // ---------------- transpose path (r3 verbatim) ----------------
        const float* src; unsigned short* dst; float* ps; float* pq;
        int C, cblk, b, p0;
        if (id < 2048) {                          // e_f: 8b x 8cblk x 32ptile
            src = ef; dst = ef_bf; ps = pf; pq = pfq; C = 512;
            b = id >> 8; cblk = (id >> 5) & 7; p0 = (id & 31) * 128;
        } else {                                  // e_g: 8b x 4cblk x 32ptile
            id -= 2048;
            src = eg; dst = eg_bf; ps = pg; pq = pgq; C = 256;
            b = id >> 7; cblk = (id >> 5) & 3; p0 = (id & 31) * 128;
        }
        int c0 = cblk * 64;
        const float* s = src + ((size_t)b * C + c0) * 4096 + p0;
        int cr = t >> 4, p4 = (t & 15) * 4;
        int lane = t & 63, grp = t >> 6;
        int pr = t >> 3, c8 = (t & 7) * 8;

        float4 r1[4], r2[4];
#pragma unroll
        for (int i = 0; i < 4; i++)
            r1[i] = *(const float4*)(s + (size_t)(i * 16 + cr) * 4096 + p4);
#pragma unroll
        for (int i = 0; i < 4; i++)
            r2[i] = *(const float4*)(s + (size_t)(i * 16 + cr) * 4096 + 64 + p4);

#pragma unroll
        for (int half = 0; half < 2; half++) {
#pragma unroll
            for (int i = 0; i < 4; i++) {
                float4 v = half ? r2[i] : r1[i];
                int c = i * 16 + cr;
                tile[c][p4 + 0] = v.x; tile[c][p4 + 1] = v.y;
                tile[c][p4 + 2] = v.z; tile[c][p4 + 3] = v.w;
            }
            __syncthreads();

            int pbase = p0 + half * 64;
            unsigned short* d = dst + ((size_t)(b * 4096 + pbase)) * C + c0;
#pragma unroll
            for (int i = 0; i < 2; i++) {
                int p = i * 32 + pr;
                uint4 pk;
                pk.x = (unsigned)f2bf(tile[c8 + 0][p]) | ((unsigned)f2bf(tile[c8 + 1][p]) << 16);
                pk.y = (unsigned)f2bf(tile[c8 + 2][p]) | ((unsigned)f2bf(tile[c8 + 3][p]) << 16);
                pk.z = (unsigned)f2bf(tile[c8 + 4][p]) | ((unsigned)f2bf(tile[c8 + 5][p]) << 16);
                pk.w = (unsigned)f2bf(tile[c8 + 6][p]) | ((unsigned)f2bf(tile[c8 + 7][p]) << 16);
                *(uint4*)(d + (size_t)p * C + c8) = pk;
            }

            float sm = 0.f, sq = 0.f;
#pragma unroll
            for (int j = 0; j < 16; j++) {
                float v = tile[grp * 16 + j][lane];
                sm += v; sq += v * v;
            }
            psum[grp][lane] = sm; pss[grp][lane] = sq;
            __syncthreads();
            if (t < 64) {
                float fs = psum[0][t] + psum[1][t] + psum[2][t] + psum[3][t];
                float fq = pss[0][t] + pss[1][t] + pss[2][t] + pss[3][t];
                ps[cblk * 32768 + b * 4096 + pbase + t] = fs;
                pq[cblk * 32768 + b * 4096 + pbase + t] = fq;
            }
            if (half == 0) __syncthreads();       // tile reuse fence
        }
    } else {
        int id2 = id - 3072;
        float* red1 = (float*)psum;               // 256-float scratch
        float* red2 = (float*)pss;
        if (id2 < 64) {
            // -- LDS-tiled 64x64 weight transpose (coalesced both sides) --
            const float* src; unsigned short* dst; const float* scale;
            int K, k0, n0;
            if (id2 < 32) {            // Wb1t-q: wq[512][256] -> [n<256][512]
                src = wq; dst = Wb1t; scale = lnfg; K = 512;
                k0 = (id2 >> 2) * 64; n0 = (id2 & 3) * 64;
            } else if (id2 < 48) {     // Wb2t: wk[256][256] -> [n][256]
                int j = id2 - 32;
                src = wk; dst = Wb2t; scale = lngg; K = 256;
                k0 = (j >> 2) * 64; n0 = (j & 3) * 64;
            } else {                   // Wot: wo[256][256] -> [n][256]
                int j = id2 - 48;
                src = wo; dst = Wot; scale = nullptr; K = 256;
                k0 = (j >> 2) * 64; n0 = (j & 3) * 64;
            }
            int rr = t >> 6, cc = t & 63;
#pragma unroll
            for (int i = 0; i < 16; i++) {
                int r = i * 4 + rr;
                tile[r][cc] = src[(size_t)(k0 + r) * 256 + n0 + cc];
            }
            __syncthreads();
            int nn = t >> 3, k8 = (t & 7) * 8;
#pragma unroll
            for (int i = 0; i < 2; i++) {
                int n = i * 32 + nn;
                float v[8];
#pragma unroll
                for (int j = 0; j < 8; j++) {
                    float s = scale ? scale[k0 + k8 + j] : 1.f;
                    v[j] = s * tile[k8 + j][n];
                }
                uint4 pk;
                pk.x = (unsigned)f2bf(v[0]) | ((unsigned)f2bf(v[1]) << 16);
                pk.y = (unsigned)f2bf(v[2]) | ((unsigned)f2bf(v[3]) << 16);
                pk.z = (unsigned)f2bf(v[4]) | ((unsigned)f2bf(v[5]) << 16);
                pk.w = (unsigned)f2bf(v[6]) | ((unsigned)f2bf(v[7]) << 16);
                *(uint4*)(dst + (size_t)(n0 + n) * K + k0 + k8) = pk;
            }
        } else if (id2 < 192) {        // Wb1t-efp half: row-major copy-convert
            int j = (id2 - 64) * 1024 + t * 4;
            float4 v = *(const float4*)(efpw + j);
            uint2 pk;
            pk.x = (unsigned)f2bf(v.x) | ((unsigned)f2bf(v.y) << 16);
            pk.y = (unsigned)f2bf(v.z) | ((unsigned)f2bf(v.w) << 16);
            *(uint2*)(Wb1t + 131072 + j) = pk;
        } else if (id2 < 256) {        // Woc copy-convert
            int j = (id2 - 192) * 1024 + t * 4;
            float4 v = *(const float4*)(outcw + j);
            uint2 pk;
            pk.x = (unsigned)f2bf(v.x) | ((unsigned)f2bf(v.y) << 16);
            pk.y = (unsigned)f2bf(v.z) | ((unsigned)f2bf(v.w) << 16);
            *(uint2*)(Woc + j) = pk;
        } else if (id2 == 256) {       // dwt [tap][ch]
#pragma unroll
            for (int tap = 0; tap < 9; tap++)
                dwt[tap * 256 + t] = dwk[t * 9 + tap];
        } else if (id2 < 265) {        // cs1/cst1: 8 blocks x 32 n, k-parallel
            int n0 = (id2 - 257) * 32;
            int nl = t & 31, kq = t >> 5;         // 8 k-groups of 64
            float cs = 0.f, ct = 0.f;
#pragma unroll 4
            for (int kk = 0; kk < 64; kk++) {
                int k = kq * 64 + kk;
                float w = wq[k * 256 + n0 + nl];
                cs += lnfg[k] * w; ct += lnfb[k] * w;
            }
            red1[kq * 32 + nl] = cs; red2[kq * 32 + nl] = ct;
            __syncthreads();
            if (t < 32) {
                float s = 0.f, c2 = 0.f;
#pragma unroll
                for (int q = 0; q < 8; q++) { s += red1[q * 32 + t]; c2 += red2[q * 32 + t]; }
                int n = n0 + t;
                cs1[n] = s; cst1[n] = c2 + bq[n];
                cs1[256 + n] = 0.f; cst1[256 + n] = efpb[n];
            }
        } else if (id2 < 273) {        // cs2-k: 8 blocks x 32 n, k-parallel
            int n0 = (id2 - 265) * 32;
            int nl = t & 31, kq = t >> 5;         // 8 k-groups of 32
            float cs = 0.f, ct = 0.f;
#pragma unroll 4
            for (int kk = 0; kk < 32; kk++) {
                int k = kq * 32 + kk;
                float w = wk[k * 256 + n0 + nl];
                cs += lngg[k] * w; ct += lngb[k] * w;
            }
            red1[kq * 32 + nl] = cs; red2[kq * 32 + nl] = ct;
            __syncthreads();
            if (t < 32) {
                float s = 0.f, c2 = 0.f;
#pragma unroll
                for (int q = 0; q < 8; q++) { s += red1[q * 32 + t]; c2 += red2[q * 32 + t]; }
                int n = n0 + t;
                cs2[n] = s; cst2[n] = c2 + bk[n];
            }
        } else if (id2 < 281) {        // cs2-v: 8 blocks x 32 n, k-parallel
            int n0 = (id2 - 273) * 32;
            int nl = t & 31, kq = t >> 5;
            float cs = 0.f, ct = 0.f;
#pragma unroll 4
            for (int kk = 0; kk < 32; kk++) {
                int k = kq * 32 + kk;
                float w = wv[k * 256 + n0 + nl];
                cs += lngg[k] * w; ct += lngb[k] * w;
            }
            red1[kq * 32 + nl] = cs; red2[kq * 32 + nl] = ct;
            __syncthreads();
            if (t < 32) {
                float s = 0.f, c2 = 0.f;
#pragma unroll
                for (int q = 0; q < 8; q++) { s += red1[q * 32 + t]; c2 += red2[q * 32 + t]; }
                int n = n0 + t;
                cs2[256 + n] = s; cst2[256 + n] = c2 + bv[n];
            }
        } else {                       // id2 == 281: BN constants
            int n = t;
            float s = bng[n] * rsqrtf(bnv[n] + EPS);
            scv[n] = s;
            shv[n] = (outcb[n] - bnm[n]) * s + bnb[n];
        }
    }
}

// ---------------- MFMA GEMM core (m97-style, 128x128) -----------------------
template<int K>
__device__ __forceinline__ void mfma_core(
    const unsigned short* __restrict__ A, const unsigned short* __restrict__ Bt,
    int m0, int n0, unsigned short* As, unsigned short* Bs, f32x4 acc[4][4])
{
    const int tid = threadIdx.x;
    const int wave = tid >> 6, lane = tid & 63;
    const int wm = (wave & 1) * 64, wn = (wave >> 1) * 64;
#pragma unroll
    for (int i = 0; i < 4; i++)
#pragma unroll
        for (int j = 0; j < 4; j++) acc[i][j] = (f32x4){0.f, 0.f, 0.f, 0.f};

    const int srow = wave * 32 + (lane >> 3);
    const int sg = (lane & 7) ^ ((lane >> 3) & 7);
    const unsigned short* ga = A + (size_t)(m0 + srow) * K + sg * 8;
    const unsigned short* gb = Bt + (size_t)(n0 + srow) * K + sg * 8;

    for (int k0 = 0; k0 < K; k0 += 64) {
#pragma unroll
        for (int t = 0; t < 4; t++) {
            async16(As + (wave * 32 + t * 8) * 64, ga + (size_t)t * 8 * K + k0);
            async16(Bs + (wave * 32 + t * 8) * 64, gb + (size_t)t * 8 * K + k0);
        }
        __syncthreads();
#pragma unroll
        for (int ks = 0; ks < 2; ks++) {
            bf16x8 af[4], bfr[4];
            int kb = ks * 4 + (lane >> 4);
            int slot = (kb ^ (lane & 7)) * 8;
#pragma unroll
            for (int i = 0; i < 4; i++) {
                int m = wm + i * 16 + (lane & 15);
                af[i] = *(const bf16x8*)&As[m * 64 + slot];
                int n = wn + i * 16 + (lane & 15);
                bfr[i] = *(const bf16x8*)&Bs[n * 64 + slot];
            }
#pragma unroll
            for (int i = 0; i < 4; i++)
#pragma unroll
                for (int j = 0; j < 4; j++)
                    acc[i][j] = __builtin_amdgcn_mfma_f32_16x16x32_bf16(
                        af[i], bfr[j], acc[i][j], 0, 0, 0);
        }
        __syncthreads();
    }
}

// ---- merged projection GEMMs + v-pool partials:
//      blocks 0..511   = gemm1 (ef_bf x Wb1t -> q|efp, 128m x 256n, LN)
//      blocks 512..1023 = gemm2k (eg_bf x Wb2t -> kfull, 128m x 128n, LN)
//      blocks 1024..1535 = weighted v-pool partials (stats inline from pg/pgq)
__global__ __launch_bounds__(256, 2) void gemm_proj(
    const unsigned short* __restrict__ ef_bf, const unsigned short* __restrict__ Wb1t,
    const float* __restrict__ cs1, const float* __restrict__ cst1,
    const float* __restrict__ pf, const float* __restrict__ pfq,
    unsigned short* __restrict__ qbuf, unsigned short* __restrict__ efpbuf,
    const unsigned short* __restrict__ eg_bf, const unsigned short* __restrict__ Wb2t,
    const float* __restrict__ cs2, const float* __restrict__ cst2,
    const float* __restrict__ pg, const float* __restrict__ pgq,
    unsigned short* __restrict__ kfull,
    const float* __restrict__ eg, float* __restrict__ s1,
    float* __restrict__ s0)
{
    __shared__ unsigned short As[128 * 64];   // 16 KB
    __shared__ unsigned short Bs[256 * 64];   // 32 KB (v-pool reuses as float)
    __shared__ float sstat[256];              // mean[128] | rstd[128]
    const int tid = threadIdx.x;
    const int wave = tid >> 6, lane = tid & 63;
    const int bid = blockIdx.x;

    if (bid < 512) {
        // ------------------------- gemm1 path -------------------------
        const int m0 = (bid >> 1) * 128, n0 = (bid & 1) * 256;
        const int wm = (wave & 1) * 64, wn = (wave >> 1) * 128;
        f32x4 acc[4][8];

        if (tid < 128) {                      // LN finalize for this block's rows
            int gm = m0 + tid;
            float s = 0.f, q = 0.f;
#pragma unroll
            for (int i = 0; i < 8; i++) { s += pf[i * 32768 + gm]; q += pfq[i * 32768 + gm]; }
            float m = s * (1.f / 512.f);
            sstat[tid] = m;
            sstat[128 + tid] = rsqrtf(q * (1.f / 512.f) - m * m + EPS);
        }

#pragma unroll
        for (int i = 0; i < 4; i++)
#pragma unroll
            for (int j = 0; j < 8; j++) acc[i][j] = (f32x4){0.f, 0.f, 0.f, 0.f};

        const int srow = lane >> 3;
        const int sg = (lane & 7) ^ (srow & 7);
        const unsigned short* ga = ef_bf + (size_t)(m0 + wave * 32 + srow) * 512 + sg * 8;
        const unsigned short* gb = Wb1t + (size_t)(n0 + wave * 64 + srow) * 512 + sg * 8;

        for (int k0 = 0; k0 < 512; k0 += 64) {
#pragma unroll
            for (int t = 0; t < 4; t++)
                async16(As + (wave * 32 + t * 8) * 64, ga + (size_t)t * 8 * 512 + k0);
#pragma unroll
            for (int t = 0; t < 8; t++)
                async16(Bs + (wave * 64 + t * 8) * 64, gb + (size_t)t * 8 * 512 + k0);
            __syncthreads();
#pragma unroll
            for (int ks = 0; ks < 2; ks++) {
                bf16x8 af[4], bfr[8];
                int kb = ks * 4 + (lane >> 4);
                int slot = (kb ^ (lane & 7)) * 8;
#pragma unroll
                for (int i = 0; i < 4; i++)
                    af[i] = *(const bf16x8*)&As[(wm + i * 16 + (lane & 15)) * 64 + slot];
#pragma unroll
                for (int j = 0; j < 8; j++)
                    bfr[j] = *(const bf16x8*)&Bs[(wn + j * 16 + (lane & 15)) * 64 + slot];
#pragma unroll
                for (int i = 0; i < 4; i++)
#pragma unroll
                    for (int j = 0; j < 8; j++)
                        acc[i][j] = __builtin_amdgcn_mfma_f32_16x16x32_bf16(
                            af[i], bfr[j], acc[i][j], 0, 0, 0);
            }
            __syncthreads();
        }

        bool isq = (n0 == 0);
#pragma unroll
        for (int i = 0; i < 4; i++) {
#pragma unroll
            for (int r = 0; r < 4; r++) {
                int lm = wm + i * 16 + ((lane >> 4) * 4) + r;
                int gm = m0 + lm;
                float mean = sstat[lm], rs = sstat[128 + lm];
#pragma unroll
                for (int j = 0; j < 8; j++) {
                    int nn = wn + j * 16 + (lane & 15);   // 0..255 within half
                    float v = acc[i][j][r];
                    if (isq) {
                        int n = nn;
                        float o = rs * (v - mean * cs1[n]) + cst1[n];
                        qbuf[(size_t)gm * 256 + nn] = f2bf(o);
                    } else {
                        int n = nn + 256;
                        efpbuf[(size_t)gm * 256 + nn] = f2bf(v + cst1[n]);
                    }
                }
            }
        }
    } else if (bid < 1024) {
        // ------------------------- gemm2k path ------------------------
        const int j2 = bid - 512;
        const int m0 = (j2 >> 1) * 128, n0 = (j2 & 1) * 128;
        f32x4 acc[4][4];

        if (tid < 128) {
            int gm = m0 + tid;
            float s = 0.f, q = 0.f;
#pragma unroll
            for (int i = 0; i < 4; i++) { s += pg[i * 32768 + gm]; q += pgq[i * 32768 + gm]; }
            float m = s * (1.f / 256.f);
            float r = rsqrtf(q * (1.f / 256.f) - m * m + EPS);
            sstat[tid] = m; sstat[128 + tid] = r;
        }

        mfma_core<256>(eg_bf, Wb2t, m0, n0, As, Bs, acc);
        int wm = (wave & 1) * 64, wn = (wave >> 1) * 64;
#pragma unroll
        for (int i = 0; i < 4; i++) {
#pragma unroll
            for (int r = 0; r < 4; r++) {
                int lm = wm + i * 16 + ((lane >> 4) * 4) + r;
                int gm = m0 + lm;
                float mean = sstat[lm], rs = sstat[128 + lm];
#pragma unroll
                for (int j = 0; j < 4; j++) {
                    int n = n0 + wn + j * 16 + (lane & 15);
                    float o = rs * (acc[i][j][r] - mean * cs2[n]) + cst2[n];
                    kfull[(size_t)gm * 256 + n] = f2bf(o);
                }
            }
        }
    } else {
        // ---- weighted v-pool partials (moved from pool_phase) ---------
        float* smem = (float*)Bs;             // 8192 floats avail, need 4352
        const int id3 = bid - 1024;
        int b = id3 >> 6, hp = (id3 >> 4) & 3, cgrp = id3 & 15;
        int rr = tid >> 4, cq = tid & 15;
        int p = (hp * 16 + rr) * 64 + cq * 4;

        // inline LN-stat finalize (bit-identical to old mg/rg values)
        float w[4], m[4];
#pragma unroll
        for (int d = 0; d < 4; d++) {
            int gp = b * 4096 + p + d;
            float s = 0.f, q = 0.f;
#pragma unroll
            for (int i = 0; i < 4; i++) { s += pg[i * 32768 + gp]; q += pgq[i * 32768 + gp]; }
            float mean = s * (1.f / 256.f);
            m[d] = mean;
            w[d] = rsqrtf(q * (1.f / 256.f) - mean * mean + EPS);
        }

        float part[16];
        const float* egb = eg + ((size_t)b * 256 + cgrp * 16) * 4096 + p;
#pragma unroll
        for (int cc = 0; cc < 16; cc++) {
            float4 v4 = *(const float4*)(egb + (size_t)cc * 4096);
            part[cc] = w[0] * v4.x + w[1] * v4.y + w[2] * v4.z + w[3] * v4.w;
        }
#pragma unroll
        for (int cc = 0; cc < 16; cc++) smem[tid * 16 + cc] = part[cc];
        if (cgrp == 0)
            smem[4096 + tid] = w[0] * m[0] + w[1] * m[1] + w[2] * m[2] + w[3] * m[3];
        __syncthreads();
        if (tid < 64) {
            int cx2 = tid >> 4, cc = tid & 15;
            float sacc = 0.f;
#pragma unroll
            for (int rr2 = 0; rr2 < 16; rr2++)
#pragma unroll
                for (int dq = 0; dq < 4; dq++)
                    sacc += smem[(rr2 * 16 + cx2 * 4 + dq) * 16 + cc];
            s1[((size_t)(b * 16 + hp * 4 + cx2)) * 256 + cgrp * 16 + cc] = sacc;
        }
        if (cgrp == 0 && tid < 4) {
            float sacc = 0.f;
#pragma unroll
            for (int rr2 = 0; rr2 < 16; rr2++)
#pragma unroll
                for (int dq = 0; dq < 4; dq++)
                    sacc += smem[4096 + rr2 * 16 + tid * 4 + dq];
            s0[b * 16 + hp * 4 + tid] = sacc;
        }
    }
}

// ---- merged pool tail: blocks 0..127 k-maxpool; 128..255 v-pool mini-GEMM --
__global__ __launch_bounds__(256) void pool_vp(
    const unsigned short* __restrict__ kfull, unsigned short* __restrict__ kpb,
    const float* __restrict__ s1, const float* __restrict__ s0,
    const float* __restrict__ lngg, const float* __restrict__ wv,
    const float* __restrict__ cs2, const float* __restrict__ cst2,
    float* __restrict__ vp)
{
    __shared__ float smem[2048];
    int id = blockIdx.x;
    int t = threadIdx.x;
    if (id < 128) {
        // ---- k max pool: (b, cell) ----
        int b = id >> 4, cell = id & 15;
        int hp = cell >> 2, wp = cell & 3;
        int g8 = t & 31, rr = t >> 5;
        float kmx[8];
#pragma unroll
        for (int j = 0; j < 8; j++) kmx[j] = -3.402823466e38f;
#pragma unroll
        for (int rsub = 0; rsub < 2; rsub++) {
            int r = rr * 2 + rsub;
            int prow = (hp * 16 + r) * 64 + wp * 16;
            for (int cl = 0; cl < 16; cl++) {
                size_t basei = ((size_t)(b * 4096 + prow + cl)) * 256 + g8 * 8;
                uint4 kv = *(const uint4*)(kfull + basei);
                kmx[0] = fmaxf(kmx[0], lof(kv.x)); kmx[1] = fmaxf(kmx[1], hif(kv.x));
                kmx[2] = fmaxf(kmx[2], lof(kv.y)); kmx[3] = fmaxf(kmx[3], hif(kv.y));
                kmx[4] = fmaxf(kmx[4], lof(kv.z)); kmx[5] = fmaxf(kmx[5], hif(kv.z));
                kmx[6] = fmaxf(kmx[6], lof(kv.w)); kmx[7] = fmaxf(kmx[7], hif(kv.w));
            }
        }
#pragma unroll
        for (int j = 0; j < 8; j++) smem[rr * 256 + g8 * 8 + j] = kmx[j];
        __syncthreads();
        float m = smem[t];
#pragma unroll
        for (int r2 = 1; r2 < 8; r2++) m = fmaxf(m, smem[r2 * 256 + t]);
        kpb[(size_t)(b * 16 + cell) * 256 + t] = f2bf(m);   // lossless
    } else {
        // ---- v-pool mini-GEMM: vp[cell][n] from s1/s0 (fp32 exact) ----
        int cell = id - 128;          // 0..127 = b*16+cell
        int n = t;
        const float* s1r = s1 + (size_t)cell * 256;
        float acc = 0.f;
        for (int c = 0; c < 256; c++)
            acc = fmaf(lngg[c] * s1r[c], wv[c * 256 + n], acc);
        vp[(size_t)cell * 256 + n] = acc * (1.f / 256.f)
            - (s0[cell] * (1.f / 256.f)) * cs2[256 + n] + cst2[256 + n];
    }
}

// ---- combined = attn@vp + dw3x3(q): scores fused, no global attns ----------
__global__ __launch_bounds__(256) void combined_dw(
    const unsigned short* __restrict__ qbuf, const unsigned short* __restrict__ kpb,
    const float* __restrict__ vp, const float* __restrict__ dwt,
    unsigned short* __restrict__ combined)
{
    __shared__ float attns[256];          // 16 pos x 16 cells
    int wave = threadIdx.x >> 6, lane = threadIdx.x & 63;
    int id = blockIdx.x;                  // 2048
    int b = id & 7, seg = id >> 3;        // batch pinned per XCD
    int pidx0 = seg * 16;

    if (wave == 0) {
        int fr = lane & 15, quad = lane >> 4;
        const unsigned short* qrow = qbuf + (size_t)(b * 4096 + pidx0 + fr) * 256 + quad * 8;
        const unsigned short* krow = kpb + (size_t)(b * 16 + fr) * 256 + quad * 8;
        f32x4 sacc = {0.f, 0.f, 0.f, 0.f};
#pragma unroll
        for (int ks = 0; ks < 8; ks++) {
            bf16x8 af = *(const bf16x8*)(qrow + ks * 32);
            bf16x8 bf_ = *(const bf16x8*)(krow + ks * 32);
            sacc = __builtin_amdgcn_mfma_f32_16x16x32_bf16(af, bf_, sacc, 0, 0, 0);
        }
#pragma unroll
        for (int r = 0; r < 4; r++) {
            float s = sacc[r] * 0.0625f;  // HID^-0.5
            float mx = s;
#pragma unroll
            for (int off = 8; off >= 1; off >>= 1) mx = fmaxf(mx, __shfl_xor(mx, off));
            float e = __expf(s - mx);
            float sum = e;
#pragma unroll
            for (int off = 8; off >= 1; off >>= 1) sum += __shfl_xor(sum, off);
            attns[(quad * 4 + r) * 16 + fr] = e / sum;
        }
    }
    __syncthreads();

    int pidx = pidx0 + wave * 4;
    int h = pidx >> 6, w0 = pidx & 63;
    int o4 = lane * 4;

    float4 kreg[9];
#pragma unroll
    for (int tap = 0; tap < 9; tap++)
        kreg[tap] = *(const float4*)&dwt[tap * 256 + o4];

    float4 acc[4];
#pragma unroll
    for (int i = 0; i < 4; i++) acc[i] = (float4){0.f, 0.f, 0.f, 0.f};

    const float* arow = attns + (wave * 4) * 16;
#pragma unroll
    for (int c = 0; c < 16; c++) {
        float4 v = *(const float4*)&vp[(size_t)(b * 16 + c) * 256 + o4];
#pragma unroll
        for (int i = 0; i < 4; i++) {
            float a = arow[i * 16 + c];
            acc[i].x = fmaf(a, v.x, acc[i].x); acc[i].y = fmaf(a, v.y, acc[i].y);
            acc[i].z = fmaf(a, v.z, acc[i].z); acc[i].w = fmaf(a, v.w, acc[i].w);
        }
    }
#pragma unroll
    for (int dy = 0; dy < 3; dy++) {
        int hh = h + dy - 1;
        if (hh < 0 || hh > 63) continue;
        const unsigned short* qr = qbuf + ((size_t)(b * 4096 + hh * 64)) * 256;
        float4 ft[6];
#pragma unroll
        for (int c = 0; c < 6; c++) {
            int xx = w0 - 1 + c;
            if (xx < 0 || xx > 63) {
                ft[c] = (float4){0.f, 0.f, 0.f, 0.f};
            } else {
                uint2 qa = *(const uint2*)(qr + (size_t)xx * 256 + o4);
                ft[c] = (float4){lof(qa.x), hif(qa.x), lof(qa.y), hif(qa.y)};
            }
        }
#pragma unroll
        for (int dx = 0; dx < 3; dx++) {
            float4 kk = kreg[dy * 3 + dx];
#pragma unroll
            for (int i = 0; i < 4; i++) {
                float4 qv = ft[i + dx];
                acc[i].x = fmaf(qv.x, kk.x, acc[i].x);
                acc[i].y = fmaf(qv.y, kk.y, acc[i].y);
                acc[i].z = fmaf(qv.z, kk.z, acc[i].z);
                acc[i].w = fmaf(qv.w, kk.w, acc[i].w);
            }
        }
    }
#pragma unroll
    for (int i = 0; i < 4; i++) {
        uint2 pk;
        pk.x = (unsigned)f2bf(acc[i].x) | ((unsigned)f2bf(acc[i].y) << 16);
        pk.y = (unsigned)f2bf(acc[i].z) | ((unsigned)f2bf(acc[i].w) << 16);
        *(uint2*)(combined + ((size_t)(b * 4096 + pidx + i)) * 256 + o4) = pk;
    }
}

// ------ GEMM3+4 fused: comb x Wot -> +bo, gate(efp) -> ea in LDS;
//        then Woc x ea^T -> out NCHW with BN+ReLU. 64 pos x 256 per block. ---
__global__ __launch_bounds__(256) void gemm34_mfma(
    const unsigned short* __restrict__ comb, const unsigned short* __restrict__ Wot,
    const float* __restrict__ bo, const unsigned short* __restrict__ efp,
    const unsigned short* __restrict__ Woc,
    const float* __restrict__ scv, const float* __restrict__ shv,
    float* __restrict__ outp)
{
    __shared__ unsigned short As[64 * 64];    // 8 KB  : phase1 A (64 pos x 64 k)
    __shared__ unsigned short Bs[256 * 64];   // 32 KB : phase1 Wot / phase2 Woc
    __shared__ unsigned short eat[64 * 256];  // 32 KB : gated ea tile (swizzled)
    const int tid = threadIdx.x;
    const int wave = tid >> 6, lane = tid & 63;
    const int m0 = blockIdx.x * 64;

    const int srow = lane >> 3;               // 0..7
    const int sg = (lane & 7) ^ (srow & 7);   // pre-swizzled k-chunk (m173)

    // ---- phase 1: comb[m0..m0+63][:] x Wot -> acc (wave n-split wn=wave*64) -
    f32x4 acc[4][4];
#pragma unroll
    for (int i = 0; i < 4; i++)
#pragma unroll
        for (int j = 0; j < 4; j++) acc[i][j] = (f32x4){0.f, 0.f, 0.f, 0.f};

    const unsigned short* ga = comb + (size_t)(m0 + wave * 16 + srow) * 256 + sg * 8;
    const unsigned short* gb = Wot + (size_t)(wave * 64 + srow) * 256 + sg * 8;

    for (int k0 = 0; k0 < 256; k0 += 64) {
#pragma unroll
        for (int t = 0; t < 2; t++)
            async16(As + (wave * 16 + t * 8) * 64, ga + (size_t)t * 8 * 256 + k0);
#pragma unroll
        for (int t = 0; t < 8; t++)
            async16(Bs + (wave * 64 + t * 8) * 64, gb + (size_t)t * 8 * 256 + k0);
        __syncthreads();
#pragma unroll
        for (int ks = 0; ks < 2; ks++) {
            bf16x8 af[4], bfr[4];
            int kb = ks * 4 + (lane >> 4);
            int slot = (kb ^ (lane & 7)) * 8;
#pragma unroll
            for (int i = 0; i < 4; i++) {
                af[i]  = *(const bf16x8*)&As[(i * 16 + (lane & 15)) * 64 + slot];
                bfr[i] = *(const bf16x8*)&Bs[(wave * 64 + i * 16 + (lane & 15)) * 64 + slot];
            }
#pragma unroll
            for (int i = 0; i < 4; i++)
#pragma unroll
                for (int j = 0; j < 4; j++)
                    acc[i][j] = __builtin_amdgcn_mfma_f32_16x16x32_bf16(
                        af[i], bfr[j], acc[i][j], 0, 0, 0);
        }
        __syncthreads();
    }

    // ---- epilogue: +bo, gate by efp, bf16 -> eat (chunk-slot swizzled) ------
    float bo4[4];
#pragma unroll
    for (int j = 0; j < 4; j++) bo4[j] = bo[wave * 64 + j * 16 + (lane & 15)];
#pragma unroll
    for (int i = 0; i < 4; i++) {
#pragma unroll
        for (int r = 0; r < 4; r++) {
            int pos = i * 16 + ((lane >> 4) * 4) + r;
#pragma unroll
            for (int j = 0; j < 4; j++) {
                int n = wave * 64 + j * 16 + (lane & 15);
                float o = (acc[i][j][r] + bo4[j])
                          * bf2f(efp[(size_t)(m0 + pos) * 256 + n]);
                int o8 = j * 2 + ((lane >> 3) & 1);       // k-octet in chunk
                int slot = o8 ^ (pos & 7);
                eat[pos * 256 + wave * 64 + slot * 8 + (lane & 7)] = f2bf(o);
            }
        }
    }

    // ---- phase 2: Woc x eat^T -> out (wave co-split, co = wave*64 + ...) ----
    f32x4 acc2[4][4];
#pragma unroll
    for (int i = 0; i < 4; i++)
#pragma unroll
        for (int j = 0; j < 4; j++) acc2[i][j] = (f32x4){0.f, 0.f, 0.f, 0.f};

    const unsigned short* gw = Woc + (size_t)(wave * 64 + srow) * 256 + sg * 8;
    for (int k0 = 0; k0 < 256; k0 += 64) {
#pragma unroll
        for (int t = 0; t < 8; t++)
            async16(Bs + (wave * 64 + t * 8) * 64, gw + (size_t)t * 8 * 256 + k0);
        __syncthreads();
        int kc = k0 >> 6;
#pragma unroll
        for (int ks = 0; ks < 2; ks++) {
            bf16x8 af2[4], bf2_[4];
            int kb = ks * 4 + (lane >> 4);
            int slot = (kb ^ (lane & 7)) * 8;
#pragma unroll
            for (int i = 0; i < 4; i++) {
                af2[i]  = *(const bf16x8*)&Bs[(wave * 64 + i * 16 + (lane & 15)) * 64 + slot];
                bf2_[i] = *(const bf16x8*)&eat[(i * 16 + (lane & 15)) * 256 + kc * 64 + slot];
            }
#pragma unroll
            for (int i = 0; i < 4; i++)
#pragma unroll
                for (int j = 0; j < 4; j++)
                    acc2[i][j] = __builtin_amdgcn_mfma_f32_16x16x32_bf16(
                        af2[i], bf2_[j], acc2[i][j], 0, 0, 0);
        }
        __syncthreads();
    }

    // ---- BN + ReLU, store NCHW -----------------------------------------------
#pragma unroll
    for (int i = 0; i < 4; i++) {
#pragma unroll
        for (int r = 0; r < 4; r++) {
            int co = wave * 64 + i * 16 + ((lane >> 4) * 4) + r;
            float s = scv[co], hh = shv[co];
#pragma unroll
            for (int j = 0; j < 4; j++) {
                int p = m0 + j * 16 + (lane & 15);
                float o = fmaxf(fmaf(acc2[i][j][r], s, hh), 0.f);
                outp[((size_t)(p >> 12)) * 1048576 + (size_t)co * 4096 + (p & 4095)] = o;
            }
        }
    }
}

// ---------------------------------------------------------------------------
extern "C" void kernel_launch(void* const* d_in, const int* in_sizes, int n_in,
                              void* d_out, int out_size, void* d_ws, size_t ws_size,
                              hipStream_t stream)
{
    const float* e_f   = (const float*)d_in[0];
    const float* e_g   = (const float*)d_in[1];
    const float* lnfg  = (const float*)d_in[4];
    const float* lnfb  = (const float*)d_in[5];
    const float* lngg  = (const float*)d_in[6];
    const float* lngb  = (const float*)d_in[7];
    const float* wq    = (const float*)d_in[8];
    const float* bq    = (const float*)d_in[9];
    const float* wk    = (const float*)d_in[10];
    const float* bk    = (const float*)d_in[11];
    const float* wv    = (const float*)d_in[12];
    const float* bv    = (const float*)d_in[13];
    const float* wo    = (const float*)d_in[14];
    const float* bo    = (const float*)d_in[15];
    const float* dwk   = (const float*)d_in[16];
    const float* efpw  = (const float*)d_in[17];
    const float* efpb  = (const float*)d_in[18];
    const float* outcw = (const float*)d_in[19];
    const float* outcb = (const float*)d_in[20];
    const float* bng   = (const float*)d_in[21];
    const float* bnb   = (const float*)d_in[22];
    const float* bnm   = (const float*)d_in[23];
    const float* bnv   = (const float*)d_in[24];
    float* outp = (float*)d_out;

    char* base = (char*)d_ws;
    auto alloc = [&](size_t bytes) -> char* {
        char* r = base; base += (bytes + 255) & ~(size_t)255; return r;
    };
    float* pf    = (float*)alloc(8 * 32768 * 4);
    float* pfq   = (float*)alloc(8 * 32768 * 4);
    float* pg    = (float*)alloc(4 * 32768 * 4);
    float* pgq   = (float*)alloc(4 * 32768 * 4);
    float* cs1   = (float*)alloc(512 * 4);
    float* cst1  = (float*)alloc(512 * 4);
    float* cs2   = (float*)alloc(512 * 4);
    float* cst2  = (float*)alloc(512 * 4);
    float* scv   = (float*)alloc(256 * 4);
    float* shv   = (float*)alloc(256 * 4);
    float* dwt   = (float*)alloc(9 * 256 * 4);
    unsigned short* Wb1t = (unsigned short*)alloc(262144 * 2);
    unsigned short* Wb2t = (unsigned short*)alloc(65536 * 2);
    unsigned short* Wot  = (unsigned short*)alloc(65536 * 2);
    unsigned short* Woc  = (unsigned short*)alloc(65536 * 2);
    unsigned short* ef_bf = (unsigned short*)alloc((size_t)32768 * 512 * 2);
    unsigned short* eg_bf = (unsigned short*)alloc((size_t)32768 * 256 * 2);
    unsigned short* qbuf  = (unsigned short*)alloc((size_t)32768 * 256 * 2);
    unsigned short* efpbuf = (unsigned short*)alloc((size_t)32768 * 256 * 2);
    unsigned short* kfull = (unsigned short*)alloc((size_t)32768 * 256 * 2); // -> combined
    unsigned short* kpb  = (unsigned short*)alloc(128 * 256 * 2);
    float* vp    = (float*)alloc(128 * 256 * 4);
    float* s1    = (float*)alloc(128 * 256 * 4);
    float* s0    = (float*)alloc(128 * 4);

    trans_prep<<<3354, 256, 0, stream>>>(
        e_f, e_g, ef_bf, eg_bf, pf, pfq, pg, pgq,
        lnfg, lnfb, wq, bq, efpw, efpb, lngg, lngb, wk, bk, wv, bv, wo,
        outcw, outcb, bng, bnb, bnm, bnv, dwk,
        Wb1t, Wb2t, Wot, Woc, dwt, cs1, cst1, cs2, cst2, scv, shv);
    gemm_proj<<<1536, 256, 0, stream>>>(
        ef_bf, Wb1t, cs1, cst1, pf, pfq, qbuf, efpbuf,
        eg_bf, Wb2t, cs2, cst2, pg, pgq, kfull,
        e_g, s1, s0);
    pool_vp<<<256, 256, 0, stream>>>(kfull, kpb, s1, s0, lngg, wv, cs2, cst2, vp);
    combined_dw<<<2048, 256, 0, stream>>>(qbuf, kpb, vp, dwt, /*combined=*/kfull);
    gemm34_mfma<<<512, 256, 0, stream>>>(/*combined=*/kfull, Wot, bo, efpbuf,
                                         Woc, scv, shv, outp);
}

// Round 11
// 286.740 us; speedup vs baseline: 1.2926x; 1.0022x over previous
//
#include <hip/hip_runtime.h>
#include <math.h>

#define EPS 1e-5f

typedef __attribute__((ext_vector_type(8))) short bf16x8;
typedef __attribute__((ext_vector_type(4))) float f32x4;

__device__ __forceinline__ unsigned short f2bf(float f) {
    unsigned int u = __float_as_uint(f);
    u += 0x7fff + ((u >> 16) & 1);            // round-to-nearest-even
    return (unsigned short)(u >> 16);
}
__device__ __forceinline__ float bf2f(unsigned short h) {
    return __uint_as_float(((unsigned int)h) << 16);
}
__device__ __forceinline__ float lof(unsigned int u) {
    return __uint_as_float(u << 16);
}
__device__ __forceinline__ float hif(unsigned int u) {
    return __uint_as_float(u & 0xffff0000u);
}
__device__ __forceinline__ void async16(void* lds, const void* g) {
    __builtin_amdgcn_global_load_lds(
        (const __attribute__((address_space(1))) unsigned int*)g,
        (__attribute__((address_space(3))) unsigned int*)lds, 16, 0, 0);
}

// ---- merged: NCHW->bf16 transpose + LN partials (blocks 0..3071)
//      and weight-prep (blocks 3072..; constants k-parallelized) -------------
__global__ __launch_bounds__(256) void trans_prep(
    const float* __restrict__ ef, const float* __restrict__ eg,
    unsigned short* __restrict__ ef_bf, unsigned short* __restrict__ eg_bf,
    float* __restrict__ pf, float* __restrict__ pfq,
    float* __restrict__ pg, float* __restrict__ pgq,
    const float* __restrict__ lnfg, const float* __restrict__ lnfb,
    const float* __restrict__ wq, const float* __restrict__ bq,
    const float* __restrict__ efpw, const float* __restrict__ efpb,
    const float* __restrict__ lngg, const float* __restrict__ lngb,
    const float* __restrict__ wk, const float* __restrict__ bk,
    const float* __restrict__ wv, const float* __restrict__ bv,
    const float* __restrict__ wo, const float* __restrict__ outcw,
    const float* __restrict__ outcb, const float* __restrict__ bng,
    const float* __restrict__ bnb, const float* __restrict__ bnm,
    const float* __restrict__ bnv, const float* __restrict__ dwk,
    unsigned short* __restrict__ Wb1t, unsigned short* __restrict__ Wb2t,
    unsigned short* __restrict__ Wot, unsigned short* __restrict__ Woc,
    float* __restrict__ dwt,
    float* __restrict__ cs1, float* __restrict__ cst1,
    float* __restrict__ cs2, float* __restrict__ cst2,
    float* __restrict__ scv, float* __restrict__ shv)
{
    __shared__ float tile[64][65];
    __shared__ float psum[4][64], pss[4][64];
    int id = blockIdx.x;
    int t = threadIdx.x;
    if (id < 3072) {
        // ---------------- transpose path (r3 verbatim) ----------------
        const float* src; unsigned short* dst; float* ps; float* pq;
        int C, cblk, b, p0;
        if (id < 2048) {                          // e_f: 8b x 8cblk x 32ptile
            src = ef; dst = ef_bf; ps = pf; pq = pfq; C = 512;
            b = id >> 8; cblk = (id >> 5) & 7; p0 = (id & 31) * 128;
        } else {                                  // e_g: 8b x 4cblk x 32ptile
            id -= 2048;
            src = eg; dst = eg_bf; ps = pg; pq = pgq; C = 256;
            b = id >> 7; cblk = (id >> 5) & 3; p0 = (id & 31) * 128;
        }
        int c0 = cblk * 64;
        const float* s = src + ((size_t)b * C + c0) * 4096 + p0;
        int cr = t >> 4, p4 = (t & 15) * 4;
        int lane = t & 63, grp = t >> 6;
        int pr = t >> 3, c8 = (t & 7) * 8;

        float4 r1[4], r2[4];
#pragma unroll
        for (int i = 0; i < 4; i++)
            r1[i] = *(const float4*)(s + (size_t)(i * 16 + cr) * 4096 + p4);
#pragma unroll
        for (int i = 0; i < 4; i++)
            r2[i] = *(const float4*)(s + (size_t)(i * 16 + cr) * 4096 + 64 + p4);

#pragma unroll
        for (int half = 0; half < 2; half++) {
#pragma unroll
            for (int i = 0; i < 4; i++) {
                float4 v = half ? r2[i] : r1[i];
                int c = i * 16 + cr;
                tile[c][p4 + 0] = v.x; tile[c][p4 + 1] = v.y;
                tile[c][p4 + 2] = v.z; tile[c][p4 + 3] = v.w;
            }
            __syncthreads();

            int pbase = p0 + half * 64;
            unsigned short* d = dst + ((size_t)(b * 4096 + pbase)) * C + c0;
#pragma unroll
            for (int i = 0; i < 2; i++) {
                int p = i * 32 + pr;
                uint4 pk;
                pk.x = (unsigned)f2bf(tile[c8 + 0][p]) | ((unsigned)f2bf(tile[c8 + 1][p]) << 16);
                pk.y = (unsigned)f2bf(tile[c8 + 2][p]) | ((unsigned)f2bf(tile[c8 + 3][p]) << 16);
                pk.z = (unsigned)f2bf(tile[c8 + 4][p]) | ((unsigned)f2bf(tile[c8 + 5][p]) << 16);
                pk.w = (unsigned)f2bf(tile[c8 + 6][p]) | ((unsigned)f2bf(tile[c8 + 7][p]) << 16);
                *(uint4*)(d + (size_t)p * C + c8) = pk;
            }

            float sm = 0.f, sq = 0.f;
#pragma unroll
            for (int j = 0; j < 16; j++) {
                float v = tile[grp * 16 + j][lane];
                sm += v; sq += v * v;
            }
            psum[grp][lane] = sm; pss[grp][lane] = sq;
            __syncthreads();
            if (t < 64) {
                float fs = psum[0][t] + psum[1][t] + psum[2][t] + psum[3][t];
                float fq = pss[0][t] + pss[1][t] + pss[2][t] + pss[3][t];
                ps[cblk * 32768 + b * 4096 + pbase + t] = fs;
                pq[cblk * 32768 + b * 4096 + pbase + t] = fq;
            }
            if (half == 0) __syncthreads();       // tile reuse fence
        }
    } else {
        int id2 = id - 3072;
        float* red1 = (float*)psum;               // 256-float scratch
        float* red2 = (float*)pss;
        if (id2 < 64) {
            // -- LDS-tiled 64x64 weight transpose (coalesced both sides) --
            const float* src; unsigned short* dst; const float* scale;
            int K, k0, n0;
            if (id2 < 32) {            // Wb1t-q: wq[512][256] -> [n<256][512]
                src = wq; dst = Wb1t; scale = lnfg; K = 512;
                k0 = (id2 >> 2) * 64; n0 = (id2 & 3) * 64;
            } else if (id2 < 48) {     // Wb2t: wk[256][256] -> [n][256]
                int j = id2 - 32;
                src = wk; dst = Wb2t; scale = lngg; K = 256;
                k0 = (j >> 2) * 64; n0 = (j & 3) * 64;
            } else {                   // Wot: wo[256][256] -> [n][256]
                int j = id2 - 48;
                src = wo; dst = Wot; scale = nullptr; K = 256;
                k0 = (j >> 2) * 64; n0 = (j & 3) * 64;
            }
            int rr = t >> 6, cc = t & 63;
#pragma unroll
            for (int i = 0; i < 16; i++) {
                int r = i * 4 + rr;
                tile[r][cc] = src[(size_t)(k0 + r) * 256 + n0 + cc];
            }
            __syncthreads();
            int nn = t >> 3, k8 = (t & 7) * 8;
#pragma unroll
            for (int i = 0; i < 2; i++) {
                int n = i * 32 + nn;
                float v[8];
#pragma unroll
                for (int j = 0; j < 8; j++) {
                    float s = scale ? scale[k0 + k8 + j] : 1.f;
                    v[j] = s * tile[k8 + j][n];
                }
                uint4 pk;
                pk.x = (unsigned)f2bf(v[0]) | ((unsigned)f2bf(v[1]) << 16);
                pk.y = (unsigned)f2bf(v[2]) | ((unsigned)f2bf(v[3]) << 16);
                pk.z = (unsigned)f2bf(v[4]) | ((unsigned)f2bf(v[5]) << 16);
                pk.w = (unsigned)f2bf(v[6]) | ((unsigned)f2bf(v[7]) << 16);
                *(uint4*)(dst + (size_t)(n0 + n) * K + k0 + k8) = pk;
            }
        } else if (id2 < 192) {        // Wb1t-efp half: row-major copy-convert
            int j = (id2 - 64) * 1024 + t * 4;
            float4 v = *(const float4*)(efpw + j);
            uint2 pk;
            pk.x = (unsigned)f2bf(v.x) | ((unsigned)f2bf(v.y) << 16);
            pk.y = (unsigned)f2bf(v.z) | ((unsigned)f2bf(v.w) << 16);
            *(uint2*)(Wb1t + 131072 + j) = pk;
        } else if (id2 < 256) {        // Woc copy-convert
            int j = (id2 - 192) * 1024 + t * 4;
            float4 v = *(const float4*)(outcw + j);
            uint2 pk;
            pk.x = (unsigned)f2bf(v.x) | ((unsigned)f2bf(v.y) << 16);
            pk.y = (unsigned)f2bf(v.z) | ((unsigned)f2bf(v.w) << 16);
            *(uint2*)(Woc + j) = pk;
        } else if (id2 == 256) {       // dwt [tap][ch]
#pragma unroll
            for (int tap = 0; tap < 9; tap++)
                dwt[tap * 256 + t] = dwk[t * 9 + tap];
        } else if (id2 < 265) {        // cs1/cst1: 8 blocks x 32 n, k-parallel
            int n0 = (id2 - 257) * 32;
            int nl = t & 31, kq = t >> 5;         // 8 k-groups of 64
            float cs = 0.f, ct = 0.f;
#pragma unroll 4
            for (int kk = 0; kk < 64; kk++) {
                int k = kq * 64 + kk;
                float w = wq[k * 256 + n0 + nl];
                cs += lnfg[k] * w; ct += lnfb[k] * w;
            }
            red1[kq * 32 + nl] = cs; red2[kq * 32 + nl] = ct;
            __syncthreads();
            if (t < 32) {
                float s = 0.f, c2 = 0.f;
#pragma unroll
                for (int q = 0; q < 8; q++) { s += red1[q * 32 + t]; c2 += red2[q * 32 + t]; }
                int n = n0 + t;
                cs1[n] = s; cst1[n] = c2 + bq[n];
                cs1[256 + n] = 0.f; cst1[256 + n] = efpb[n];
            }
        } else if (id2 < 273) {        // cs2-k: 8 blocks x 32 n, k-parallel
            int n0 = (id2 - 265) * 32;
            int nl = t & 31, kq = t >> 5;         // 8 k-groups of 32
            float cs = 0.f, ct = 0.f;
#pragma unroll 4
            for (int kk = 0; kk < 32; kk++) {
                int k = kq * 32 + kk;
                float w = wk[k * 256 + n0 + nl];
                cs += lngg[k] * w; ct += lngb[k] * w;
            }
            red1[kq * 32 + nl] = cs; red2[kq * 32 + nl] = ct;
            __syncthreads();
            if (t < 32) {
                float s = 0.f, c2 = 0.f;
#pragma unroll
                for (int q = 0; q < 8; q++) { s += red1[q * 32 + t]; c2 += red2[q * 32 + t]; }
                int n = n0 + t;
                cs2[n] = s; cst2[n] = c2 + bk[n];
            }
        } else if (id2 < 281) {        // cs2-v: 8 blocks x 32 n, k-parallel
            int n0 = (id2 - 273) * 32;
            int nl = t & 31, kq = t >> 5;
            float cs = 0.f, ct = 0.f;
#pragma unroll 4
            for (int kk = 0; kk < 32; kk++) {
                int k = kq * 32 + kk;
                float w = wv[k * 256 + n0 + nl];
                cs += lngg[k] * w; ct += lngb[k] * w;
            }
            red1[kq * 32 + nl] = cs; red2[kq * 32 + nl] = ct;
            __syncthreads();
            if (t < 32) {
                float s = 0.f, c2 = 0.f;
#pragma unroll
                for (int q = 0; q < 8; q++) { s += red1[q * 32 + t]; c2 += red2[q * 32 + t]; }
                int n = n0 + t;
                cs2[256 + n] = s; cst2[256 + n] = c2 + bv[n];
            }
        } else {                       // id2 == 281: BN constants
            int n = t;
            float s = bng[n] * rsqrtf(bnv[n] + EPS);
            scv[n] = s;
            shv[n] = (outcb[n] - bnm[n]) * s + bnb[n];
        }
    }
}

// ---------------- MFMA GEMM core (m97-style, 128x128) -----------------------
template<int K>
__device__ __forceinline__ void mfma_core(
    const unsigned short* __restrict__ A, const unsigned short* __restrict__ Bt,
    int m0, int n0, unsigned short* As, unsigned short* Bs, f32x4 acc[4][4])
{
    const int tid = threadIdx.x;
    const int wave = tid >> 6, lane = tid & 63;
    const int wm = (wave & 1) * 64, wn = (wave >> 1) * 64;
#pragma unroll
    for (int i = 0; i < 4; i++)
#pragma unroll
        for (int j = 0; j < 4; j++) acc[i][j] = (f32x4){0.f, 0.f, 0.f, 0.f};

    const int srow = wave * 32 + (lane >> 3);
    const int sg = (lane & 7) ^ ((lane >> 3) & 7);
    const unsigned short* ga = A + (size_t)(m0 + srow) * K + sg * 8;
    const unsigned short* gb = Bt + (size_t)(n0 + srow) * K + sg * 8;

    for (int k0 = 0; k0 < K; k0 += 64) {
#pragma unroll
        for (int t = 0; t < 4; t++) {
            async16(As + (wave * 32 + t * 8) * 64, ga + (size_t)t * 8 * K + k0);
            async16(Bs + (wave * 32 + t * 8) * 64, gb + (size_t)t * 8 * K + k0);
        }
        __syncthreads();
#pragma unroll
        for (int ks = 0; ks < 2; ks++) {
            bf16x8 af[4], bfr[4];
            int kb = ks * 4 + (lane >> 4);
            int slot = (kb ^ (lane & 7)) * 8;
#pragma unroll
            for (int i = 0; i < 4; i++) {
                int m = wm + i * 16 + (lane & 15);
                af[i] = *(const bf16x8*)&As[m * 64 + slot];
                int n = wn + i * 16 + (lane & 15);
                bfr[i] = *(const bf16x8*)&Bs[n * 64 + slot];
            }
#pragma unroll
            for (int i = 0; i < 4; i++)
#pragma unroll
                for (int j = 0; j < 4; j++)
                    acc[i][j] = __builtin_amdgcn_mfma_f32_16x16x32_bf16(
                        af[i], bfr[j], acc[i][j], 0, 0, 0);
        }
        __syncthreads();
    }
}

// ---- merged projection GEMMs + v-pool partials:
//      blocks 0..511   = gemm1 (ef_bf x Wb1t -> q|efp, 128m x 256n, LN)
//      blocks 512..1023 = gemm2k (eg_bf x Wb2t -> kfull, 128m x 128n, LN)
//      blocks 1024..1535 = weighted v-pool partials (stats inline from pg/pgq)
__global__ __launch_bounds__(256, 2) void gemm_proj(
    const unsigned short* __restrict__ ef_bf, const unsigned short* __restrict__ Wb1t,
    const float* __restrict__ cs1, const float* __restrict__ cst1,
    const float* __restrict__ pf, const float* __restrict__ pfq,
    unsigned short* __restrict__ qbuf, unsigned short* __restrict__ efpbuf,
    const unsigned short* __restrict__ eg_bf, const unsigned short* __restrict__ Wb2t,
    const float* __restrict__ cs2, const float* __restrict__ cst2,
    const float* __restrict__ pg, const float* __restrict__ pgq,
    unsigned short* __restrict__ kfull,
    const float* __restrict__ eg, float* __restrict__ s1,
    float* __restrict__ s0)
{
    __shared__ unsigned short As[128 * 64];   // 16 KB
    __shared__ unsigned short Bs[256 * 64];   // 32 KB (v-pool reuses as float)
    __shared__ float sstat[256];              // mean[128] | rstd[128]
    const int tid = threadIdx.x;
    const int wave = tid >> 6, lane = tid & 63;
    const int bid = blockIdx.x;

    if (bid < 512) {
        // ------------------------- gemm1 path -------------------------
        const int m0 = (bid >> 1) * 128, n0 = (bid & 1) * 256;
        const int wm = (wave & 1) * 64, wn = (wave >> 1) * 128;
        f32x4 acc[4][8];

        if (tid < 128) {                      // LN finalize for this block's rows
            int gm = m0 + tid;
            float s = 0.f, q = 0.f;
#pragma unroll
            for (int i = 0; i < 8; i++) { s += pf[i * 32768 + gm]; q += pfq[i * 32768 + gm]; }
            float m = s * (1.f / 512.f);
            sstat[tid] = m;
            sstat[128 + tid] = rsqrtf(q * (1.f / 512.f) - m * m + EPS);
        }

#pragma unroll
        for (int i = 0; i < 4; i++)
#pragma unroll
            for (int j = 0; j < 8; j++) acc[i][j] = (f32x4){0.f, 0.f, 0.f, 0.f};

        const int srow = lane >> 3;
        const int sg = (lane & 7) ^ (srow & 7);
        const unsigned short* ga = ef_bf + (size_t)(m0 + wave * 32 + srow) * 512 + sg * 8;
        const unsigned short* gb = Wb1t + (size_t)(n0 + wave * 64 + srow) * 512 + sg * 8;

        for (int k0 = 0; k0 < 512; k0 += 64) {
#pragma unroll
            for (int t = 0; t < 4; t++)
                async16(As + (wave * 32 + t * 8) * 64, ga + (size_t)t * 8 * 512 + k0);
#pragma unroll
            for (int t = 0; t < 8; t++)
                async16(Bs + (wave * 64 + t * 8) * 64, gb + (size_t)t * 8 * 512 + k0);
            __syncthreads();
#pragma unroll
            for (int ks = 0; ks < 2; ks++) {
                bf16x8 af[4], bfr[8];
                int kb = ks * 4 + (lane >> 4);
                int slot = (kb ^ (lane & 7)) * 8;
#pragma unroll
                for (int i = 0; i < 4; i++)
                    af[i] = *(const bf16x8*)&As[(wm + i * 16 + (lane & 15)) * 64 + slot];
#pragma unroll
                for (int j = 0; j < 8; j++)
                    bfr[j] = *(const bf16x8*)&Bs[(wn + j * 16 + (lane & 15)) * 64 + slot];
#pragma unroll
                for (int i = 0; i < 4; i++)
#pragma unroll
                    for (int j = 0; j < 8; j++)
                        acc[i][j] = __builtin_amdgcn_mfma_f32_16x16x32_bf16(
                            af[i], bfr[j], acc[i][j], 0, 0, 0);
            }
            __syncthreads();
        }

        bool isq = (n0 == 0);
#pragma unroll
        for (int i = 0; i < 4; i++) {
#pragma unroll
            for (int r = 0; r < 4; r++) {
                int lm = wm + i * 16 + ((lane >> 4) * 4) + r;
                int gm = m0 + lm;
                float mean = sstat[lm], rs = sstat[128 + lm];
#pragma unroll
                for (int j = 0; j < 8; j++) {
                    int nn = wn + j * 16 + (lane & 15);   // 0..255 within half
                    float v = acc[i][j][r];
                    if (isq) {
                        int n = nn;
                        float o = rs * (v - mean * cs1[n]) + cst1[n];
                        qbuf[(size_t)gm * 256 + nn] = f2bf(o);
                    } else {
                        int n = nn + 256;
                        efpbuf[(size_t)gm * 256 + nn] = f2bf(v + cst1[n]);
                    }
                }
            }
        }
    } else if (bid < 1024) {
        // ------------------------- gemm2k path ------------------------
        const int j2 = bid - 512;
        const int m0 = (j2 >> 1) * 128, n0 = (j2 & 1) * 128;
        f32x4 acc[4][4];

        if (tid < 128) {
            int gm = m0 + tid;
            float s = 0.f, q = 0.f;
#pragma unroll
            for (int i = 0; i < 4; i++) { s += pg[i * 32768 + gm]; q += pgq[i * 32768 + gm]; }
            float m = s * (1.f / 256.f);
            float r = rsqrtf(q * (1.f / 256.f) - m * m + EPS);
            sstat[tid] = m; sstat[128 + tid] = r;
        }

        mfma_core<256>(eg_bf, Wb2t, m0, n0, As, Bs, acc);
        int wm = (wave & 1) * 64, wn = (wave >> 1) * 64;
#pragma unroll
        for (int i = 0; i < 4; i++) {
#pragma unroll
            for (int r = 0; r < 4; r++) {
                int lm = wm + i * 16 + ((lane >> 4) * 4) + r;
                int gm = m0 + lm;
                float mean = sstat[lm], rs = sstat[128 + lm];
#pragma unroll
                for (int j = 0; j < 4; j++) {
                    int n = n0 + wn + j * 16 + (lane & 15);
                    float o = rs * (acc[i][j][r] - mean * cs2[n]) + cst2[n];
                    kfull[(size_t)gm * 256 + n] = f2bf(o);
                }
            }
        }
    } else {
        // ---- weighted v-pool partials (moved from pool_phase) ---------
        float* smem = (float*)Bs;             // 8192 floats avail, need 4352
        const int id3 = bid - 1024;
        int b = id3 >> 6, hp = (id3 >> 4) & 3, cgrp = id3 & 15;
        int rr = tid >> 4, cq = tid & 15;
        int p = (hp * 16 + rr) * 64 + cq * 4;

        // inline LN-stat finalize (bit-identical to old mg/rg values)
        float w[4], m[4];
#pragma unroll
        for (int d = 0; d < 4; d++) {
            int gp = b * 4096 + p + d;
            float s = 0.f, q = 0.f;
#pragma unroll
            for (int i = 0; i < 4; i++) { s += pg[i * 32768 + gp]; q += pgq[i * 32768 + gp]; }
            float mean = s * (1.f / 256.f);
            m[d] = mean;
            w[d] = rsqrtf(q * (1.f / 256.f) - mean * mean + EPS);
        }

        float part[16];
        const float* egb = eg + ((size_t)b * 256 + cgrp * 16) * 4096 + p;
#pragma unroll
        for (int cc = 0; cc < 16; cc++) {
            float4 v4 = *(const float4*)(egb + (size_t)cc * 4096);
            part[cc] = w[0] * v4.x + w[1] * v4.y + w[2] * v4.z + w[3] * v4.w;
        }
#pragma unroll
        for (int cc = 0; cc < 16; cc++) smem[tid * 16 + cc] = part[cc];
        if (cgrp == 0)
            smem[4096 + tid] = w[0] * m[0] + w[1] * m[1] + w[2] * m[2] + w[3] * m[3];
        __syncthreads();
        if (tid < 64) {
            int cx2 = tid >> 4, cc = tid & 15;
            float sacc = 0.f;
#pragma unroll
            for (int rr2 = 0; rr2 < 16; rr2++)
#pragma unroll
                for (int dq = 0; dq < 4; dq++)
                    sacc += smem[(rr2 * 16 + cx2 * 4 + dq) * 16 + cc];
            s1[((size_t)(b * 16 + hp * 4 + cx2)) * 256 + cgrp * 16 + cc] = sacc;
        }
        if (cgrp == 0 && tid < 4) {
            float sacc = 0.f;
#pragma unroll
            for (int rr2 = 0; rr2 < 16; rr2++)
#pragma unroll
                for (int dq = 0; dq < 4; dq++)
                    sacc += smem[4096 + rr2 * 16 + tid * 4 + dq];
            s0[b * 16 + hp * 4 + tid] = sacc;
        }
    }
}

// ---- merged pool tail: blocks 0..127 k-maxpool; 128..255 v-pool mini-GEMM --
__global__ __launch_bounds__(256) void pool_vp(
    const unsigned short* __restrict__ kfull, unsigned short* __restrict__ kpb,
    const float* __restrict__ s1, const float* __restrict__ s0,
    const float* __restrict__ lngg, const float* __restrict__ wv,
    const float* __restrict__ cs2, const float* __restrict__ cst2,
    float* __restrict__ vp)
{
    __shared__ float smem[2048];
    int id = blockIdx.x;
    int t = threadIdx.x;
    if (id < 128) {
        // ---- k max pool: (b, cell) ----
        int b = id >> 4, cell = id & 15;
        int hp = cell >> 2, wp = cell & 3;
        int g8 = t & 31, rr = t >> 5;
        float kmx[8];
#pragma unroll
        for (int j = 0; j < 8; j++) kmx[j] = -3.402823466e38f;
#pragma unroll
        for (int rsub = 0; rsub < 2; rsub++) {
            int r = rr * 2 + rsub;
            int prow = (hp * 16 + r) * 64 + wp * 16;
            for (int cl = 0; cl < 16; cl++) {
                size_t basei = ((size_t)(b * 4096 + prow + cl)) * 256 + g8 * 8;
                uint4 kv = *(const uint4*)(kfull + basei);
                kmx[0] = fmaxf(kmx[0], lof(kv.x)); kmx[1] = fmaxf(kmx[1], hif(kv.x));
                kmx[2] = fmaxf(kmx[2], lof(kv.y)); kmx[3] = fmaxf(kmx[3], hif(kv.y));
                kmx[4] = fmaxf(kmx[4], lof(kv.z)); kmx[5] = fmaxf(kmx[5], hif(kv.z));
                kmx[6] = fmaxf(kmx[6], lof(kv.w)); kmx[7] = fmaxf(kmx[7], hif(kv.w));
            }
        }
#pragma unroll
        for (int j = 0; j < 8; j++) smem[rr * 256 + g8 * 8 + j] = kmx[j];
        __syncthreads();
        float m = smem[t];
#pragma unroll
        for (int r2 = 1; r2 < 8; r2++) m = fmaxf(m, smem[r2 * 256 + t]);
        kpb[(size_t)(b * 16 + cell) * 256 + t] = f2bf(m);   // lossless
    } else {
        // ---- v-pool mini-GEMM: vp[cell][n] from s1/s0 (fp32 exact) ----
        int cell = id - 128;          // 0..127 = b*16+cell
        int n = t;
        const float* s1r = s1 + (size_t)cell * 256;
        float acc = 0.f;
        for (int c = 0; c < 256; c++)
            acc = fmaf(lngg[c] * s1r[c], wv[c * 256 + n], acc);
        vp[(size_t)cell * 256 + n] = acc * (1.f / 256.f)
            - (s0[cell] * (1.f / 256.f)) * cs2[256 + n] + cst2[256 + n];
    }
}

// ---- combined = attn@vp + dw3x3(q): one image row per block, 4 waves x
//      16 positions each. Every wave: scores -> softmax -> PV + dw conv.
//      (score/PV/dw bodies verbatim from proven r5 fused kernel.) -----------
__global__ __launch_bounds__(256) void combined_dw(
    const unsigned short* __restrict__ qbuf, const unsigned short* __restrict__ kpb,
    const float* __restrict__ vp, const float* __restrict__ dwt,
    unsigned short* __restrict__ combined)
{
    __shared__ float attns[1024];         // [wave][16 pos][16 cells]
    int wave = threadIdx.x >> 6, lane = threadIdx.x & 63;
    int id = blockIdx.x;                  // 512
    int b = id & 7, row = id >> 3;        // batch pinned per XCD
    int pidx0 = row * 64 + wave * 16;     // this wave's 16 positions
    int h = row;

    // ---- scores + softmax for this wave's 16 positions ----
    {
        int fr = lane & 15, quad = lane >> 4;
        const unsigned short* qrow =
            qbuf + (size_t)(b * 4096 + pidx0 + fr) * 256 + quad * 8;
        const unsigned short* krow = kpb + (size_t)(b * 16 + fr) * 256 + quad * 8;
        f32x4 sacc = {0.f, 0.f, 0.f, 0.f};
#pragma unroll
        for (int ks = 0; ks < 8; ks++) {
            bf16x8 af = *(const bf16x8*)(qrow + ks * 32);
            bf16x8 bf_ = *(const bf16x8*)(krow + ks * 32);
            sacc = __builtin_amdgcn_mfma_f32_16x16x32_bf16(af, bf_, sacc, 0, 0, 0);
        }
#pragma unroll
        for (int r = 0; r < 4; r++) {
            float s = sacc[r] * 0.0625f;  // HID^-0.5
            float mx = s;
#pragma unroll
            for (int off = 8; off >= 1; off >>= 1) mx = fmaxf(mx, __shfl_xor(mx, off));
            float e = __expf(s - mx);
            float sum = e;
#pragma unroll
            for (int off = 8; off >= 1; off >>= 1) sum += __shfl_xor(sum, off);
            attns[wave * 256 + (quad * 4 + r) * 16 + fr] = e / sum;
        }
    }
    __syncthreads();                      // LDS visibility (per-wave segments)

    int o4 = lane * 4;
    float4 kreg[9];
#pragma unroll
    for (int tap = 0; tap < 9; tap++)
        kreg[tap] = *(const float4*)&dwt[tap * 256 + o4];
    const float* arow_base = attns + wave * 256;

#pragma unroll
    for (int sub = 0; sub < 4; sub++) {
        int pidx = pidx0 + sub * 4;
        int w0 = pidx & 63;
        float4 acc[4];
#pragma unroll
        for (int i = 0; i < 4; i++) acc[i] = (float4){0.f, 0.f, 0.f, 0.f};
#pragma unroll
        for (int c = 0; c < 16; c++) {
            float4 v = *(const float4*)&vp[(size_t)(b * 16 + c) * 256 + o4];
#pragma unroll
            for (int i = 0; i < 4; i++) {
                float a = arow_base[(sub * 4 + i) * 16 + c];
                acc[i].x = fmaf(a, v.x, acc[i].x); acc[i].y = fmaf(a, v.y, acc[i].y);
                acc[i].z = fmaf(a, v.z, acc[i].z); acc[i].w = fmaf(a, v.w, acc[i].w);
            }
        }
#pragma unroll
        for (int dy = 0; dy < 3; dy++) {
            int hh = h + dy - 1;
            if (hh < 0 || hh > 63) continue;
            const unsigned short* qr = qbuf + ((size_t)(b * 4096 + hh * 64)) * 256;
            float4 ft[6];
#pragma unroll
            for (int c = 0; c < 6; c++) {
                int xx = w0 - 1 + c;
                if (xx < 0 || xx > 63) {
                    ft[c] = (float4){0.f, 0.f, 0.f, 0.f};
                } else {
                    uint2 qa = *(const uint2*)(qr + (size_t)xx * 256 + o4);
                    ft[c] = (float4){lof(qa.x), hif(qa.x), lof(qa.y), hif(qa.y)};
                }
            }
#pragma unroll
            for (int dx = 0; dx < 3; dx++) {
                float4 kk = kreg[dy * 3 + dx];
#pragma unroll
                for (int i = 0; i < 4; i++) {
                    float4 qv = ft[i + dx];
                    acc[i].x = fmaf(qv.x, kk.x, acc[i].x);
                    acc[i].y = fmaf(qv.y, kk.y, acc[i].y);
                    acc[i].z = fmaf(qv.z, kk.z, acc[i].z);
                    acc[i].w = fmaf(qv.w, kk.w, acc[i].w);
                }
            }
        }
#pragma unroll
        for (int i = 0; i < 4; i++) {
            uint2 pk;
            pk.x = (unsigned)f2bf(acc[i].x) | ((unsigned)f2bf(acc[i].y) << 16);
            pk.y = (unsigned)f2bf(acc[i].z) | ((unsigned)f2bf(acc[i].w) << 16);
            *(uint2*)(combined + ((size_t)(b * 4096 + pidx + i)) * 256 + o4) = pk;
        }
    }
}

// ------ GEMM3+4 fused: comb x Wot -> +bo, gate(efp) -> ea in LDS;
//        then Woc x ea^T -> out NCHW with BN+ReLU. 64 pos x 256 per block. ---
__global__ __launch_bounds__(256) void gemm34_mfma(
    const unsigned short* __restrict__ comb, const unsigned short* __restrict__ Wot,
    const float* __restrict__ bo, const unsigned short* __restrict__ efp,
    const unsigned short* __restrict__ Woc,
    const float* __restrict__ scv, const float* __restrict__ shv,
    float* __restrict__ outp)
{
    __shared__ unsigned short As[64 * 64];    // 8 KB  : phase1 A (64 pos x 64 k)
    __shared__ unsigned short Bs[256 * 64];   // 32 KB : phase1 Wot / phase2 Woc
    __shared__ unsigned short eat[64 * 256];  // 32 KB : gated ea tile (swizzled)
    const int tid = threadIdx.x;
    const int wave = tid >> 6, lane = tid & 63;
    const int m0 = blockIdx.x * 64;

    const int srow = lane >> 3;               // 0..7
    const int sg = (lane & 7) ^ (srow & 7);   // pre-swizzled k-chunk (m173)

    // ---- phase 1: comb[m0..m0+63][:] x Wot -> acc (wave n-split wn=wave*64) -
    f32x4 acc[4][4];
#pragma unroll
    for (int i = 0; i < 4; i++)
#pragma unroll
        for (int j = 0; j < 4; j++) acc[i][j] = (f32x4){0.f, 0.f, 0.f, 0.f};

    const unsigned short* ga = comb + (size_t)(m0 + wave * 16 + srow) * 256 + sg * 8;
    const unsigned short* gb = Wot + (size_t)(wave * 64 + srow) * 256 + sg * 8;

    for (int k0 = 0; k0 < 256; k0 += 64) {
#pragma unroll
        for (int t = 0; t < 2; t++)
            async16(As + (wave * 16 + t * 8) * 64, ga + (size_t)t * 8 * 256 + k0);
#pragma unroll
        for (int t = 0; t < 8; t++)
            async16(Bs + (wave * 64 + t * 8) * 64, gb + (size_t)t * 8 * 256 + k0);
        __syncthreads();
#pragma unroll
        for (int ks = 0; ks < 2; ks++) {
            bf16x8 af[4], bfr[4];
            int kb = ks * 4 + (lane >> 4);
            int slot = (kb ^ (lane & 7)) * 8;
#pragma unroll
            for (int i = 0; i < 4; i++) {
                af[i]  = *(const bf16x8*)&As[(i * 16 + (lane & 15)) * 64 + slot];
                bfr[i] = *(const bf16x8*)&Bs[(wave * 64 + i * 16 + (lane & 15)) * 64 + slot];
            }
#pragma unroll
            for (int i = 0; i < 4; i++)
#pragma unroll
                for (int j = 0; j < 4; j++)
                    acc[i][j] = __builtin_amdgcn_mfma_f32_16x16x32_bf16(
                        af[i], bfr[j], acc[i][j], 0, 0, 0);
        }
        __syncthreads();
    }

    // ---- epilogue: +bo, gate by efp, bf16 -> eat (chunk-slot swizzled) ------
    float bo4[4];
#pragma unroll
    for (int j = 0; j < 4; j++) bo4[j] = bo[wave * 64 + j * 16 + (lane & 15)];
#pragma unroll
    for (int i = 0; i < 4; i++) {
#pragma unroll
        for (int r = 0; r < 4; r++) {
            int pos = i * 16 + ((lane >> 4) * 4) + r;
#pragma unroll
            for (int j = 0; j < 4; j++) {
                int n = wave * 64 + j * 16 + (lane & 15);
                float o = (acc[i][j][r] + bo4[j])
                          * bf2f(efp[(size_t)(m0 + pos) * 256 + n]);
                int o8 = j * 2 + ((lane >> 3) & 1);       // k-octet in chunk
                int slot = o8 ^ (pos & 7);
                eat[pos * 256 + wave * 64 + slot * 8 + (lane & 7)] = f2bf(o);
            }
        }
    }

    // ---- phase 2: Woc x eat^T -> out (wave co-split, co = wave*64 + ...) ----
    f32x4 acc2[4][4];
#pragma unroll
    for (int i = 0; i < 4; i++)
#pragma unroll
        for (int j = 0; j < 4; j++) acc2[i][j] = (f32x4){0.f, 0.f, 0.f, 0.f};

    const unsigned short* gw = Woc + (size_t)(wave * 64 + srow) * 256 + sg * 8;
    for (int k0 = 0; k0 < 256; k0 += 64) {
#pragma unroll
        for (int t = 0; t < 8; t++)
            async16(Bs + (wave * 64 + t * 8) * 64, gw + (size_t)t * 8 * 256 + k0);
        __syncthreads();
        int kc = k0 >> 6;
#pragma unroll
        for (int ks = 0; ks < 2; ks++) {
            bf16x8 af2[4], bf2_[4];
            int kb = ks * 4 + (lane >> 4);
            int slot = (kb ^ (lane & 7)) * 8;
#pragma unroll
            for (int i = 0; i < 4; i++) {
                af2[i]  = *(const bf16x8*)&Bs[(wave * 64 + i * 16 + (lane & 15)) * 64 + slot];
                bf2_[i] = *(const bf16x8*)&eat[(i * 16 + (lane & 15)) * 256 + kc * 64 + slot];
            }
#pragma unroll
            for (int i = 0; i < 4; i++)
#pragma unroll
                for (int j = 0; j < 4; j++)
                    acc2[i][j] = __builtin_amdgcn_mfma_f32_16x16x32_bf16(
                        af2[i], bf2_[j], acc2[i][j], 0, 0, 0);
        }
        __syncthreads();
    }

    // ---- BN + ReLU, store NCHW -----------------------------------------------
#pragma unroll
    for (int i = 0; i < 4; i++) {
#pragma unroll
        for (int r = 0; r < 4; r++) {
            int co = wave * 64 + i * 16 + ((lane >> 4) * 4) + r;
            float s = scv[co], hh = shv[co];
#pragma unroll
            for (int j = 0; j < 4; j++) {
                int p = m0 + j * 16 + (lane & 15);
                float o = fmaxf(fmaf(acc2[i][j][r], s, hh), 0.f);
                outp[((size_t)(p >> 12)) * 1048576 + (size_t)co * 4096 + (p & 4095)] = o;
            }
        }
    }
}

// ---------------------------------------------------------------------------
extern "C" void kernel_launch(void* const* d_in, const int* in_sizes, int n_in,
                              void* d_out, int out_size, void* d_ws, size_t ws_size,
                              hipStream_t stream)
{
    const float* e_f   = (const float*)d_in[0];
    const float* e_g   = (const float*)d_in[1];
    const float* lnfg  = (const float*)d_in[4];
    const float* lnfb  = (const float*)d_in[5];
    const float* lngg  = (const float*)d_in[6];
    const float* lngb  = (const float*)d_in[7];
    const float* wq    = (const float*)d_in[8];
    const float* bq    = (const float*)d_in[9];
    const float* wk    = (const float*)d_in[10];
    const float* bk    = (const float*)d_in[11];
    const float* wv    = (const float*)d_in[12];
    const float* bv    = (const float*)d_in[13];
    const float* wo    = (const float*)d_in[14];
    const float* bo    = (const float*)d_in[15];
    const float* dwk   = (const float*)d_in[16];
    const float* efpw  = (const float*)d_in[17];
    const float* efpb  = (const float*)d_in[18];
    const float* outcw = (const float*)d_in[19];
    const float* outcb = (const float*)d_in[20];
    const float* bng   = (const float*)d_in[21];
    const float* bnb   = (const float*)d_in[22];
    const float* bnm   = (const float*)d_in[23];
    const float* bnv   = (const float*)d_in[24];
    float* outp = (float*)d_out;

    char* base = (char*)d_ws;
    auto alloc = [&](size_t bytes) -> char* {
        char* r = base; base += (bytes + 255) & ~(size_t)255; return r;
    };
    float* pf    = (float*)alloc(8 * 32768 * 4);
    float* pfq   = (float*)alloc(8 * 32768 * 4);
    float* pg    = (float*)alloc(4 * 32768 * 4);
    float* pgq   = (float*)alloc(4 * 32768 * 4);
    float* cs1   = (float*)alloc(512 * 4);
    float* cst1  = (float*)alloc(512 * 4);
    float* cs2   = (float*)alloc(512 * 4);
    float* cst2  = (float*)alloc(512 * 4);
    float* scv   = (float*)alloc(256 * 4);
    float* shv   = (float*)alloc(256 * 4);
    float* dwt   = (float*)alloc(9 * 256 * 4);
    unsigned short* Wb1t = (unsigned short*)alloc(262144 * 2);
    unsigned short* Wb2t = (unsigned short*)alloc(65536 * 2);
    unsigned short* Wot  = (unsigned short*)alloc(65536 * 2);
    unsigned short* Woc  = (unsigned short*)alloc(65536 * 2);
    unsigned short* ef_bf = (unsigned short*)alloc((size_t)32768 * 512 * 2);
    unsigned short* eg_bf = (unsigned short*)alloc((size_t)32768 * 256 * 2);
    unsigned short* qbuf  = (unsigned short*)alloc((size_t)32768 * 256 * 2);
    unsigned short* efpbuf = (unsigned short*)alloc((size_t)32768 * 256 * 2);
    unsigned short* kfull = (unsigned short*)alloc((size_t)32768 * 256 * 2); // -> combined
    unsigned short* kpb  = (unsigned short*)alloc(128 * 256 * 2);
    float* vp    = (float*)alloc(128 * 256 * 4);
    float* s1    = (float*)alloc(128 * 256 * 4);
    float* s0    = (float*)alloc(128 * 4);

    trans_prep<<<3354, 256, 0, stream>>>(
        e_f, e_g, ef_bf, eg_bf, pf, pfq, pg, pgq,
        lnfg, lnfb, wq, bq, efpw, efpb, lngg, lngb, wk, bk, wv, bv, wo,
        outcw, outcb, bng, bnb, bnm, bnv, dwk,
        Wb1t, Wb2t, Wot, Woc, dwt, cs1, cst1, cs2, cst2, scv, shv);
    gemm_proj<<<1536, 256, 0, stream>>>(
        ef_bf, Wb1t, cs1, cst1, pf, pfq, qbuf, efpbuf,
        eg_bf, Wb2t, cs2, cst2, pg, pgq, kfull,
        e_g, s1, s0);
    pool_vp<<<256, 256, 0, stream>>>(kfull, kpb, s1, s0, lngg, wv, cs2, cst2, vp);
    combined_dw<<<512, 256, 0, stream>>>(qbuf, kpb, vp, dwt, /*combined=*/kfull);
    gemm34_mfma<<<512, 256, 0, stream>>>(/*combined=*/kfull, Wot, bo, efpbuf,
                                         Woc, scv, shv, outp);
}